// Round 6
// baseline (10103.138 us; speedup 1.0000x reference)
//
#include <hip/hip_runtime.h>
#include <math.h>

typedef double double2v __attribute__((ext_vector_type(2)));

// ===================== JAX Threefry-2x32 (bit-exact) =====================
__device__ __forceinline__ void threefry2x32(unsigned k0, unsigned k1,
                                             unsigned x0, unsigned x1,
                                             unsigned& o0, unsigned& o1)
{
  unsigned ks2 = k0 ^ k1 ^ 0x1BD11BDAu;
  x0 += k0; x1 += k1;
#define TFR(r) { x0 += x1; x1 = (x1 << r) | (x1 >> (32 - r)); x1 ^= x0; }
  TFR(13) TFR(15) TFR(26) TFR(6)
  x0 += k1;  x1 += ks2 + 1u;
  TFR(17) TFR(29) TFR(16) TFR(24)
  x0 += ks2; x1 += k0 + 2u;
  TFR(13) TFR(15) TFR(26) TFR(6)
  x0 += k0;  x1 += k1 + 3u;
  TFR(17) TFR(29) TFR(16) TFR(24)
  x0 += k1;  x1 += ks2 + 4u;
  TFR(13) TFR(15) TFR(26) TFR(6)
  x0 += ks2; x1 += k0 + 5u;
#undef TFR
  o0 = x0; o1 = x1;
}

// jax_threefry_partitionable=True: word e = o0 ^ o1 of block (0, e)
__device__ __forceinline__ unsigned rand_word(unsigned kA, unsigned kB, unsigned e)
{
  unsigned o0, o1;
  threefry2x32(kA, kB, 0u, e, o0, o1);
  return o0 ^ o1;
}

__device__ __forceinline__ float bits_to_unit(unsigned bits)
{
  unsigned u = (bits >> 9) | 0x3f800000u;
  return __uint_as_float(u) - 1.0f;   // exact, in [0,1)
}

// erfinv in double: Giles poly init + 1 Halley iteration on erf()
__device__ __forceinline__ double erfinv_d(double x)
{
  double w = -log((1.0 - x) * (1.0 + x));
  double p;
  if (w < 5.0) {
    w -= 2.5;
    p = 2.81022636e-08;
    p = fma(p, w, 3.43273939e-07);
    p = fma(p, w, -3.5233877e-06);
    p = fma(p, w, -4.39150654e-06);
    p = fma(p, w, 0.00021858087);
    p = fma(p, w, -0.00125372503);
    p = fma(p, w, -0.00417768164);
    p = fma(p, w, 0.246640727);
    p = fma(p, w, 1.50140941);
  } else {
    w = sqrt(w) - 3.0;
    p = -0.000200214257;
    p = fma(p, w, 0.000100950558);
    p = fma(p, w, 0.00134934322);
    p = fma(p, w, -0.00367342844);
    p = fma(p, w, 0.00573950773);
    p = fma(p, w, -0.0076224613);
    p = fma(p, w, 0.00943887047);
    p = fma(p, w, 1.00167406);
    p = fma(p, w, 2.83297682);
  }
  double r = p * x;
  double f  = erf(r) - x;
  double fp = 1.1283791670955126 * exp(-r * r);   // 2/sqrt(pi) e^{-r^2}
  double q  = f / fp;
  return r - q / (1.0 + r * q);
}

// N(0,1) sample e of a jax.random.normal(f32) draw
__device__ __forceinline__ double eps_normal(unsigned kA, unsigned kB, unsigned e)
{
  float f = bits_to_unit(rand_word(kA, kB, e));
  double u = (double)f * (2.0 - 5.9604644775390625e-8)
           - (1.0 - 5.9604644775390625e-8);
  return 1.4142135623730951 * erfinv_d(u);
}

__device__ __forceinline__ double sigd(double x) { return 1.0 / (1.0 + exp(-x)); }

__device__ __forceinline__ double gumbel_d(unsigned kA, unsigned kB, unsigned e)
{
  float f = bits_to_unit(rand_word(kA, kB, e));
  double u = (f == 0.0f) ? 1.1754943508222875e-38 : (double)f;
  return -log(-log(u));
}

// ===================== setup kernels =====================
__global__ void k_keys(unsigned* keys)
{
  if (threadIdx.x != 0 || blockIdx.x != 0) return;
  unsigned a0,a1,b0,b1,c0,c1,d0,d1;
  unsigned kx = 0u, ky = 42u;                 // jax.random.key(42)
  threefry2x32(kx, ky, 0u, 0u, a0, a1);       // carried key
  threefry2x32(kx, ky, 0u, 1u, b0, b1);       // k0 (h0 uniform)
  keys[0] = b0; keys[1] = b1;
  kx = a0; ky = a1;
  for (int s = 0; s < 100; ++s) {
    threefry2x32(kx, ky, 0u, 0u, a0, a1);     // k
    threefry2x32(kx, ky, 0u, 1u, c0, c1);     // ke
    threefry2x32(kx, ky, 0u, 2u, d0, d1);     // kr
    keys[2 + 4*s + 0] = c0; keys[2 + 4*s + 1] = c1;
    keys[2 + 4*s + 2] = d0; keys[2 + 4*s + 3] = d1;
    kx = a0; ky = a1;
  }
}

__global__ __launch_bounds__(256) void k_prep(
    const float* fcz_w, const float* fcz_b, const float* fcr_w, const float* fcr_b,
    const float* fcn_w, const float* fcn_b, const float* fco_w, const float* fco_b,
    const float* h2l_w, const float* h2l_b,
    double* wzrT, double* wnT, double* wo, double* bz, double* br,
    double* bnn, double* bo, double* h2lw, double* h2lb)
{
  int id = blockIdx.x * 256 + threadIdx.x;
  if (id < 65536) {
    int k = id >> 8, j = id & 255;
    wzrT[id] = (double)((j < 128) ? fcz_w[j*256 + k] : fcr_w[(j-128)*256 + k]);
    return;
  }
  id -= 65536;
  if (id < 65536) { int k = id >> 8, j = id & 255; wnT[id] = (double)fcn_w[j*256 + k]; return; }
  id -= 65536;
  if (id < 256) { wo[id] = (double)fco_w[id]; return; }
  id -= 256;
  if (id < 128) { bz[id] = (double)fcz_b[id]; return; }
  id -= 128;
  if (id < 128) { br[id] = (double)fcr_b[id]; return; }
  id -= 128;
  if (id < 256) { bnn[id] = (double)fcn_b[id]; return; }
  id -= 256;
  if (id < 1) { bo[0] = (double)fco_b[0]; return; }
  id -= 1;
  if (id < 384) { h2lw[id] = (double)h2l_w[id]; return; }
  id -= 384;
  if (id < 3) { h2lb[id] = (double)h2l_b[id]; return; }
}

__global__ __launch_bounds__(256) void k_h0(const unsigned* keys, double* h, double* p)
{
  unsigned e = blockIdx.x * 256 + threadIdx.x;    // < 524288
  h[e] = (double)bits_to_unit(rand_word(keys[0], keys[1], e));
  if (e < 4096) p[e] = (double)(float)log(1.0 / 128.0);
}

// ===================== frontend (map CNN encoder) =====================
__global__ __launch_bounds__(256) void k_conv1(const float* in, const float* w, double* out)
{
  int bc = blockIdx.x; int b = bc >> 4, co = bc & 15;
  __shared__ double wl[25];
  __shared__ float plf[4096];
  if (threadIdx.x < 25) wl[threadIdx.x] = (double)w[co*25 + threadIdx.x];
  const float* ib = in + (size_t)b * 4096;
  for (int j = 0; j < 16; ++j) plf[threadIdx.x + j*256] = ib[threadIdx.x + j*256];
  __syncthreads();
  for (int q = 0; q < 4; ++q) {
    int px = q*256 + threadIdx.x;
    int oh = px >> 5, ow = px & 31;
    double acc = 0.0;
    for (int kh = 0; kh < 5; ++kh) {
      int ih = oh*2 - 2 + kh; if (ih < 0 || ih >= 64) continue;
      for (int kw = 0; kw < 5; ++kw) {
        int iw = ow*2 - 2 + kw; if (iw < 0 || iw >= 64) continue;
        acc = fma((double)plf[ih*64 + iw], wl[kh*5 + kw], acc);
      }
    }
    out[((size_t)b*16 + co)*1024 + px] = fmax(acc, 0.0);
  }
}

__global__ __launch_bounds__(256) void k_conv3x3(const double* in, const float* w,
                                                 double* out, int Ci, int Co)
{
  int bc = blockIdx.x; int b = bc / Co, co = bc % Co;
  __shared__ double wl[288];
  __shared__ double pl[2][1024];
  for (int e = threadIdx.x; e < Ci*9; e += 256) wl[e] = (double)w[co*Ci*9 + e];
  double acc[4] = {0.0, 0.0, 0.0, 0.0};
  const double* ib = in + (size_t)b * Ci * 1024;
  // preload plane 0
  for (int q = 0; q < 4; ++q)
    pl[0][threadIdx.x + q*256] = ib[threadIdx.x + q*256];
  __syncthreads();
  for (int ci = 0; ci < Ci; ++ci) {
    int cur = ci & 1;
    // prefetch next plane into other buffer (overlaps with compute below)
    if (ci + 1 < Ci) {
      for (int q = 0; q < 4; ++q)
        pl[cur ^ 1][threadIdx.x + q*256] = ib[(ci + 1)*1024 + threadIdx.x + q*256];
    }
    const double* wp = wl + ci*9;
    for (int q = 0; q < 4; ++q) {
      int px = q*256 + threadIdx.x;
      int oh = px >> 5, ow = px & 31;
      double a = acc[q];
      for (int kh = 0; kh < 3; ++kh) {
        int ih = oh - 1 + kh; if (ih < 0 || ih >= 32) continue;
        for (int kw = 0; kw < 3; ++kw) {
          int iw = ow - 1 + kw; if (iw < 0 || iw >= 32) continue;
          a = fma(pl[cur][ih*32 + iw], wp[kh*3 + kw], a);
        }
      }
      acc[q] = a;
    }
    __syncthreads();
  }
  for (int q = 0; q < 4; ++q) {
    int px = q*256 + threadIdx.x;
    out[((size_t)b*Co + co)*1024 + px] = fmax(acc[q], 0.0);
  }
}

// BN stats, stage 1: per (c, chunk-of-4-batches) partial sums
__global__ __launch_bounds__(256) void k_bnstats1(const double* __restrict__ x,
    double* __restrict__ partS, double* __restrict__ partS2, int C)
{
  int c = blockIdx.x >> 3, chunk = blockIdx.x & 7;
  double s = 0.0, s2 = 0.0;
  for (int e = threadIdx.x; e < 4096; e += 256) {
    int b = chunk*4 + (e >> 10), px = e & 1023;
    double v = x[((size_t)b*C + c)*1024 + px];
    s += v; s2 = fma(v, v, s2);
  }
  __shared__ double rs[256], rs2[256];
  rs[threadIdx.x] = s; rs2[threadIdx.x] = s2;
  __syncthreads();
  for (int d = 128; d; d >>= 1) {
    if (threadIdx.x < d) { rs[threadIdx.x] += rs[threadIdx.x + d]; rs2[threadIdx.x] += rs2[threadIdx.x + d]; }
    __syncthreads();
  }
  if (threadIdx.x == 0) { partS[blockIdx.x] = rs[0]; partS2[blockIdx.x] = rs2[0]; }
}

// BN stats, stage 2: deterministic combine
__global__ void k_bnstats2(const double* __restrict__ partS,
                           const double* __restrict__ partS2,
                           const float* g, const float* bta, double* scsh, int C)
{
  int c = threadIdx.x;
  if (c >= C) return;
  double s = 0.0, s2 = 0.0;
  for (int j = 0; j < 8; ++j) { s += partS[c*8 + j]; s2 += partS2[c*8 + j]; }
  double n = 32768.0;
  double mean = s / n;
  double var = s2 / n - mean*mean;
  double sc = (double)g[c] / sqrt(var + 1e-5);
  scsh[c*2] = sc;
  scsh[c*2 + 1] = (double)bta[c] - mean * sc;
}

__global__ __launch_bounds__(256) void k_bnapply(double* x, const double* scsh, int C)
{
  size_t e = (size_t)blockIdx.x * 256 + threadIdx.x;
  int c = (int)((e >> 10) % (size_t)C);
  x[e] = fma(x[e], scsh[c*2], scsh[c*2 + 1]);
}

__global__ __launch_bounds__(256) void k_mapfc(const double* x, const float* w,
                                               const float* bias, double* emb)
{
  int blk = blockIdx.x; int b = blk >> 4, jg = blk & 15;
  double acc[8];
  #pragma unroll
  for (int jj = 0; jj < 8; ++jj) acc[jj] = 0.0;
  const double* xb = x + (size_t)b * 32768;
  for (int e = threadIdx.x; e < 32768; e += 256) {
    double xv = xb[e];
    #pragma unroll
    for (int jj = 0; jj < 8; ++jj)
      acc[jj] = fma(xv, (double)w[(size_t)(jg*8 + jj)*32768 + e], acc[jj]);
  }
  __shared__ double red[8][256];
  #pragma unroll
  for (int jj = 0; jj < 8; ++jj) red[jj][threadIdx.x] = acc[jj];
  __syncthreads();
  for (int d = 128; d; d >>= 1) {
    if (threadIdx.x < d)
      #pragma unroll
      for (int jj = 0; jj < 8; ++jj) red[jj][threadIdx.x] += red[jj][threadIdx.x + d];
    __syncthreads();
  }
  if (threadIdx.x < 8) {
    int j = jg*8 + threadIdx.x;
    emb[b*128 + j] = fmax(red[threadIdx.x][0] + (double)bias[j], 0.0);
  }
}

__global__ void k_maps(const double* emb, const float* m2o_w, const float* m2o_b,
                       const float* m2a_w, const float* m2a_b,
                       double* omap, double* amap)
{
  int b = blockIdx.x, j = threadIdx.x;   // 64 threads
  double a1 = (double)m2o_b[j], a2 = (double)m2a_b[j];
  for (int k = 0; k < 128; ++k) {
    double ev = emb[b*128 + k];
    a1 = fma(ev, (double)m2o_w[j*128 + k], a1);
    a2 = fma(ev, (double)m2a_w[j*128 + k], a2);
  }
  omap[b*64 + j] = fmax(a1, 0.0);
  amap[b*64 + j] = fmax(a2, 0.0);
}

// xs + xo (xo = x-part of fco dot product)
__global__ __launch_bounds__(128) void k_xs(const float* obs_in, const float* act_in,
                                            const float* obs_w, const float* obs_b,
                                            const float* act_w, const float* act_b,
                                            const double* omap, const double* amap,
                                            const double* wo,
                                            double* xs, double* xo)
{
  int s = blockIdx.x, b = blockIdx.y, j = threadIdx.x;
  double v;
  if (j < 64) {
    double a = (double)obs_b[j];
    const float* o = obs_in + ((size_t)b*100 + s)*16;
    for (int k = 0; k < 16; ++k) a = fma((double)o[k], (double)obs_w[j*16 + k], a);
    v = fmax(a, 0.0) * omap[b*64 + j];
  } else {
    int j2 = j - 64;
    double a = (double)act_b[j2];
    const float* o = act_in + ((size_t)b*100 + s)*3;
    for (int k = 0; k < 3; ++k) a = fma((double)o[k], (double)act_w[j2*3 + k], a);
    v = fmax(a, 0.0) * amap[b*64 + j2];
  }
  xs[((size_t)s*32 + b)*128 + j] = v;
  __shared__ double red[128];
  red[j] = v * wo[128 + j];
  __syncthreads();
  for (int d = 64; d; d >>= 1) {
    if (j < d) red[j] += red[j + d];
    __syncthreads();
  }
  if (j == 0) xo[s*32 + b] = red[0];
}

// x-part precompute, GEMM form: 400 blocks = (s, group-of-8-batches)
__global__ __launch_bounds__(256, 2) void k_xpre2(const double* __restrict__ xs,
    const double* __restrict__ wzrT, const double* __restrict__ wnT,
    double* __restrict__ xzr, double* __restrict__ xn)
{
  int s = blockIdx.x >> 2, bg = blockIdx.x & 3;
  __shared__ double xl[8][128];
  int t = threadIdx.x;
  #pragma unroll
  for (int j = 0; j < 4; ++j) {
    int e = t + j*256;
    int i = e >> 7, cc = e & 127;
    xl[i][cc] = xs[((size_t)s*32 + bg*8 + i)*128 + cc];
  }
  __syncthreads();
  double az[8], an[8];
  #pragma unroll
  for (int i = 0; i < 8; ++i) { az[i] = 0.0; an[i] = 0.0; }
  for (int k = 0; k < 128; ++k) {
    double wz = wzrT[k*256 + t];
    double wn = wnT[(128 + k)*256 + t];
    #pragma unroll
    for (int i = 0; i < 8; ++i) {
      double xv = xl[i][k];
      az[i] = fma(xv, wz, az[i]);
      an[i] = fma(xv, wn, an[i]);
    }
  }
  #pragma unroll
  for (int i = 0; i < 8; ++i) {
    size_t sb = (size_t)s*32 + bg*8 + i;
    xzr[sb*256 + t] = az[i];
    xn [sb*256 + t] = an[i];
  }
}

// ===================== fused scan kernels =====================
// k_step1: 512 blocks x 512 threads; 8 rows/block; thread = (rg = t>>8 ->
// 4-row subgroup, c = t&255 output column). 4 outputs/thread per GEMM.
__global__ __launch_bounds__(512, 4) void k_step1(
    const double* __restrict__ hsrc, const int* __restrict__ idxp,
    const double* __restrict__ xzr, const double* __restrict__ xn,
    const double* __restrict__ xo,
    const double* __restrict__ wzrT, const double* __restrict__ wnT,
    const double* __restrict__ bz, const double* __restrict__ br,
    const double* __restrict__ bnn, const double* __restrict__ wo,
    const double* __restrict__ bo, const double* __restrict__ p,
    const double* __restrict__ h2lw, const double* __restrict__ h2lb,
    double* __restrict__ h1out, double* __restrict__ logpdf,
    float* __restrict__ pfout, const unsigned* __restrict__ keys, int s)
{
  __shared__ double ah[8][128];    // gathered h (= hst of step s-1)
  __shared__ double aw[8][128];    // rg*h, later eps
  __shared__ double zsh[8][128];   // z, later h1
  __shared__ double sps[8][128];   // softplus(var)
  const int t  = threadIdx.x;
  const int rg = t >> 8;           // 0/1: rows rg*4 .. rg*4+3
  const int c  = t & 255;          // output column 0..255
  const int r0 = blockIdx.x * 8;
  const bool first = (idxp == nullptr);
  // gather prev h (2 elements/thread, coalesced)
  #pragma unroll
  for (int j = 0; j < 2; ++j) {
    int e = t + j*512;
    int r = e >> 7, cc = e & 127;
    int R = r0 + r, b = R & 31;
    int src = first ? R : (idxp[R]*32 + b);
    ah[r][cc] = hsrc[(size_t)src*128 + cc];
  }
  __syncthreads();
  // pf for previous step: 8 waves x 1 row
  if (pfout != nullptr) {
    int wv = t >> 6, lane = t & 63;
    double v0 = ah[wv][lane*2], v1 = ah[wv][lane*2 + 1];
    double s0 = fma(v0, h2lw[lane*2],       v1 * h2lw[lane*2 + 1]);
    double s1 = fma(v0, h2lw[128 + lane*2], v1 * h2lw[128 + lane*2 + 1]);
    double s2 = fma(v0, h2lw[256 + lane*2], v1 * h2lw[256 + lane*2 + 1]);
    for (int d = 32; d; d >>= 1) {
      s0 += __shfl_xor(s0, d, 64);
      s1 += __shfl_xor(s1, d, 64);
      s2 += __shfl_xor(s2, d, 64);
    }
    if (lane == 0) {
      float* o = pfout + (r0 + wv) * 3;
      o[0] = (float)(1.0 / (1.0 + exp(-(s0 + h2lb[0]))));
      o[1] = (float)(1.0 / (1.0 + exp(-(s1 + h2lb[1]))));
      o[2] = (float)(1.0 / (1.0 + exp(-(s2 + h2lb[2]))));
    }
  }
  // GEMM1: h-part of [x|h] @ Wzr^T  (col c; 4 rows; k vectorized by 2)
  double acc[4];
  #pragma unroll
  for (int i = 0; i < 4; ++i) acc[i] = 0.0;
  {
    const double2v* ap0 = (const double2v*)&ah[rg*4 + 0][0];
    const double2v* ap1 = (const double2v*)&ah[rg*4 + 1][0];
    const double2v* ap2 = (const double2v*)&ah[rg*4 + 2][0];
    const double2v* ap3 = (const double2v*)&ah[rg*4 + 3][0];
    for (int k2 = 0; k2 < 64; ++k2) {
      double w0 = wzrT[(128 + 2*k2)*256 + c];
      double w1 = wzrT[(128 + 2*k2 + 1)*256 + c];
      double2v a0 = ap0[k2], a1 = ap1[k2], a2 = ap2[k2], a3 = ap3[k2];
      acc[0] = fma(a0.y, w1, fma(a0.x, w0, acc[0]));
      acc[1] = fma(a1.y, w1, fma(a1.x, w0, acc[1]));
      acc[2] = fma(a2.y, w1, fma(a2.x, w0, acc[2]));
      acc[3] = fma(a3.y, w1, fma(a3.x, w0, acc[3]));
    }
  }
  if (c < 128) {               // z columns
    double bzv = bz[c];
    #pragma unroll
    for (int i = 0; i < 4; ++i) {
      int b = (r0 + rg*4 + i) & 31;
      zsh[rg*4 + i][c] = sigd(acc[i] + xzr[b*256 + c] + bzv);
    }
  } else {                     // rg columns -> aw = rg*h
    int cc = c - 128;
    double brv = br[cc];
    #pragma unroll
    for (int i = 0; i < 4; ++i) {
      int b = (r0 + rg*4 + i) & 31;
      double rgv = sigd(acc[i] + xzr[b*256 + c] + brv);
      aw[rg*4 + i][cc] = rgv * ah[rg*4 + i][cc];
    }
  }
  __syncthreads();
  // GEMM2: (rg*h)-part of [rg*h|x] @ Wn^T
  #pragma unroll
  for (int i = 0; i < 4; ++i) acc[i] = 0.0;
  {
    const double2v* ap0 = (const double2v*)&aw[rg*4 + 0][0];
    const double2v* ap1 = (const double2v*)&aw[rg*4 + 1][0];
    const double2v* ap2 = (const double2v*)&aw[rg*4 + 2][0];
    const double2v* ap3 = (const double2v*)&aw[rg*4 + 3][0];
    for (int k2 = 0; k2 < 64; ++k2) {
      double w0 = wnT[(2*k2)*256 + c];
      double w1 = wnT[(2*k2 + 1)*256 + c];
      double2v a0 = ap0[k2], a1 = ap1[k2], a2 = ap2[k2], a3 = ap3[k2];
      acc[0] = fma(a0.y, w1, fma(a0.x, w0, acc[0]));
      acc[1] = fma(a1.y, w1, fma(a1.x, w0, acc[1]));
      acc[2] = fma(a2.y, w1, fma(a2.x, w0, acc[2]));
      acc[3] = fma(a3.y, w1, fma(a3.x, w0, acc[3]));
    }
  }
  // finish mu / softplus(var) in registers
  double mv[4];
  if (c < 128) {               // mu columns
    double bn0 = bnn[c];
    #pragma unroll
    for (int i = 0; i < 4; ++i) {
      int b = (r0 + rg*4 + i) & 31;
      mv[i] = acc[i] + xn[b*256 + c] + bn0;
    }
  } else {                     // var columns -> softplus
    double bn1 = bnn[c];
    #pragma unroll
    for (int i = 0; i < 4; ++i) {
      int b = (r0 + rg*4 + i) & 31;
      double var = acc[i] + xn[b*256 + c] + bn1;
      mv[i] = fmax(var, 0.0) + log1p(exp(-fabs(var)));
    }
  }
  __syncthreads();   // all aw reads (GEMM2) complete
  if (c >= 128) {
    int cc = c - 128;
    #pragma unroll
    for (int i = 0; i < 4; ++i) sps[rg*4 + i][cc] = mv[i];
  }
  // eps: distributed over all 512 threads (2 each), into aw
  {
    unsigned keA = keys[2 + 4*s], keB = keys[2 + 4*s + 1];
    #pragma unroll
    for (int j = 0; j < 2; ++j) {
      int e = t + j*512;
      int r = e >> 7, cc = e & 127;
      aw[r][cc] = eps_normal(keA, keB, (unsigned)((r0 + r)*128 + cc));
    }
  }
  __syncthreads();
  // h1 = (1-z)*n + z*h  (mu threads), write global + keep in zsh
  if (c < 128) {
    #pragma unroll
    for (int i = 0; i < 4; ++i) {
      int row = rg*4 + i, R = r0 + row;
      double n  = fma(aw[row][c], sps[row][c], mv[i]);
      double z  = zsh[row][c];
      double hv = (1.0 - z)*n + z*ah[row][c];
      h1out[(size_t)R*128 + c] = hv;
      zsh[row][c] = hv;
    }
  }
  __syncthreads();
  // logpdf: 8 waves x 1 row
  {
    int wv = t >> 6, lane = t & 63;
    int R = r0 + wv, b = R & 31;
    double part = fma(zsh[wv][lane], wo[lane], zsh[wv][lane + 64] * wo[lane + 64]);
    for (int d = 32; d; d >>= 1) part += __shfl_xor(part, d, 64);
    if (lane == 0) logpdf[R] = part + xo[b] + bo[0] + p[R];
  }
}

// k_sr: per-batch softmax + Gumbel-argmax resample + pn normalize + y.
__global__ __launch_bounds__(1024) void k_sr(
    const double* __restrict__ logpdf, const double* __restrict__ h1,
    const unsigned* __restrict__ keys, int s,
    int* __restrict__ idx, double* __restrict__ p,
    const double* __restrict__ h2lw, const double* __restrict__ h2lb,
    float* __restrict__ yout)
{
  int b = blockIdx.x, t = threadIdx.x;
  __shared__ double p1s[128], lgs[128], pns[128], wsh[128], ys[128];
  __shared__ double red8[8][128];
  __shared__ int    is[128];
  __shared__ double sm[2], ss[2];
  // phase 1: log_softmax over particles
  if (t < 128) {
    double v = logpdf[t*32 + b];
    double m = v;
    for (int d = 32; d; d >>= 1) m = fmax(m, __shfl_xor(m, d, 64));
    if ((t & 63) == 0) sm[t >> 6] = m;
  }
  __syncthreads();
  if (t < 128) {
    double v = logpdf[t*32 + b];
    double m = fmax(sm[0], sm[1]);
    double e = exp(v - m), su = e;
    for (int d = 32; d; d >>= 1) su += __shfl_xor(su, d, 64);
    if ((t & 63) == 0) ss[t >> 6] = su;
  }
  __syncthreads();
  if (t < 128) {
    double v = logpdf[t*32 + b];
    double m = fmax(sm[0], sm[1]);
    double p1v = v - m - log(ss[0] + ss[1]);
    p1s[t] = p1v;
    lgs[t] = log(0.5*exp(p1v) + 0.00390625);
  }
  __syncthreads();
  // phase 2: Gumbel-argmax, one draw row per wave iteration
  {
    unsigned kA = keys[2 + 4*s + 2], kB = keys[2 + 4*s + 3];
    int lane = t & 63;
    for (int i = (t >> 6); i < 128; i += 16) {
      int r = i*32 + b;
      double v0 = gumbel_d(kA, kB, (unsigned)(r*128 + lane)) + lgs[lane];
      double v1 = gumbel_d(kA, kB, (unsigned)(r*128 + lane + 64)) + lgs[lane + 64];
      double val; int bj;
      if (v0 >= v1) { val = v0; bj = lane; } else { val = v1; bj = lane + 64; }
      for (int d = 32; d; d >>= 1) {
        double ov = __shfl_xor(val, d, 64);
        int    oj = __shfl_xor(bj, d, 64);
        if (ov > val || (ov == val && oj < bj)) { val = ov; bj = oj; }
      }
      if (lane == 0) {
        is[i] = bj;
        idx[i*32 + b] = bj;
        double pe = exp(p1s[bj]);
        pns[i] = log(pe / (0.5*pe + 0.00390625));
      }
    }
  }
  __syncthreads();
  // phase 3: normalize pn, store carry p and weights
  if (t < 128) {
    double q = pns[t];
    double m = q;
    for (int d = 32; d; d >>= 1) m = fmax(m, __shfl_xor(m, d, 64));
    if ((t & 63) == 0) sm[t >> 6] = m;
  }
  __syncthreads();
  if (t < 128) {
    double q = pns[t];
    double m = fmax(sm[0], sm[1]);
    double e = exp(q - m), su = e;
    for (int d = 32; d; d >>= 1) su += __shfl_xor(su, d, 64);
    if ((t & 63) == 0) ss[t >> 6] = su;
  }
  __syncthreads();
  if (t < 128) {
    double q = pns[t];
    double m = fmax(sm[0], sm[1]);
    double pn = q - (m + log(ss[0] + ss[1]));
    p[t*32 + b] = pn;
    wsh[t] = exp(pn);
  }
  __syncthreads();
  // phase 4: y = sum_i w_i * h1[idx_i]  (8-way split over ii), h2l + sigmoid
  {
    int col = t & 127, g = t >> 7;   // g in 0..7
    double acc = 0.0;
    for (int q = 0; q < 16; ++q) {
      int ii = g*16 + q;
      acc = fma(wsh[ii], h1[(size_t)(is[ii]*32 + b)*128 + col], acc);
    }
    red8[g][col] = acc;
  }
  __syncthreads();
  if (t < 128) {
    double a = red8[0][t];
    for (int gg = 1; gg < 8; ++gg) a += red8[gg][t];
    ys[t] = a;
  }
  __syncthreads();
  if (t < 3) {
    double d = h2lb[t];
    for (int c = 0; c < 128; ++c) d = fma(h2lw[t*128 + c], ys[c], d);
    yout[s*96 + b*3 + t] = (float)(1.0 / (1.0 + exp(-d)));
  }
}

// epilogue: pf for the last step (gather via idx)
__global__ __launch_bounds__(256) void k_pfend(const double* __restrict__ h1,
    const int* __restrict__ idx, const double* __restrict__ h2lw,
    const double* __restrict__ h2lb, float* __restrict__ pfout)
{
  int wv = threadIdx.x >> 6, lane = threadIdx.x & 63;
  int r = blockIdx.x * 4 + wv;
  int b = r & 31;
  const double* hr = h1 + (size_t)(idx[r]*32 + b) * 128;
  double v0 = hr[lane*2], v1 = hr[lane*2 + 1];
  double s0 = fma(v0, h2lw[lane*2],       v1 * h2lw[lane*2 + 1]);
  double s1 = fma(v0, h2lw[128 + lane*2], v1 * h2lw[128 + lane*2 + 1]);
  double s2 = fma(v0, h2lw[256 + lane*2], v1 * h2lw[256 + lane*2 + 1]);
  for (int d = 32; d; d >>= 1) {
    s0 += __shfl_xor(s0, d, 64);
    s1 += __shfl_xor(s1, d, 64);
    s2 += __shfl_xor(s2, d, 64);
  }
  if (lane == 0) {
    float* o = pfout + r * 3;
    o[0] = (float)(1.0 / (1.0 + exp(-(s0 + h2lb[0]))));
    o[1] = (float)(1.0 / (1.0 + exp(-(s1 + h2lb[1]))));
    o[2] = (float)(1.0 / (1.0 + exp(-(s2 + h2lb[2]))));
  }
}

// ===================== host launch =====================
extern "C" void kernel_launch(void* const* d_in, const int* in_sizes, int n_in,
                              void* d_out, int out_size, void* d_ws, size_t ws_size,
                              hipStream_t stream)
{
  (void)in_sizes; (void)n_in; (void)out_size; (void)ws_size;
  const float* map_in = (const float*)d_in[0];
  const float* obs_in = (const float*)d_in[1];
  const float* act_in = (const float*)d_in[2];
  const float* c1_w = (const float*)d_in[3];
  const float* c1_g = (const float*)d_in[4];
  const float* c1_b = (const float*)d_in[5];
  const float* c2_w = (const float*)d_in[6];
  const float* c2_g = (const float*)d_in[7];
  const float* c2_b = (const float*)d_in[8];
  const float* c3_w = (const float*)d_in[9];
  const float* c3_g = (const float*)d_in[10];
  const float* c3_b = (const float*)d_in[11];
  const float* map_w = (const float*)d_in[12];
  const float* map_b = (const float*)d_in[13];
  const float* m2o_w = (const float*)d_in[14];
  const float* m2o_b = (const float*)d_in[15];
  const float* m2a_w = (const float*)d_in[16];
  const float* m2a_b = (const float*)d_in[17];
  const float* obs_w = (const float*)d_in[18];
  const float* obs_b = (const float*)d_in[19];
  const float* act_w = (const float*)d_in[20];
  const float* act_b = (const float*)d_in[21];
  const float* fcz_w = (const float*)d_in[22];
  const float* fcz_b = (const float*)d_in[23];
  const float* fcr_w = (const float*)d_in[24];
  const float* fcr_b = (const float*)d_in[25];
  const float* fcn_w = (const float*)d_in[26];
  const float* fcn_b = (const float*)d_in[27];
  const float* fco_w = (const float*)d_in[28];
  const float* fco_b = (const float*)d_in[29];
  const float* h2l_w = (const float*)d_in[30];
  const float* h2l_b = (const float*)d_in[31];

  float* yout  = (float*)d_out;
  float* pfout = (float*)d_out + 9600;

  char* ws = (char*)d_ws;
  double*   H0     = (double*)(ws + 0);           // 4096*128
  double*   H1A    = (double*)(ws + 4194304);
  double*   H1B    = (double*)(ws + 8388608);
  double*   XS     = (double*)(ws + 12582912);    // 100*32*128
  // conv region (dead after k_mapfc) overlaid by XZR/XN/XO
  double*   C1O    = (double*)(ws + 15859712);    // 32*16*1024
  double*   C2O    = (double*)(ws + 20054016);    // 32*32*1024
  double*   C3O    = (double*)(ws + 28442624);    // 32*32*1024
  double*   XZR    = (double*)(ws + 15859712);    // 100*32*256 (overlay)
  double*   XN     = (double*)(ws + 22413312);    // 100*32*256 (overlay)
  double*   XO     = (double*)(ws + 28966912);    // 100*32     (overlay)
  double*   WZRT   = (double*)(ws + 36831232);    // 256*256
  double*   WNT    = (double*)(ws + 37355520);
  double*   WO     = (double*)(ws + 37879808);
  double*   BZ     = (double*)(ws + 37881856);
  double*   BR     = (double*)(ws + 37882880);
  double*   BNN    = (double*)(ws + 37883904);
  double*   BO     = (double*)(ws + 37885952);
  double*   H2LW   = (double*)(ws + 37886208);
  double*   H2LB   = (double*)(ws + 37889280);
  double*   EMB    = (double*)(ws + 37889536);    // 32*128
  double*   OMAP   = (double*)(ws + 37922304);    // 32*64
  double*   AMAP   = (double*)(ws + 37938688);
  double*   P      = (double*)(ws + 37955072);    // 4096
  double*   LOGPDF = (double*)(ws + 37987840);    // 4096
  int*      IDX    = (int*)   (ws + 38020608);    // 4096
  unsigned* KEYS   = (unsigned*)(ws + 38036992);  // 402
  double*   SCSH   = (double*)(ws + 38039040);    // 32*2
  double*   PARTS  = (double*)(ws + 38039552);    // 256
  double*   PARTS2 = (double*)(ws + 38041600);    // 256

  // ---- setup ----
  k_keys<<<1, 64, 0, stream>>>(KEYS);
  k_prep<<<517, 256, 0, stream>>>(fcz_w, fcz_b, fcr_w, fcr_b, fcn_w, fcn_b,
                                  fco_w, fco_b, h2l_w, h2l_b,
                                  WZRT, WNT, WO, BZ, BR, BNN, BO, H2LW, H2LB);
  k_h0<<<2048, 256, 0, stream>>>(KEYS, H0, P);

  // ---- frontend ----
  k_conv1<<<512, 256, 0, stream>>>(map_in, c1_w, C1O);
  k_bnstats1<<<128, 256, 0, stream>>>(C1O, PARTS, PARTS2, 16);
  k_bnstats2<<<1, 32, 0, stream>>>(PARTS, PARTS2, c1_g, c1_b, SCSH, 16);
  k_bnapply<<<2048, 256, 0, stream>>>(C1O, SCSH, 16);
  k_conv3x3<<<1024, 256, 0, stream>>>(C1O, c2_w, C2O, 16, 32);
  k_bnstats1<<<256, 256, 0, stream>>>(C2O, PARTS, PARTS2, 32);
  k_bnstats2<<<1, 32, 0, stream>>>(PARTS, PARTS2, c2_g, c2_b, SCSH, 32);
  k_bnapply<<<4096, 256, 0, stream>>>(C2O, SCSH, 32);
  k_conv3x3<<<1024, 256, 0, stream>>>(C2O, c3_w, C3O, 32, 32);
  k_bnstats1<<<256, 256, 0, stream>>>(C3O, PARTS, PARTS2, 32);
  k_bnstats2<<<1, 32, 0, stream>>>(PARTS, PARTS2, c3_g, c3_b, SCSH, 32);
  k_bnapply<<<4096, 256, 0, stream>>>(C3O, SCSH, 32);
  k_mapfc<<<512, 256, 0, stream>>>(C3O, map_w, map_b, EMB);
  k_maps<<<32, 64, 0, stream>>>(EMB, m2o_w, m2o_b, m2a_w, m2a_b, OMAP, AMAP);
  {
    dim3 g(100, 32);
    k_xs<<<g, 128, 0, stream>>>(obs_in, act_in, obs_w, obs_b, act_w, act_b,
                                OMAP, AMAP, WO, XS, XO);
  }
  k_xpre2<<<400, 256, 0, stream>>>(XS, WZRT, WNT, XZR, XN);

  // ---- scan over 100 timesteps (2 kernels/step) ----
  double* hb[2] = { H1A, H1B };
  for (int s = 0; s < 100; ++s) {
    const double* hsrc = (s == 0) ? H0 : hb[(s - 1) & 1];
    const int* idxp = (s == 0) ? nullptr : IDX;
    float* pfprev = (s == 0) ? nullptr : (pfout + (size_t)(s - 1) * 12288);
    k_step1<<<512, 512, 0, stream>>>(hsrc, idxp,
        XZR + (size_t)s*32*256, XN + (size_t)s*32*256, XO + (size_t)s*32,
        WZRT, WNT, BZ, BR, BNN, WO, BO, P, H2LW, H2LB,
        hb[s & 1], LOGPDF, pfprev, KEYS, s);
    k_sr<<<32, 1024, 0, stream>>>(LOGPDF, hb[s & 1], KEYS, s, IDX, P,
                                  H2LW, H2LB, yout);
  }
  k_pfend<<<1024, 256, 0, stream>>>(hb[99 & 1], IDX, H2LW, H2LB,
                                    pfout + (size_t)99 * 12288);
}

// Round 8
// 8339.117 us; speedup vs baseline: 1.2115x; 1.2115x over previous
//
#include <hip/hip_runtime.h>
#include <math.h>

typedef double double2v __attribute__((ext_vector_type(2)));

// ===================== JAX Threefry-2x32 (bit-exact) =====================
__device__ __forceinline__ void threefry2x32(unsigned k0, unsigned k1,
                                             unsigned x0, unsigned x1,
                                             unsigned& o0, unsigned& o1)
{
  unsigned ks2 = k0 ^ k1 ^ 0x1BD11BDAu;
  x0 += k0; x1 += k1;
#define TFR(r) { x0 += x1; x1 = (x1 << r) | (x1 >> (32 - r)); x1 ^= x0; }
  TFR(13) TFR(15) TFR(26) TFR(6)
  x0 += k1;  x1 += ks2 + 1u;
  TFR(17) TFR(29) TFR(16) TFR(24)
  x0 += ks2; x1 += k0 + 2u;
  TFR(13) TFR(15) TFR(26) TFR(6)
  x0 += k0;  x1 += k1 + 3u;
  TFR(17) TFR(29) TFR(16) TFR(24)
  x0 += k1;  x1 += ks2 + 4u;
  TFR(13) TFR(15) TFR(26) TFR(6)
  x0 += ks2; x1 += k0 + 5u;
#undef TFR
  o0 = x0; o1 = x1;
}

// jax_threefry_partitionable=True: word e = o0 ^ o1 of block (0, e)
__device__ __forceinline__ unsigned rand_word(unsigned kA, unsigned kB, unsigned e)
{
  unsigned o0, o1;
  threefry2x32(kA, kB, 0u, e, o0, o1);
  return o0 ^ o1;
}

__device__ __forceinline__ float bits_to_unit(unsigned bits)
{
  unsigned u = (bits >> 9) | 0x3f800000u;
  return __uint_as_float(u) - 1.0f;   // exact, in [0,1)
}

// erfinv in double: Giles poly init + 1 Halley iteration on erf()
__device__ __forceinline__ double erfinv_d(double x)
{
  double w = -log((1.0 - x) * (1.0 + x));
  double p;
  if (w < 5.0) {
    w -= 2.5;
    p = 2.81022636e-08;
    p = fma(p, w, 3.43273939e-07);
    p = fma(p, w, -3.5233877e-06);
    p = fma(p, w, -4.39150654e-06);
    p = fma(p, w, 0.00021858087);
    p = fma(p, w, -0.00125372503);
    p = fma(p, w, -0.00417768164);
    p = fma(p, w, 0.246640727);
    p = fma(p, w, 1.50140941);
  } else {
    w = sqrt(w) - 3.0;
    p = -0.000200214257;
    p = fma(p, w, 0.000100950558);
    p = fma(p, w, 0.00134934322);
    p = fma(p, w, -0.00367342844);
    p = fma(p, w, 0.00573950773);
    p = fma(p, w, -0.0076224613);
    p = fma(p, w, 0.00943887047);
    p = fma(p, w, 1.00167406);
    p = fma(p, w, 2.83297682);
  }
  double r = p * x;
  double f  = erf(r) - x;
  double fp = 1.1283791670955126 * exp(-r * r);   // 2/sqrt(pi) e^{-r^2}
  double q  = f / fp;
  return r - q / (1.0 + r * q);
}

// N(0,1) sample e of a jax.random.normal(f32) draw
__device__ __forceinline__ double eps_normal(unsigned kA, unsigned kB, unsigned e)
{
  float f = bits_to_unit(rand_word(kA, kB, e));
  double u = (double)f * (2.0 - 5.9604644775390625e-8)
           - (1.0 - 5.9604644775390625e-8);
  return 1.4142135623730951 * erfinv_d(u);
}

__device__ __forceinline__ double sigd(double x) { return 1.0 / (1.0 + exp(-x)); }

__device__ __forceinline__ double gumbel_d(unsigned kA, unsigned kB, unsigned e)
{
  float f = bits_to_unit(rand_word(kA, kB, e));
  double u = (f == 0.0f) ? 1.1754943508222875e-38 : (double)f;
  return -log(-log(u));
}

// ===================== setup kernels =====================
__global__ void k_keys(unsigned* keys)
{
  if (threadIdx.x != 0 || blockIdx.x != 0) return;
  unsigned a0,a1,b0,b1,c0,c1,d0,d1;
  unsigned kx = 0u, ky = 42u;                 // jax.random.key(42)
  threefry2x32(kx, ky, 0u, 0u, a0, a1);       // carried key
  threefry2x32(kx, ky, 0u, 1u, b0, b1);       // k0 (h0 uniform)
  keys[0] = b0; keys[1] = b1;
  kx = a0; ky = a1;
  for (int s = 0; s < 100; ++s) {
    threefry2x32(kx, ky, 0u, 0u, a0, a1);     // k
    threefry2x32(kx, ky, 0u, 1u, c0, c1);     // ke
    threefry2x32(kx, ky, 0u, 2u, d0, d1);     // kr
    keys[2 + 4*s + 0] = c0; keys[2 + 4*s + 1] = c1;
    keys[2 + 4*s + 2] = d0; keys[2 + 4*s + 3] = d1;
    kx = a0; ky = a1;
  }
}

__global__ __launch_bounds__(256) void k_prep(
    const float* fcz_w, const float* fcz_b, const float* fcr_w, const float* fcr_b,
    const float* fcn_w, const float* fcn_b, const float* fco_w, const float* fco_b,
    const float* h2l_w, const float* h2l_b,
    double* wzrT, double* wnT, double* wo, double* bz, double* br,
    double* bnn, double* bo, double* h2lw, double* h2lb)
{
  int id = blockIdx.x * 256 + threadIdx.x;
  if (id < 65536) {
    int k = id >> 8, j = id & 255;
    wzrT[id] = (double)((j < 128) ? fcz_w[j*256 + k] : fcr_w[(j-128)*256 + k]);
    return;
  }
  id -= 65536;
  if (id < 65536) { int k = id >> 8, j = id & 255; wnT[id] = (double)fcn_w[j*256 + k]; return; }
  id -= 65536;
  if (id < 256) { wo[id] = (double)fco_w[id]; return; }
  id -= 256;
  if (id < 128) { bz[id] = (double)fcz_b[id]; return; }
  id -= 128;
  if (id < 128) { br[id] = (double)fcr_b[id]; return; }
  id -= 128;
  if (id < 256) { bnn[id] = (double)fcn_b[id]; return; }
  id -= 256;
  if (id < 1) { bo[0] = (double)fco_b[0]; return; }
  id -= 1;
  if (id < 384) { h2lw[id] = (double)h2l_w[id]; return; }
  id -= 384;
  if (id < 3) { h2lb[id] = (double)h2l_b[id]; return; }
}

__global__ __launch_bounds__(256) void k_h0(const unsigned* keys, double* h, double* p)
{
  unsigned e = blockIdx.x * 256 + threadIdx.x;    // < 524288
  h[e] = (double)bits_to_unit(rand_word(keys[0], keys[1], e));
  if (e < 4096) p[e] = (double)(float)log(1.0 / 128.0);
}

// ===================== frontend (map CNN encoder) =====================
__global__ __launch_bounds__(256) void k_conv1(const float* in, const float* w, double* out)
{
  int bc = blockIdx.x; int b = bc >> 4, co = bc & 15;
  __shared__ double wl[25];
  __shared__ float plf[4096];
  if (threadIdx.x < 25) wl[threadIdx.x] = (double)w[co*25 + threadIdx.x];
  const float* ib = in + (size_t)b * 4096;
  for (int j = 0; j < 16; ++j) plf[threadIdx.x + j*256] = ib[threadIdx.x + j*256];
  __syncthreads();
  for (int q = 0; q < 4; ++q) {
    int px = q*256 + threadIdx.x;
    int oh = px >> 5, ow = px & 31;
    double acc = 0.0;
    for (int kh = 0; kh < 5; ++kh) {
      int ih = oh*2 - 2 + kh; if (ih < 0 || ih >= 64) continue;
      for (int kw = 0; kw < 5; ++kw) {
        int iw = ow*2 - 2 + kw; if (iw < 0 || iw >= 64) continue;
        acc = fma((double)plf[ih*64 + iw], wl[kh*5 + kw], acc);
      }
    }
    out[((size_t)b*16 + co)*1024 + px] = fmax(acc, 0.0);
  }
}

__global__ __launch_bounds__(256) void k_conv3x3(const double* in, const float* w,
                                                 double* out, int Ci, int Co)
{
  int bc = blockIdx.x; int b = bc / Co, co = bc % Co;
  __shared__ double wl[288];
  __shared__ double pl[2][1024];
  for (int e = threadIdx.x; e < Ci*9; e += 256) wl[e] = (double)w[co*Ci*9 + e];
  double acc[4] = {0.0, 0.0, 0.0, 0.0};
  const double* ib = in + (size_t)b * Ci * 1024;
  for (int q = 0; q < 4; ++q)
    pl[0][threadIdx.x + q*256] = ib[threadIdx.x + q*256];
  __syncthreads();
  for (int ci = 0; ci < Ci; ++ci) {
    int cur = ci & 1;
    if (ci + 1 < Ci) {
      for (int q = 0; q < 4; ++q)
        pl[cur ^ 1][threadIdx.x + q*256] = ib[(ci + 1)*1024 + threadIdx.x + q*256];
    }
    const double* wp = wl + ci*9;
    for (int q = 0; q < 4; ++q) {
      int px = q*256 + threadIdx.x;
      int oh = px >> 5, ow = px & 31;
      double a = acc[q];
      for (int kh = 0; kh < 3; ++kh) {
        int ih = oh - 1 + kh; if (ih < 0 || ih >= 32) continue;
        for (int kw = 0; kw < 3; ++kw) {
          int iw = ow - 1 + kw; if (iw < 0 || iw >= 32) continue;
          a = fma(pl[cur][ih*32 + iw], wp[kh*3 + kw], a);
        }
      }
      acc[q] = a;
    }
    __syncthreads();
  }
  for (int q = 0; q < 4; ++q) {
    int px = q*256 + threadIdx.x;
    out[((size_t)b*Co + co)*1024 + px] = fmax(acc[q], 0.0);
  }
}

__global__ __launch_bounds__(256) void k_bnstats1(const double* __restrict__ x,
    double* __restrict__ partS, double* __restrict__ partS2, int C)
{
  int c = blockIdx.x >> 3, chunk = blockIdx.x & 7;
  double s = 0.0, s2 = 0.0;
  for (int e = threadIdx.x; e < 4096; e += 256) {
    int b = chunk*4 + (e >> 10), px = e & 1023;
    double v = x[((size_t)b*C + c)*1024 + px];
    s += v; s2 = fma(v, v, s2);
  }
  __shared__ double rs[256], rs2[256];
  rs[threadIdx.x] = s; rs2[threadIdx.x] = s2;
  __syncthreads();
  for (int d = 128; d; d >>= 1) {
    if (threadIdx.x < d) { rs[threadIdx.x] += rs[threadIdx.x + d]; rs2[threadIdx.x] += rs2[threadIdx.x + d]; }
    __syncthreads();
  }
  if (threadIdx.x == 0) { partS[blockIdx.x] = rs[0]; partS2[blockIdx.x] = rs2[0]; }
}

__global__ void k_bnstats2(const double* __restrict__ partS,
                           const double* __restrict__ partS2,
                           const float* g, const float* bta, double* scsh, int C)
{
  int c = threadIdx.x;
  if (c >= C) return;
  double s = 0.0, s2 = 0.0;
  for (int j = 0; j < 8; ++j) { s += partS[c*8 + j]; s2 += partS2[c*8 + j]; }
  double n = 32768.0;
  double mean = s / n;
  double var = s2 / n - mean*mean;
  double sc = (double)g[c] / sqrt(var + 1e-5);
  scsh[c*2] = sc;
  scsh[c*2 + 1] = (double)bta[c] - mean * sc;
}

__global__ __launch_bounds__(256) void k_bnapply(double* x, const double* scsh, int C)
{
  size_t e = (size_t)blockIdx.x * 256 + threadIdx.x;
  int c = (int)((e >> 10) % (size_t)C);
  x[e] = fma(x[e], scsh[c*2], scsh[c*2 + 1]);
}

__global__ __launch_bounds__(256) void k_mapfc(const double* x, const float* w,
                                               const float* bias, double* emb)
{
  int blk = blockIdx.x; int b = blk >> 4, jg = blk & 15;
  double acc[8];
  #pragma unroll
  for (int jj = 0; jj < 8; ++jj) acc[jj] = 0.0;
  const double* xb = x + (size_t)b * 32768;
  for (int e = threadIdx.x; e < 32768; e += 256) {
    double xv = xb[e];
    #pragma unroll
    for (int jj = 0; jj < 8; ++jj)
      acc[jj] = fma(xv, (double)w[(size_t)(jg*8 + jj)*32768 + e], acc[jj]);
  }
  __shared__ double red[8][256];
  #pragma unroll
  for (int jj = 0; jj < 8; ++jj) red[jj][threadIdx.x] = acc[jj];
  __syncthreads();
  for (int d = 128; d; d >>= 1) {
    if (threadIdx.x < d)
      #pragma unroll
      for (int jj = 0; jj < 8; ++jj) red[jj][threadIdx.x] += red[jj][threadIdx.x + d];
    __syncthreads();
  }
  if (threadIdx.x < 8) {
    int j = jg*8 + threadIdx.x;
    emb[b*128 + j] = fmax(red[threadIdx.x][0] + (double)bias[j], 0.0);
  }
}

__global__ void k_maps(const double* emb, const float* m2o_w, const float* m2o_b,
                       const float* m2a_w, const float* m2a_b,
                       double* omap, double* amap)
{
  int b = blockIdx.x, j = threadIdx.x;   // 64 threads
  double a1 = (double)m2o_b[j], a2 = (double)m2a_b[j];
  for (int k = 0; k < 128; ++k) {
    double ev = emb[b*128 + k];
    a1 = fma(ev, (double)m2o_w[j*128 + k], a1);
    a2 = fma(ev, (double)m2a_w[j*128 + k], a2);
  }
  omap[b*64 + j] = fmax(a1, 0.0);
  amap[b*64 + j] = fmax(a2, 0.0);
}

__global__ __launch_bounds__(128) void k_xs(const float* obs_in, const float* act_in,
                                            const float* obs_w, const float* obs_b,
                                            const float* act_w, const float* act_b,
                                            const double* omap, const double* amap,
                                            const double* wo,
                                            double* xs, double* xo)
{
  int s = blockIdx.x, b = blockIdx.y, j = threadIdx.x;
  double v;
  if (j < 64) {
    double a = (double)obs_b[j];
    const float* o = obs_in + ((size_t)b*100 + s)*16;
    for (int k = 0; k < 16; ++k) a = fma((double)o[k], (double)obs_w[j*16 + k], a);
    v = fmax(a, 0.0) * omap[b*64 + j];
  } else {
    int j2 = j - 64;
    double a = (double)act_b[j2];
    const float* o = act_in + ((size_t)b*100 + s)*3;
    for (int k = 0; k < 3; ++k) a = fma((double)o[k], (double)act_w[j2*3 + k], a);
    v = fmax(a, 0.0) * amap[b*64 + j2];
  }
  xs[((size_t)s*32 + b)*128 + j] = v;
  __shared__ double red[128];
  red[j] = v * wo[128 + j];
  __syncthreads();
  for (int d = 64; d; d >>= 1) {
    if (j < d) red[j] += red[j + d];
    __syncthreads();
  }
  if (j == 0) xo[s*32 + b] = red[0];
}

__global__ __launch_bounds__(256, 2) void k_xpre2(const double* __restrict__ xs,
    const double* __restrict__ wzrT, const double* __restrict__ wnT,
    double* __restrict__ xzr, double* __restrict__ xn)
{
  int s = blockIdx.x >> 2, bg = blockIdx.x & 3;
  __shared__ double xl[8][128];
  int t = threadIdx.x;
  #pragma unroll
  for (int j = 0; j < 4; ++j) {
    int e = t + j*256;
    int i = e >> 7, cc = e & 127;
    xl[i][cc] = xs[((size_t)s*32 + bg*8 + i)*128 + cc];
  }
  __syncthreads();
  double az[8], an[8];
  #pragma unroll
  for (int i = 0; i < 8; ++i) { az[i] = 0.0; an[i] = 0.0; }
  for (int k = 0; k < 128; ++k) {
    double wz = wzrT[k*256 + t];
    double wn = wnT[(128 + k)*256 + t];
    #pragma unroll
    for (int i = 0; i < 8; ++i) {
      double xv = xl[i][k];
      az[i] = fma(xv, wz, az[i]);
      an[i] = fma(xv, wn, an[i]);
    }
  }
  #pragma unroll
  for (int i = 0; i < 8; ++i) {
    size_t sb = (size_t)s*32 + bg*8 + i;
    xzr[sb*256 + t] = az[i];
    xn [sb*256 + t] = an[i];
  }
}

// ===================== fused scan kernels =====================
// k_step1: 512 blocks x 512 threads; 8 rows/block.
// thread = (rq = t>>7 -> rows rq*2, rq*2+1; c2 = t&127 -> cols c2, c2+128).
// Blocks 0..31 first run phase C of step s-1 (pn normalize + y), overlapped.
__global__ __launch_bounds__(512, 4) void k_step1(
    const double* __restrict__ hsrc, const int* __restrict__ idxp,
    const double* __restrict__ xzr, const double* __restrict__ xn,
    const double* __restrict__ xo,
    const double* __restrict__ wzrT, const double* __restrict__ wnT,
    const double* __restrict__ bz, const double* __restrict__ br,
    const double* __restrict__ bnn, const double* __restrict__ wo,
    const double* __restrict__ bo, double* __restrict__ P,
    const double* __restrict__ h2lw, const double* __restrict__ h2lb,
    double* __restrict__ h1out, double* __restrict__ LP,
    const double* __restrict__ PNPRE,
    float* __restrict__ pfout, float* __restrict__ yout,
    const unsigned* __restrict__ keys, int s)
{
  __shared__ double ah[8][128];    // gathered h
  __shared__ double aw[8][128];    // rg*h, later h1
  __shared__ double wsh[128], ys[128], red8[8][128];
  __shared__ int    isx[128];
  __shared__ double smx[2], ssx[2];
  const int t  = threadIdx.x;
  const int rq = t >> 7;           // 0..3: rows rq*2, rq*2+1
  const int c2 = t & 127;          // cols c2, c2+128
  const int r0 = blockIdx.x * 8;
  const int wv = t >> 6, lane = t & 63;
  const bool first = (idxp == nullptr);

  // ---- phase C of step s-1 (blocks 0..31): pn normalize + y ----
  if (!first && blockIdx.x < 32) {
    int b = blockIdx.x;
    if (t < 128) {
      double q = PNPRE[b*128 + t];
      double m = q;
      for (int d = 32; d; d >>= 1) m = fmax(m, __shfl_xor(m, d, 64));
      if ((t & 63) == 0) smx[t >> 6] = m;
    }
    __syncthreads();
    if (t < 128) {
      double q = PNPRE[b*128 + t];
      double m = fmax(smx[0], smx[1]);
      double e = exp(q - m), su = e;
      for (int d = 32; d; d >>= 1) su += __shfl_xor(su, d, 64);
      if ((t & 63) == 0) ssx[t >> 6] = su;
    }
    __syncthreads();
    if (t < 128) {
      double q = PNPRE[b*128 + t];
      double m = fmax(smx[0], smx[1]);
      double pn = q - (m + log(ssx[0] + ssx[1]));
      P[b*128 + t] = pn;
      wsh[t] = exp(pn);
      isx[t] = idxp[t*32 + b];
    }
    __syncthreads();
    {
      #pragma unroll
      for (int colh = 0; colh < 2; ++colh) {
        int col = lane + colh*64;
        double acc = 0.0;
        for (int q = 0; q < 16; ++q) {
          int ii = wv*16 + q;
          acc = fma(wsh[ii], hsrc[(size_t)(isx[ii]*32 + b)*128 + col], acc);
        }
        red8[wv][col] = acc;
      }
    }
    __syncthreads();
    if (t < 128) {
      double a = red8[0][t];
      for (int gg = 1; gg < 8; ++gg) a += red8[gg][t];
      ys[t] = a;
    }
    __syncthreads();
    if (t < 3) {
      double dsum = h2lb[t];
      for (int cc = 0; cc < 128; ++cc)
        dsum = fma(h2lw[t*128 + cc], ys[cc], dsum);
      yout[(s - 1)*96 + b*3 + t] = (float)(1.0 / (1.0 + exp(-dsum)));
    }
    __syncthreads();
  }

  // ---- gather prev h (2 elements/thread, coalesced) ----
  #pragma unroll
  for (int j = 0; j < 2; ++j) {
    int e = t + j*512;
    int r = e >> 7, cc = e & 127;
    int R = r0 + r, b = R & 31;
    int src = first ? R : (idxp[R]*32 + b);
    ah[r][cc] = hsrc[(size_t)src*128 + cc];
  }
  __syncthreads();
  // ---- pf for previous step: 8 waves x 1 row ----
  if (pfout != nullptr) {
    double v0 = ah[wv][lane*2], v1 = ah[wv][lane*2 + 1];
    double s0 = fma(v0, h2lw[lane*2],       v1 * h2lw[lane*2 + 1]);
    double s1 = fma(v0, h2lw[128 + lane*2], v1 * h2lw[128 + lane*2 + 1]);
    double s2 = fma(v0, h2lw[256 + lane*2], v1 * h2lw[256 + lane*2 + 1]);
    for (int d = 32; d; d >>= 1) {
      s0 += __shfl_xor(s0, d, 64);
      s1 += __shfl_xor(s1, d, 64);
      s2 += __shfl_xor(s2, d, 64);
    }
    if (lane == 0) {
      float* o = pfout + (r0 + wv) * 3;
      o[0] = (float)(1.0 / (1.0 + exp(-(s0 + h2lb[0]))));
      o[1] = (float)(1.0 / (1.0 + exp(-(s1 + h2lb[1]))));
      o[2] = (float)(1.0 / (1.0 + exp(-(s2 + h2lb[2]))));
    }
  }
  // ---- GEMM1: h-part of [x|h] @ Wzr^T; 2 rows x 2 cols/thread ----
  double a00 = 0.0, a01 = 0.0, a10 = 0.0, a11 = 0.0;   // [row i][col j]
  {
    const double2v* ap0 = (const double2v*)&ah[rq*2 + 0][0];
    const double2v* ap1 = (const double2v*)&ah[rq*2 + 1][0];
    for (int k2 = 0; k2 < 64; ++k2) {
      const double* wr0 = &wzrT[(128 + 2*k2)*256];
      const double* wr1 = &wzrT[(128 + 2*k2 + 1)*256];
      double w00 = wr0[c2],       w01 = wr1[c2];
      double w10 = wr0[c2 + 128], w11 = wr1[c2 + 128];
      double2v A0 = ap0[k2], A1 = ap1[k2];
      a00 = fma(A0.y, w01, fma(A0.x, w00, a00));
      a01 = fma(A0.y, w11, fma(A0.x, w10, a01));
      a10 = fma(A1.y, w01, fma(A1.x, w00, a10));
      a11 = fma(A1.y, w11, fma(A1.x, w10, a11));
    }
  }
  double zr[2];
  {
    double bzv = bz[c2], brv = br[c2];
    double az[2] = { a00, a10 }, ar[2] = { a01, a11 };
    #pragma unroll
    for (int i = 0; i < 2; ++i) {
      int row = rq*2 + i;
      int b = (r0 + row) & 31;
      zr[i] = sigd(az[i] + xzr[b*256 + c2] + bzv);
      double rgv = sigd(ar[i] + xzr[b*256 + c2 + 128] + brv);
      aw[row][c2] = rgv * ah[row][c2];
    }
  }
  __syncthreads();
  // ---- GEMM2: (rg*h)-part of [rg*h|x] @ Wn^T ----
  a00 = 0.0; a01 = 0.0; a10 = 0.0; a11 = 0.0;
  {
    const double2v* ap0 = (const double2v*)&aw[rq*2 + 0][0];
    const double2v* ap1 = (const double2v*)&aw[rq*2 + 1][0];
    for (int k2 = 0; k2 < 64; ++k2) {
      const double* wr0 = &wnT[(2*k2)*256];
      const double* wr1 = &wnT[(2*k2 + 1)*256];
      double w00 = wr0[c2],       w01 = wr1[c2];
      double w10 = wr0[c2 + 128], w11 = wr1[c2 + 128];
      double2v A0 = ap0[k2], A1 = ap1[k2];
      a00 = fma(A0.y, w01, fma(A0.x, w00, a00));
      a01 = fma(A0.y, w11, fma(A0.x, w10, a01));
      a10 = fma(A1.y, w01, fma(A1.x, w00, a10));
      a11 = fma(A1.y, w11, fma(A1.x, w10, a11));
    }
  }
  // mu / softplus(var) / eps / h1 — all thread-local now
  double hv[2];
  {
    unsigned keA = keys[2 + 4*s], keB = keys[2 + 4*s + 1];
    double bn0 = bnn[c2], bn1 = bnn[c2 + 128];
    double am[2] = { a00, a10 }, av[2] = { a01, a11 };
    #pragma unroll
    for (int i = 0; i < 2; ++i) {
      int row = rq*2 + i, R = r0 + row;
      int b = R & 31;
      double mu  = am[i] + xn[b*256 + c2] + bn0;
      double var = av[i] + xn[b*256 + c2 + 128] + bn1;
      double sp = fmax(var, 0.0) + log1p(exp(-fabs(var)));
      double ep = eps_normal(keA, keB, (unsigned)(R*128 + c2));
      double n  = fma(ep, sp, mu);
      hv[i] = (1.0 - zr[i])*n + zr[i]*ah[row][c2];
      h1out[(size_t)R*128 + c2] = hv[i];
    }
  }
  __syncthreads();   // all GEMM2 aw reads complete
  #pragma unroll
  for (int i = 0; i < 2; ++i) aw[rq*2 + i][c2] = hv[i];
  __syncthreads();
  // ---- logpdf partial (without +p): 8 waves x 1 row ----
  {
    int R = r0 + wv, b = R & 31;
    double part = fma(aw[wv][lane], wo[lane], aw[wv][lane + 64] * wo[lane + 64]);
    for (int d = 32; d; d >>= 1) part += __shfl_xor(part, d, 64);
    if (lane == 0) LP[b*128 + (R >> 5)] = part + xo[b] + bo[0];
  }
}

// k_sr: barrier-free per-wave softmax + Gumbel-argmax.  512 blocks x 512
// threads; wave wv handles row rw = blockIdx*8 + wv.
__global__ __launch_bounds__(512, 4) void k_sr(
    const double* __restrict__ LP, const double* __restrict__ P,
    const unsigned* __restrict__ keys, int s,
    int* __restrict__ idx, double* __restrict__ PNPRE)
{
  int t = threadIdx.x;
  int wv = t >> 6, lane = t & 63;
  int rw = blockIdx.x * 8 + wv;
  int bw = rw & 31;
  unsigned kA = keys[2 + 4*s + 2], kB = keys[2 + 4*s + 3];
  double v0 = LP[bw*128 + lane]      + P[bw*128 + lane];
  double v1 = LP[bw*128 + lane + 64] + P[bw*128 + lane + 64];
  double m0 = v0, m1 = v1;
  for (int d = 32; d; d >>= 1) {
    m0 = fmax(m0, __shfl_xor(m0, d, 64));
    m1 = fmax(m1, __shfl_xor(m1, d, 64));
  }
  double m = fmax(m0, m1);
  double e0 = exp(v0 - m), e1 = exp(v1 - m);
  double s0 = e0, s1 = e1;
  for (int d = 32; d; d >>= 1) {
    s0 += __shfl_xor(s0, d, 64);
    s1 += __shfl_xor(s1, d, 64);
  }
  double lse = log(s0 + s1);
  double p1_0 = v0 - m - lse;
  double p1_1 = v1 - m - lse;
  double lg0 = log(0.5*exp(p1_0) + 0.00390625);
  double lg1 = log(0.5*exp(p1_1) + 0.00390625);
  double g0 = gumbel_d(kA, kB, (unsigned)(rw*128 + lane)) + lg0;
  double g1 = gumbel_d(kA, kB, (unsigned)(rw*128 + lane + 64)) + lg1;
  double val; int bj;
  if (g0 >= g1) { val = g0; bj = lane; } else { val = g1; bj = lane + 64; }
  for (int d = 32; d; d >>= 1) {
    double ov = __shfl_xor(val, d, 64);
    int    oj = __shfl_xor(bj, d, 64);
    if (ov > val || (ov == val && oj < bj)) { val = ov; bj = oj; }
  }
  double pl = __shfl(p1_0, bj & 63, 64);
  double ph = __shfl(p1_1, bj & 63, 64);
  if (lane == 0) {
    idx[rw] = bj;
    double p1b = (bj < 64) ? pl : ph;
    double pe = exp(p1b);
    PNPRE[bw*128 + (rw >> 5)] = log(pe / (0.5*pe + 0.00390625));
  }
}

// k_yfinal: phase C for step 99 (32 blocks x 512)
__global__ __launch_bounds__(512) void k_yfinal(
    const double* __restrict__ hlast, const int* __restrict__ idxp,
    const double* __restrict__ PNPRE, double* __restrict__ P,
    const double* __restrict__ h2lw, const double* __restrict__ h2lb,
    float* __restrict__ yout)
{
  __shared__ double wsh[128], ys[128], red8[8][128];
  __shared__ int    isx[128];
  __shared__ double smx[2], ssx[2];
  int t = threadIdx.x, b = blockIdx.x;
  int wv = t >> 6, lane = t & 63;
  if (t < 128) {
    double q = PNPRE[b*128 + t];
    double m = q;
    for (int d = 32; d; d >>= 1) m = fmax(m, __shfl_xor(m, d, 64));
    if ((t & 63) == 0) smx[t >> 6] = m;
  }
  __syncthreads();
  if (t < 128) {
    double q = PNPRE[b*128 + t];
    double m = fmax(smx[0], smx[1]);
    double e = exp(q - m), su = e;
    for (int d = 32; d; d >>= 1) su += __shfl_xor(su, d, 64);
    if ((t & 63) == 0) ssx[t >> 6] = su;
  }
  __syncthreads();
  if (t < 128) {
    double q = PNPRE[b*128 + t];
    double m = fmax(smx[0], smx[1]);
    double pn = q - (m + log(ssx[0] + ssx[1]));
    P[b*128 + t] = pn;
    wsh[t] = exp(pn);
    isx[t] = idxp[t*32 + b];
  }
  __syncthreads();
  #pragma unroll
  for (int colh = 0; colh < 2; ++colh) {
    int col = lane + colh*64;
    double acc = 0.0;
    for (int q = 0; q < 16; ++q) {
      int ii = wv*16 + q;
      acc = fma(wsh[ii], hlast[(size_t)(isx[ii]*32 + b)*128 + col], acc);
    }
    red8[wv][col] = acc;
  }
  __syncthreads();
  if (t < 128) {
    double a = red8[0][t];
    for (int gg = 1; gg < 8; ++gg) a += red8[gg][t];
    ys[t] = a;
  }
  __syncthreads();
  if (t < 3) {
    double dsum = h2lb[t];
    for (int cc = 0; cc < 128; ++cc)
      dsum = fma(h2lw[t*128 + cc], ys[cc], dsum);
    yout[99*96 + b*3 + t] = (float)(1.0 / (1.0 + exp(-dsum)));
  }
}

// epilogue: pf for the last step (gather via idx)
__global__ __launch_bounds__(256) void k_pfend(const double* __restrict__ h1,
    const int* __restrict__ idx, const double* __restrict__ h2lw,
    const double* __restrict__ h2lb, float* __restrict__ pfout)
{
  int wv = threadIdx.x >> 6, lane = threadIdx.x & 63;
  int r = blockIdx.x * 4 + wv;
  int b = r & 31;
  const double* hr = h1 + (size_t)(idx[r]*32 + b) * 128;
  double v0 = hr[lane*2], v1 = hr[lane*2 + 1];
  double s0 = fma(v0, h2lw[lane*2],       v1 * h2lw[lane*2 + 1]);
  double s1 = fma(v0, h2lw[128 + lane*2], v1 * h2lw[128 + lane*2 + 1]);
  double s2 = fma(v0, h2lw[256 + lane*2], v1 * h2lw[256 + lane*2 + 1]);
  for (int d = 32; d; d >>= 1) {
    s0 += __shfl_xor(s0, d, 64);
    s1 += __shfl_xor(s1, d, 64);
    s2 += __shfl_xor(s2, d, 64);
  }
  if (lane == 0) {
    float* o = pfout + r * 3;
    o[0] = (float)(1.0 / (1.0 + exp(-(s0 + h2lb[0]))));
    o[1] = (float)(1.0 / (1.0 + exp(-(s1 + h2lb[1]))));
    o[2] = (float)(1.0 / (1.0 + exp(-(s2 + h2lb[2]))));
  }
}

// ===================== host launch =====================
extern "C" void kernel_launch(void* const* d_in, const int* in_sizes, int n_in,
                              void* d_out, int out_size, void* d_ws, size_t ws_size,
                              hipStream_t stream)
{
  (void)in_sizes; (void)n_in; (void)out_size; (void)ws_size;
  const float* map_in = (const float*)d_in[0];
  const float* obs_in = (const float*)d_in[1];
  const float* act_in = (const float*)d_in[2];
  const float* c1_w = (const float*)d_in[3];
  const float* c1_g = (const float*)d_in[4];
  const float* c1_b = (const float*)d_in[5];
  const float* c2_w = (const float*)d_in[6];
  const float* c2_g = (const float*)d_in[7];
  const float* c2_b = (const float*)d_in[8];
  const float* c3_w = (const float*)d_in[9];
  const float* c3_g = (const float*)d_in[10];
  const float* c3_b = (const float*)d_in[11];
  const float* map_w = (const float*)d_in[12];
  const float* map_b = (const float*)d_in[13];
  const float* m2o_w = (const float*)d_in[14];
  const float* m2o_b = (const float*)d_in[15];
  const float* m2a_w = (const float*)d_in[16];
  const float* m2a_b = (const float*)d_in[17];
  const float* obs_w = (const float*)d_in[18];
  const float* obs_b = (const float*)d_in[19];
  const float* act_w = (const float*)d_in[20];
  const float* act_b = (const float*)d_in[21];
  const float* fcz_w = (const float*)d_in[22];
  const float* fcz_b = (const float*)d_in[23];
  const float* fcr_w = (const float*)d_in[24];
  const float* fcr_b = (const float*)d_in[25];
  const float* fcn_w = (const float*)d_in[26];
  const float* fcn_b = (const float*)d_in[27];
  const float* fco_w = (const float*)d_in[28];
  const float* fco_b = (const float*)d_in[29];
  const float* h2l_w = (const float*)d_in[30];
  const float* h2l_b = (const float*)d_in[31];

  float* yout  = (float*)d_out;
  float* pfout = (float*)d_out + 9600;

  char* ws = (char*)d_ws;
  double*   H0     = (double*)(ws + 0);           // 4096*128
  double*   H1A    = (double*)(ws + 4194304);
  double*   H1B    = (double*)(ws + 8388608);
  double*   XS     = (double*)(ws + 12582912);    // 100*32*128
  double*   C1O    = (double*)(ws + 15859712);    // 32*16*1024
  double*   C2O    = (double*)(ws + 20054016);    // 32*32*1024
  double*   C3O    = (double*)(ws + 28442624);    // 32*32*1024
  double*   XZR    = (double*)(ws + 15859712);    // 100*32*256 (overlay)
  double*   XN     = (double*)(ws + 22413312);    // 100*32*256 (overlay)
  double*   XO     = (double*)(ws + 28966912);    // 100*32     (overlay)
  double*   WZRT   = (double*)(ws + 36831232);    // 256*256
  double*   WNT    = (double*)(ws + 37355520);
  double*   WO     = (double*)(ws + 37879808);
  double*   BZ     = (double*)(ws + 37881856);
  double*   BR     = (double*)(ws + 37882880);
  double*   BNN    = (double*)(ws + 37883904);
  double*   BO     = (double*)(ws + 37885952);
  double*   H2LW   = (double*)(ws + 37886208);
  double*   H2LB   = (double*)(ws + 37889280);
  double*   EMB    = (double*)(ws + 37889536);    // 32*128
  double*   OMAP   = (double*)(ws + 37922304);    // 32*64
  double*   AMAP   = (double*)(ws + 37938688);
  double*   P      = (double*)(ws + 37955072);    // 4096  [b][p]
  double*   LP     = (double*)(ws + 37987840);    // 4096  [b][p]
  int*      IDX    = (int*)   (ws + 38020608);    // 4096  [p*32+b]
  unsigned* KEYS   = (unsigned*)(ws + 38036992);  // 402
  double*   SCSH   = (double*)(ws + 38039040);    // 32*2
  double*   PARTS  = (double*)(ws + 38039552);    // 256
  double*   PARTS2 = (double*)(ws + 38041600);    // 256
  double*   PNPRE  = (double*)(ws + 38043648);    // 4096  [b][p]

  // ---- setup ----
  k_keys<<<1, 64, 0, stream>>>(KEYS);
  k_prep<<<517, 256, 0, stream>>>(fcz_w, fcz_b, fcr_w, fcr_b, fcn_w, fcn_b,
                                  fco_w, fco_b, h2l_w, h2l_b,
                                  WZRT, WNT, WO, BZ, BR, BNN, BO, H2LW, H2LB);
  k_h0<<<2048, 256, 0, stream>>>(KEYS, H0, P);

  // ---- frontend ----
  k_conv1<<<512, 256, 0, stream>>>(map_in, c1_w, C1O);
  k_bnstats1<<<128, 256, 0, stream>>>(C1O, PARTS, PARTS2, 16);
  k_bnstats2<<<1, 32, 0, stream>>>(PARTS, PARTS2, c1_g, c1_b, SCSH, 16);
  k_bnapply<<<2048, 256, 0, stream>>>(C1O, SCSH, 16);
  k_conv3x3<<<1024, 256, 0, stream>>>(C1O, c2_w, C2O, 16, 32);
  k_bnstats1<<<256, 256, 0, stream>>>(C2O, PARTS, PARTS2, 32);
  k_bnstats2<<<1, 32, 0, stream>>>(PARTS, PARTS2, c2_g, c2_b, SCSH, 32);
  k_bnapply<<<4096, 256, 0, stream>>>(C2O, SCSH, 32);
  k_conv3x3<<<1024, 256, 0, stream>>>(C2O, c3_w, C3O, 32, 32);
  k_bnstats1<<<256, 256, 0, stream>>>(C3O, PARTS, PARTS2, 32);
  k_bnstats2<<<1, 32, 0, stream>>>(PARTS, PARTS2, c3_g, c3_b, SCSH, 32);
  k_bnapply<<<4096, 256, 0, stream>>>(C3O, SCSH, 32);
  k_mapfc<<<512, 256, 0, stream>>>(C3O, map_w, map_b, EMB);
  k_maps<<<32, 64, 0, stream>>>(EMB, m2o_w, m2o_b, m2a_w, m2a_b, OMAP, AMAP);
  {
    dim3 g(100, 32);
    k_xs<<<g, 128, 0, stream>>>(obs_in, act_in, obs_w, obs_b, act_w, act_b,
                                OMAP, AMAP, WO, XS, XO);
  }
  k_xpre2<<<400, 256, 0, stream>>>(XS, WZRT, WNT, XZR, XN);

  // ---- scan over 100 timesteps (2 kernels/step) ----
  double* hb[2] = { H1A, H1B };
  for (int s = 0; s < 100; ++s) {
    const double* hsrc = (s == 0) ? H0 : hb[(s - 1) & 1];
    const int* idxp = (s == 0) ? nullptr : IDX;
    float* pfprev = (s == 0) ? nullptr : (pfout + (size_t)(s - 1) * 12288);
    k_step1<<<512, 512, 0, stream>>>(hsrc, idxp,
        XZR + (size_t)s*32*256, XN + (size_t)s*32*256, XO + (size_t)s*32,
        WZRT, WNT, BZ, BR, BNN, WO, BO, P, H2LW, H2LB,
        hb[s & 1], LP, PNPRE, pfprev, yout, KEYS, s);
    k_sr<<<512, 512, 0, stream>>>(LP, P, KEYS, s, IDX, PNPRE);
  }
  k_yfinal<<<32, 512, 0, stream>>>(hb[1], IDX, PNPRE, P, H2LW, H2LB, yout);
  k_pfend<<<1024, 256, 0, stream>>>(hb[1], IDX, H2LW, H2LB,
                                    pfout + (size_t)99 * 12288);
}

// Round 9
// 6338.728 us; speedup vs baseline: 1.5939x; 1.3156x over previous
//
#include <hip/hip_runtime.h>
#include <math.h>

typedef double double2v __attribute__((ext_vector_type(2)));

// ===================== JAX Threefry-2x32 (bit-exact) =====================
__device__ __forceinline__ void threefry2x32(unsigned k0, unsigned k1,
                                             unsigned x0, unsigned x1,
                                             unsigned& o0, unsigned& o1)
{
  unsigned ks2 = k0 ^ k1 ^ 0x1BD11BDAu;
  x0 += k0; x1 += k1;
#define TFR(r) { x0 += x1; x1 = (x1 << r) | (x1 >> (32 - r)); x1 ^= x0; }
  TFR(13) TFR(15) TFR(26) TFR(6)
  x0 += k1;  x1 += ks2 + 1u;
  TFR(17) TFR(29) TFR(16) TFR(24)
  x0 += ks2; x1 += k0 + 2u;
  TFR(13) TFR(15) TFR(26) TFR(6)
  x0 += k0;  x1 += k1 + 3u;
  TFR(17) TFR(29) TFR(16) TFR(24)
  x0 += k1;  x1 += ks2 + 4u;
  TFR(13) TFR(15) TFR(26) TFR(6)
  x0 += ks2; x1 += k0 + 5u;
#undef TFR
  o0 = x0; o1 = x1;
}

// jax_threefry_partitionable=True: word e = o0 ^ o1 of block (0, e)
__device__ __forceinline__ unsigned rand_word(unsigned kA, unsigned kB, unsigned e)
{
  unsigned o0, o1;
  threefry2x32(kA, kB, 0u, e, o0, o1);
  return o0 ^ o1;
}

__device__ __forceinline__ float bits_to_unit(unsigned bits)
{
  unsigned u = (bits >> 9) | 0x3f800000u;
  return __uint_as_float(u) - 1.0f;   // exact, in [0,1)
}

// erfinv in double: Giles poly init + 1 Halley iteration on erf()
__device__ __forceinline__ double erfinv_d(double x)
{
  double w = -log((1.0 - x) * (1.0 + x));
  double p;
  if (w < 5.0) {
    w -= 2.5;
    p = 2.81022636e-08;
    p = fma(p, w, 3.43273939e-07);
    p = fma(p, w, -3.5233877e-06);
    p = fma(p, w, -4.39150654e-06);
    p = fma(p, w, 0.00021858087);
    p = fma(p, w, -0.00125372503);
    p = fma(p, w, -0.00417768164);
    p = fma(p, w, 0.246640727);
    p = fma(p, w, 1.50140941);
  } else {
    w = sqrt(w) - 3.0;
    p = -0.000200214257;
    p = fma(p, w, 0.000100950558);
    p = fma(p, w, 0.00134934322);
    p = fma(p, w, -0.00367342844);
    p = fma(p, w, 0.00573950773);
    p = fma(p, w, -0.0076224613);
    p = fma(p, w, 0.00943887047);
    p = fma(p, w, 1.00167406);
    p = fma(p, w, 2.83297682);
  }
  double r = p * x;
  double f  = erf(r) - x;
  double fp = 1.1283791670955126 * exp(-r * r);   // 2/sqrt(pi) e^{-r^2}
  double q  = f / fp;
  return r - q / (1.0 + r * q);
}

// N(0,1) sample e of a jax.random.normal(f32) draw
__device__ __forceinline__ double eps_normal(unsigned kA, unsigned kB, unsigned e)
{
  float f = bits_to_unit(rand_word(kA, kB, e));
  double u = (double)f * (2.0 - 5.9604644775390625e-8)
           - (1.0 - 5.9604644775390625e-8);
  return 1.4142135623730951 * erfinv_d(u);
}

__device__ __forceinline__ double sigd(double x) { return 1.0 / (1.0 + exp(-x)); }

__device__ __forceinline__ double gumbel_d(unsigned kA, unsigned kB, unsigned e)
{
  float f = bits_to_unit(rand_word(kA, kB, e));
  double u = (f == 0.0f) ? 1.1754943508222875e-38 : (double)f;
  return -log(-log(u));
}

// ===================== setup kernels =====================
__global__ void k_keys(unsigned* keys)
{
  if (threadIdx.x != 0 || blockIdx.x != 0) return;
  unsigned a0,a1,b0,b1,c0,c1,d0,d1;
  unsigned kx = 0u, ky = 42u;                 // jax.random.key(42)
  threefry2x32(kx, ky, 0u, 0u, a0, a1);       // carried key
  threefry2x32(kx, ky, 0u, 1u, b0, b1);       // k0 (h0 uniform)
  keys[0] = b0; keys[1] = b1;
  kx = a0; ky = a1;
  for (int s = 0; s < 100; ++s) {
    threefry2x32(kx, ky, 0u, 0u, a0, a1);     // k
    threefry2x32(kx, ky, 0u, 1u, c0, c1);     // ke
    threefry2x32(kx, ky, 0u, 2u, d0, d1);     // kr
    keys[2 + 4*s + 0] = c0; keys[2 + 4*s + 1] = c1;
    keys[2 + 4*s + 2] = d0; keys[2 + 4*s + 3] = d1;
    kx = a0; ky = a1;
  }
}

__global__ __launch_bounds__(256) void k_prep(
    const float* fcz_w, const float* fcz_b, const float* fcr_w, const float* fcr_b,
    const float* fcn_w, const float* fcn_b, const float* fco_w, const float* fco_b,
    const float* h2l_w, const float* h2l_b,
    double* wzrT, double* wnT, double* wo, double* bz, double* br,
    double* bnn, double* bo, double* h2lw, double* h2lb)
{
  int id = blockIdx.x * 256 + threadIdx.x;
  if (id < 65536) {
    int k = id >> 8, j = id & 255;
    wzrT[id] = (double)((j < 128) ? fcz_w[j*256 + k] : fcr_w[(j-128)*256 + k]);
    return;
  }
  id -= 65536;
  if (id < 65536) { int k = id >> 8, j = id & 255; wnT[id] = (double)fcn_w[j*256 + k]; return; }
  id -= 65536;
  if (id < 256) { wo[id] = (double)fco_w[id]; return; }
  id -= 256;
  if (id < 128) { bz[id] = (double)fcz_b[id]; return; }
  id -= 128;
  if (id < 128) { br[id] = (double)fcr_b[id]; return; }
  id -= 128;
  if (id < 256) { bnn[id] = (double)fcn_b[id]; return; }
  id -= 256;
  if (id < 1) { bo[0] = (double)fco_b[0]; return; }
  id -= 1;
  if (id < 384) { h2lw[id] = (double)h2l_w[id]; return; }
  id -= 384;
  if (id < 3) { h2lb[id] = (double)h2l_b[id]; return; }
}

__global__ __launch_bounds__(256) void k_h0(const unsigned* keys, double* h, double* p)
{
  unsigned e = blockIdx.x * 256 + threadIdx.x;    // < 524288
  h[e] = (double)bits_to_unit(rand_word(keys[0], keys[1], e));
  if (e < 4096) p[e] = (double)(float)log(1.0 / 128.0);
}

// ===================== frontend (map CNN encoder) =====================
__global__ __launch_bounds__(256) void k_conv1(const float* in, const float* w, double* out)
{
  int bc = blockIdx.x; int b = bc >> 4, co = bc & 15;
  __shared__ double wl[25];
  __shared__ float plf[4096];
  if (threadIdx.x < 25) wl[threadIdx.x] = (double)w[co*25 + threadIdx.x];
  const float* ib = in + (size_t)b * 4096;
  for (int j = 0; j < 16; ++j) plf[threadIdx.x + j*256] = ib[threadIdx.x + j*256];
  __syncthreads();
  for (int q = 0; q < 4; ++q) {
    int px = q*256 + threadIdx.x;
    int oh = px >> 5, ow = px & 31;
    double acc = 0.0;
    for (int kh = 0; kh < 5; ++kh) {
      int ih = oh*2 - 2 + kh; if (ih < 0 || ih >= 64) continue;
      for (int kw = 0; kw < 5; ++kw) {
        int iw = ow*2 - 2 + kw; if (iw < 0 || iw >= 64) continue;
        acc = fma((double)plf[ih*64 + iw], wl[kh*5 + kw], acc);
      }
    }
    out[((size_t)b*16 + co)*1024 + px] = fmax(acc, 0.0);
  }
}

// 2 output channels per block: input planes read once per pair
__global__ __launch_bounds__(256) void k_conv3x3(const double* in, const float* w,
                                                 double* out, int Ci, int Co)
{
  int bc = blockIdx.x; int b = bc / (Co >> 1), cop = bc % (Co >> 1);
  int co0 = cop * 2;
  __shared__ double wl0[288], wl1[288];
  __shared__ double pl[2][1024];
  for (int e = threadIdx.x; e < Ci*9; e += 256) {
    wl0[e] = (double)w[(size_t)co0*Ci*9 + e];
    wl1[e] = (double)w[(size_t)(co0 + 1)*Ci*9 + e];
  }
  double acc0[4] = {0.0, 0.0, 0.0, 0.0};
  double acc1[4] = {0.0, 0.0, 0.0, 0.0};
  const double* ib = in + (size_t)b * Ci * 1024;
  for (int q = 0; q < 4; ++q)
    pl[0][threadIdx.x + q*256] = ib[threadIdx.x + q*256];
  __syncthreads();
  for (int ci = 0; ci < Ci; ++ci) {
    int cur = ci & 1;
    if (ci + 1 < Ci) {
      for (int q = 0; q < 4; ++q)
        pl[cur ^ 1][threadIdx.x + q*256] = ib[(ci + 1)*1024 + threadIdx.x + q*256];
    }
    const double* wp0 = wl0 + ci*9;
    const double* wp1 = wl1 + ci*9;
    for (int q = 0; q < 4; ++q) {
      int px = q*256 + threadIdx.x;
      int oh = px >> 5, ow = px & 31;
      double a0 = acc0[q], a1 = acc1[q];
      for (int kh = 0; kh < 3; ++kh) {
        int ih = oh - 1 + kh; if (ih < 0 || ih >= 32) continue;
        for (int kw = 0; kw < 3; ++kw) {
          int iw = ow - 1 + kw; if (iw < 0 || iw >= 32) continue;
          double pv = pl[cur][ih*32 + iw];
          a0 = fma(pv, wp0[kh*3 + kw], a0);
          a1 = fma(pv, wp1[kh*3 + kw], a1);
        }
      }
      acc0[q] = a0; acc1[q] = a1;
    }
    __syncthreads();
  }
  for (int q = 0; q < 4; ++q) {
    int px = q*256 + threadIdx.x;
    out[((size_t)b*Co + co0)*1024 + px]     = fmax(acc0[q], 0.0);
    out[((size_t)b*Co + co0 + 1)*1024 + px] = fmax(acc1[q], 0.0);
  }
}

__global__ __launch_bounds__(256) void k_bnstats1(const double* __restrict__ x,
    double* __restrict__ partS, double* __restrict__ partS2, int C)
{
  int c = blockIdx.x >> 3, chunk = blockIdx.x & 7;
  double s = 0.0, s2 = 0.0;
  for (int e = threadIdx.x; e < 4096; e += 256) {
    int b = chunk*4 + (e >> 10), px = e & 1023;
    double v = x[((size_t)b*C + c)*1024 + px];
    s += v; s2 = fma(v, v, s2);
  }
  __shared__ double rs[256], rs2[256];
  rs[threadIdx.x] = s; rs2[threadIdx.x] = s2;
  __syncthreads();
  for (int d = 128; d; d >>= 1) {
    if (threadIdx.x < d) { rs[threadIdx.x] += rs[threadIdx.x + d]; rs2[threadIdx.x] += rs2[threadIdx.x + d]; }
    __syncthreads();
  }
  if (threadIdx.x == 0) { partS[blockIdx.x] = rs[0]; partS2[blockIdx.x] = rs2[0]; }
}

__global__ void k_bnstats2(const double* __restrict__ partS,
                           const double* __restrict__ partS2,
                           const float* g, const float* bta, double* scsh, int C)
{
  int c = threadIdx.x;
  if (c >= C) return;
  double s = 0.0, s2 = 0.0;
  for (int j = 0; j < 8; ++j) { s += partS[c*8 + j]; s2 += partS2[c*8 + j]; }
  double n = 32768.0;
  double mean = s / n;
  double var = s2 / n - mean*mean;
  double sc = (double)g[c] / sqrt(var + 1e-5);
  scsh[c*2] = sc;
  scsh[c*2 + 1] = (double)bta[c] - mean * sc;
}

__global__ __launch_bounds__(256) void k_bnapply(double* x, const double* scsh, int C)
{
  size_t e = (size_t)blockIdx.x * 256 + threadIdx.x;
  int c = (int)((e >> 10) % (size_t)C);
  x[e] = fma(x[e], scsh[c*2], scsh[c*2 + 1]);
}

__global__ __launch_bounds__(256) void k_mapfc(const double* x, const float* w,
                                               const float* bias, double* emb)
{
  int blk = blockIdx.x; int b = blk >> 4, jg = blk & 15;
  double acc[8];
  #pragma unroll
  for (int jj = 0; jj < 8; ++jj) acc[jj] = 0.0;
  const double* xb = x + (size_t)b * 32768;
  for (int e = threadIdx.x; e < 32768; e += 256) {
    double xv = xb[e];
    #pragma unroll
    for (int jj = 0; jj < 8; ++jj)
      acc[jj] = fma(xv, (double)w[(size_t)(jg*8 + jj)*32768 + e], acc[jj]);
  }
  __shared__ double red[8][256];
  #pragma unroll
  for (int jj = 0; jj < 8; ++jj) red[jj][threadIdx.x] = acc[jj];
  __syncthreads();
  for (int d = 128; d; d >>= 1) {
    if (threadIdx.x < d)
      #pragma unroll
      for (int jj = 0; jj < 8; ++jj) red[jj][threadIdx.x] += red[jj][threadIdx.x + d];
    __syncthreads();
  }
  if (threadIdx.x < 8) {
    int j = jg*8 + threadIdx.x;
    emb[b*128 + j] = fmax(red[threadIdx.x][0] + (double)bias[j], 0.0);
  }
}

__global__ void k_maps(const double* emb, const float* m2o_w, const float* m2o_b,
                       const float* m2a_w, const float* m2a_b,
                       double* omap, double* amap)
{
  int b = blockIdx.x, j = threadIdx.x;   // 64 threads
  double a1 = (double)m2o_b[j], a2 = (double)m2a_b[j];
  for (int k = 0; k < 128; ++k) {
    double ev = emb[b*128 + k];
    a1 = fma(ev, (double)m2o_w[j*128 + k], a1);
    a2 = fma(ev, (double)m2a_w[j*128 + k], a2);
  }
  omap[b*64 + j] = fmax(a1, 0.0);
  amap[b*64 + j] = fmax(a2, 0.0);
}

__global__ __launch_bounds__(128) void k_xs(const float* obs_in, const float* act_in,
                                            const float* obs_w, const float* obs_b,
                                            const float* act_w, const float* act_b,
                                            const double* omap, const double* amap,
                                            const double* wo,
                                            double* xs, double* xo)
{
  int s = blockIdx.x, b = blockIdx.y, j = threadIdx.x;
  double v;
  if (j < 64) {
    double a = (double)obs_b[j];
    const float* o = obs_in + ((size_t)b*100 + s)*16;
    for (int k = 0; k < 16; ++k) a = fma((double)o[k], (double)obs_w[j*16 + k], a);
    v = fmax(a, 0.0) * omap[b*64 + j];
  } else {
    int j2 = j - 64;
    double a = (double)act_b[j2];
    const float* o = act_in + ((size_t)b*100 + s)*3;
    for (int k = 0; k < 3; ++k) a = fma((double)o[k], (double)act_w[j2*3 + k], a);
    v = fmax(a, 0.0) * amap[b*64 + j2];
  }
  xs[((size_t)s*32 + b)*128 + j] = v;
  __shared__ double red[128];
  red[j] = v * wo[128 + j];
  __syncthreads();
  for (int d = 64; d; d >>= 1) {
    if (j < d) red[j] += red[j + d];
    __syncthreads();
  }
  if (j == 0) xo[s*32 + b] = red[0];
}

__global__ __launch_bounds__(256, 2) void k_xpre2(const double* __restrict__ xs,
    const double* __restrict__ wzrT, const double* __restrict__ wnT,
    double* __restrict__ xzr, double* __restrict__ xn)
{
  int s = blockIdx.x >> 2, bg = blockIdx.x & 3;
  __shared__ double xl[8][128];
  int t = threadIdx.x;
  #pragma unroll
  for (int j = 0; j < 4; ++j) {
    int e = t + j*256;
    int i = e >> 7, cc = e & 127;
    xl[i][cc] = xs[((size_t)s*32 + bg*8 + i)*128 + cc];
  }
  __syncthreads();
  double az[8], an[8];
  #pragma unroll
  for (int i = 0; i < 8; ++i) { az[i] = 0.0; an[i] = 0.0; }
  for (int k = 0; k < 128; ++k) {
    double wz = wzrT[k*256 + t];
    double wn = wnT[(128 + k)*256 + t];
    #pragma unroll
    for (int i = 0; i < 8; ++i) {
      double xv = xl[i][k];
      az[i] = fma(xv, wz, az[i]);
      an[i] = fma(xv, wn, an[i]);
    }
  }
  #pragma unroll
  for (int i = 0; i < 8; ++i) {
    size_t sb = (size_t)s*32 + bg*8 + i;
    xzr[sb*256 + t] = az[i];
    xn [sb*256 + t] = an[i];
  }
}

// ===================== fused scan kernels =====================
// k_step1: 256 blocks x 512 threads; 16 rows/block.
// thread = (rq = t>>7 -> rows rq*4..rq*4+3; c2 = t&127 -> cols c2, c2+128).
// Blocks 0..31 first run phase C of step s-1 (pn normalize + y), overlapped.
__global__ __launch_bounds__(512, 2) void k_step1(
    const double* __restrict__ hsrc, const int* __restrict__ idxp,
    const double* __restrict__ xzr, const double* __restrict__ xn,
    const double* __restrict__ xo,
    const double* __restrict__ wzrT, const double* __restrict__ wnT,
    const double* __restrict__ bz, const double* __restrict__ br,
    const double* __restrict__ bnn, const double* __restrict__ wo,
    const double* __restrict__ bo, double* __restrict__ P,
    const double* __restrict__ h2lw, const double* __restrict__ h2lb,
    double* __restrict__ h1out, double* __restrict__ LP,
    const double* __restrict__ PNPRE,
    float* __restrict__ pfout, float* __restrict__ yout,
    const unsigned* __restrict__ keys, int s)
{
  __shared__ double ah[16][128];   // gathered h
  __shared__ double aw[16][128];   // rg*h, later h1
  __shared__ double wsh[128], ys[128], red8[8][128];
  __shared__ int    isx[128];
  __shared__ double smx[2], ssx[2];
  const int t  = threadIdx.x;
  const int rq = t >> 7;           // 0..3: rows rq*4 .. rq*4+3
  const int c2 = t & 127;          // cols c2, c2+128
  const int r0 = blockIdx.x * 16;
  const int wv = t >> 6, lane = t & 63;
  const bool first = (idxp == nullptr);

  // ---- phase C of step s-1 (blocks 0..31): pn normalize + y ----
  if (!first && blockIdx.x < 32) {
    int b = blockIdx.x;
    if (t < 128) {
      double q = PNPRE[b*128 + t];
      double m = q;
      for (int d = 32; d; d >>= 1) m = fmax(m, __shfl_xor(m, d, 64));
      if ((t & 63) == 0) smx[t >> 6] = m;
    }
    __syncthreads();
    if (t < 128) {
      double q = PNPRE[b*128 + t];
      double m = fmax(smx[0], smx[1]);
      double e = exp(q - m), su = e;
      for (int d = 32; d; d >>= 1) su += __shfl_xor(su, d, 64);
      if ((t & 63) == 0) ssx[t >> 6] = su;
    }
    __syncthreads();
    if (t < 128) {
      double q = PNPRE[b*128 + t];
      double m = fmax(smx[0], smx[1]);
      double pn = q - (m + log(ssx[0] + ssx[1]));
      P[b*128 + t] = pn;
      wsh[t] = exp(pn);
      isx[t] = idxp[t*32 + b];
    }
    __syncthreads();
    {
      #pragma unroll
      for (int colh = 0; colh < 2; ++colh) {
        int col = lane + colh*64;
        double acc = 0.0;
        for (int q = 0; q < 16; ++q) {
          int ii = wv*16 + q;
          acc = fma(wsh[ii], hsrc[(size_t)(isx[ii]*32 + b)*128 + col], acc);
        }
        red8[wv][col] = acc;
      }
    }
    __syncthreads();
    if (t < 128) {
      double a = red8[0][t];
      for (int gg = 1; gg < 8; ++gg) a += red8[gg][t];
      ys[t] = a;
    }
    __syncthreads();
    if (t < 3) {
      double dsum = h2lb[t];
      for (int cc = 0; cc < 128; ++cc)
        dsum = fma(h2lw[t*128 + cc], ys[cc], dsum);
      yout[(s - 1)*96 + b*3 + t] = (float)(1.0 / (1.0 + exp(-dsum)));
    }
    __syncthreads();
  }

  // ---- gather prev h (4 elements/thread, coalesced) ----
  #pragma unroll
  for (int j = 0; j < 4; ++j) {
    int e = t + j*512;
    int r = e >> 7, cc = e & 127;
    int R = r0 + r, b = R & 31;
    int src = first ? R : (idxp[R]*32 + b);
    ah[r][cc] = hsrc[(size_t)src*128 + cc];
  }
  __syncthreads();
  // ---- pf for previous step: 8 waves x 2 rows ----
  if (pfout != nullptr) {
    #pragma unroll
    for (int q = 0; q < 2; ++q) {
      int i = wv*2 + q;
      double v0 = ah[i][lane*2], v1 = ah[i][lane*2 + 1];
      double s0 = fma(v0, h2lw[lane*2],       v1 * h2lw[lane*2 + 1]);
      double s1 = fma(v0, h2lw[128 + lane*2], v1 * h2lw[128 + lane*2 + 1]);
      double s2 = fma(v0, h2lw[256 + lane*2], v1 * h2lw[256 + lane*2 + 1]);
      for (int d = 32; d; d >>= 1) {
        s0 += __shfl_xor(s0, d, 64);
        s1 += __shfl_xor(s1, d, 64);
        s2 += __shfl_xor(s2, d, 64);
      }
      if (lane == 0) {
        float* o = pfout + (r0 + i) * 3;
        o[0] = (float)(1.0 / (1.0 + exp(-(s0 + h2lb[0]))));
        o[1] = (float)(1.0 / (1.0 + exp(-(s1 + h2lb[1]))));
        o[2] = (float)(1.0 / (1.0 + exp(-(s2 + h2lb[2]))));
      }
    }
  }
  // ---- GEMM1: h-part of [x|h] @ Wzr^T; 4 rows x 2 cols/thread ----
  double ac0[4], ac1[4];           // [row i][col 0/1]
  #pragma unroll
  for (int i = 0; i < 4; ++i) { ac0[i] = 0.0; ac1[i] = 0.0; }
  {
    const double2v* ap0 = (const double2v*)&ah[rq*4 + 0][0];
    const double2v* ap1 = (const double2v*)&ah[rq*4 + 1][0];
    const double2v* ap2 = (const double2v*)&ah[rq*4 + 2][0];
    const double2v* ap3 = (const double2v*)&ah[rq*4 + 3][0];
    for (int k2 = 0; k2 < 64; ++k2) {
      const double* wr0 = &wzrT[(128 + 2*k2)*256];
      const double* wr1 = &wzrT[(128 + 2*k2 + 1)*256];
      double w00 = wr0[c2],       w01 = wr1[c2];
      double w10 = wr0[c2 + 128], w11 = wr1[c2 + 128];
      double2v A0 = ap0[k2], A1 = ap1[k2], A2 = ap2[k2], A3 = ap3[k2];
      ac0[0] = fma(A0.y, w01, fma(A0.x, w00, ac0[0]));
      ac1[0] = fma(A0.y, w11, fma(A0.x, w10, ac1[0]));
      ac0[1] = fma(A1.y, w01, fma(A1.x, w00, ac0[1]));
      ac1[1] = fma(A1.y, w11, fma(A1.x, w10, ac1[1]));
      ac0[2] = fma(A2.y, w01, fma(A2.x, w00, ac0[2]));
      ac1[2] = fma(A2.y, w11, fma(A2.x, w10, ac1[2]));
      ac0[3] = fma(A3.y, w01, fma(A3.x, w00, ac0[3]));
      ac1[3] = fma(A3.y, w11, fma(A3.x, w10, ac1[3]));
    }
  }
  double zrv[4];
  {
    double bzv = bz[c2], brv = br[c2];
    #pragma unroll
    for (int i = 0; i < 4; ++i) {
      int row = rq*4 + i;
      int b = (r0 + row) & 31;
      zrv[i] = sigd(ac0[i] + xzr[b*256 + c2] + bzv);
      double rgv = sigd(ac1[i] + xzr[b*256 + c2 + 128] + brv);
      aw[row][c2] = rgv * ah[row][c2];
    }
  }
  __syncthreads();
  // ---- GEMM2: (rg*h)-part of [rg*h|x] @ Wn^T ----
  #pragma unroll
  for (int i = 0; i < 4; ++i) { ac0[i] = 0.0; ac1[i] = 0.0; }
  {
    const double2v* ap0 = (const double2v*)&aw[rq*4 + 0][0];
    const double2v* ap1 = (const double2v*)&aw[rq*4 + 1][0];
    const double2v* ap2 = (const double2v*)&aw[rq*4 + 2][0];
    const double2v* ap3 = (const double2v*)&aw[rq*4 + 3][0];
    for (int k2 = 0; k2 < 64; ++k2) {
      const double* wr0 = &wnT[(2*k2)*256];
      const double* wr1 = &wnT[(2*k2 + 1)*256];
      double w00 = wr0[c2],       w01 = wr1[c2];
      double w10 = wr0[c2 + 128], w11 = wr1[c2 + 128];
      double2v A0 = ap0[k2], A1 = ap1[k2], A2 = ap2[k2], A3 = ap3[k2];
      ac0[0] = fma(A0.y, w01, fma(A0.x, w00, ac0[0]));
      ac1[0] = fma(A0.y, w11, fma(A0.x, w10, ac1[0]));
      ac0[1] = fma(A1.y, w01, fma(A1.x, w00, ac0[1]));
      ac1[1] = fma(A1.y, w11, fma(A1.x, w10, ac1[1]));
      ac0[2] = fma(A2.y, w01, fma(A2.x, w00, ac0[2]));
      ac1[2] = fma(A2.y, w11, fma(A2.x, w10, ac1[2]));
      ac0[3] = fma(A3.y, w01, fma(A3.x, w00, ac0[3]));
      ac1[3] = fma(A3.y, w11, fma(A3.x, w10, ac1[3]));
    }
  }
  // mu / softplus(var) / eps / h1 — all thread-local
  double hv[4];
  {
    unsigned keA = keys[2 + 4*s], keB = keys[2 + 4*s + 1];
    double bn0 = bnn[c2], bn1 = bnn[c2 + 128];
    #pragma unroll
    for (int i = 0; i < 4; ++i) {
      int row = rq*4 + i, R = r0 + row;
      int b = R & 31;
      double mu  = ac0[i] + xn[b*256 + c2] + bn0;
      double var = ac1[i] + xn[b*256 + c2 + 128] + bn1;
      double sp = fmax(var, 0.0) + log1p(exp(-fabs(var)));
      double ep = eps_normal(keA, keB, (unsigned)(R*128 + c2));
      double n  = fma(ep, sp, mu);
      hv[i] = (1.0 - zrv[i])*n + zrv[i]*ah[row][c2];
      h1out[(size_t)R*128 + c2] = hv[i];
    }
  }
  __syncthreads();   // all GEMM2 aw reads complete
  #pragma unroll
  for (int i = 0; i < 4; ++i) aw[rq*4 + i][c2] = hv[i];
  __syncthreads();
  // ---- logpdf partial (without +p): 8 waves x 2 rows ----
  {
    #pragma unroll
    for (int q = 0; q < 2; ++q) {
      int row = wv*2 + q, R = r0 + row, b = R & 31;
      double part = fma(aw[row][lane], wo[lane], aw[row][lane + 64] * wo[lane + 64]);
      for (int d = 32; d; d >>= 1) part += __shfl_xor(part, d, 64);
      if (lane == 0) LP[b*128 + (R >> 5)] = part + xo[b] + bo[0];
    }
  }
}

// k_sr: barrier-free per-wave softmax + Gumbel-argmax.  512 blocks x 512
// threads; wave wv handles row rw = blockIdx*8 + wv.
__global__ __launch_bounds__(512, 4) void k_sr(
    const double* __restrict__ LP, const double* __restrict__ P,
    const unsigned* __restrict__ keys, int s,
    int* __restrict__ idx, double* __restrict__ PNPRE)
{
  int t = threadIdx.x;
  int wv = t >> 6, lane = t & 63;
  int rw = blockIdx.x * 8 + wv;
  int bw = rw & 31;
  unsigned kA = keys[2 + 4*s + 2], kB = keys[2 + 4*s + 3];
  double v0 = LP[bw*128 + lane]      + P[bw*128 + lane];
  double v1 = LP[bw*128 + lane + 64] + P[bw*128 + lane + 64];
  double m0 = v0, m1 = v1;
  for (int d = 32; d; d >>= 1) {
    m0 = fmax(m0, __shfl_xor(m0, d, 64));
    m1 = fmax(m1, __shfl_xor(m1, d, 64));
  }
  double m = fmax(m0, m1);
  double e0 = exp(v0 - m), e1 = exp(v1 - m);
  double s0 = e0, s1 = e1;
  for (int d = 32; d; d >>= 1) {
    s0 += __shfl_xor(s0, d, 64);
    s1 += __shfl_xor(s1, d, 64);
  }
  double lse = log(s0 + s1);
  double p1_0 = v0 - m - lse;
  double p1_1 = v1 - m - lse;
  double lg0 = log(0.5*exp(p1_0) + 0.00390625);
  double lg1 = log(0.5*exp(p1_1) + 0.00390625);
  double g0 = gumbel_d(kA, kB, (unsigned)(rw*128 + lane)) + lg0;
  double g1 = gumbel_d(kA, kB, (unsigned)(rw*128 + lane + 64)) + lg1;
  double val; int bj;
  if (g0 >= g1) { val = g0; bj = lane; } else { val = g1; bj = lane + 64; }
  for (int d = 32; d; d >>= 1) {
    double ov = __shfl_xor(val, d, 64);
    int    oj = __shfl_xor(bj, d, 64);
    if (ov > val || (ov == val && oj < bj)) { val = ov; bj = oj; }
  }
  double pl = __shfl(p1_0, bj & 63, 64);
  double ph = __shfl(p1_1, bj & 63, 64);
  if (lane == 0) {
    idx[rw] = bj;
    double p1b = (bj < 64) ? pl : ph;
    double pe = exp(p1b);
    PNPRE[bw*128 + (rw >> 5)] = log(pe / (0.5*pe + 0.00390625));
  }
}

// k_yfinal: phase C for step 99 (32 blocks x 512)
__global__ __launch_bounds__(512) void k_yfinal(
    const double* __restrict__ hlast, const int* __restrict__ idxp,
    const double* __restrict__ PNPRE, double* __restrict__ P,
    const double* __restrict__ h2lw, const double* __restrict__ h2lb,
    float* __restrict__ yout)
{
  __shared__ double wsh[128], ys[128], red8[8][128];
  __shared__ int    isx[128];
  __shared__ double smx[2], ssx[2];
  int t = threadIdx.x, b = blockIdx.x;
  int wv = t >> 6, lane = t & 63;
  if (t < 128) {
    double q = PNPRE[b*128 + t];
    double m = q;
    for (int d = 32; d; d >>= 1) m = fmax(m, __shfl_xor(m, d, 64));
    if ((t & 63) == 0) smx[t >> 6] = m;
  }
  __syncthreads();
  if (t < 128) {
    double q = PNPRE[b*128 + t];
    double m = fmax(smx[0], smx[1]);
    double e = exp(q - m), su = e;
    for (int d = 32; d; d >>= 1) su += __shfl_xor(su, d, 64);
    if ((t & 63) == 0) ssx[t >> 6] = su;
  }
  __syncthreads();
  if (t < 128) {
    double q = PNPRE[b*128 + t];
    double m = fmax(smx[0], smx[1]);
    double pn = q - (m + log(ssx[0] + ssx[1]));
    P[b*128 + t] = pn;
    wsh[t] = exp(pn);
    isx[t] = idxp[t*32 + b];
  }
  __syncthreads();
  #pragma unroll
  for (int colh = 0; colh < 2; ++colh) {
    int col = lane + colh*64;
    double acc = 0.0;
    for (int q = 0; q < 16; ++q) {
      int ii = wv*16 + q;
      acc = fma(wsh[ii], hlast[(size_t)(isx[ii]*32 + b)*128 + col], acc);
    }
    red8[wv][col] = acc;
  }
  __syncthreads();
  if (t < 128) {
    double a = red8[0][t];
    for (int gg = 1; gg < 8; ++gg) a += red8[gg][t];
    ys[t] = a;
  }
  __syncthreads();
  if (t < 3) {
    double dsum = h2lb[t];
    for (int cc = 0; cc < 128; ++cc)
      dsum = fma(h2lw[t*128 + cc], ys[cc], dsum);
    yout[99*96 + b*3 + t] = (float)(1.0 / (1.0 + exp(-dsum)));
  }
}

// epilogue: pf for the last step (gather via idx)
__global__ __launch_bounds__(256) void k_pfend(const double* __restrict__ h1,
    const int* __restrict__ idx, const double* __restrict__ h2lw,
    const double* __restrict__ h2lb, float* __restrict__ pfout)
{
  int wv = threadIdx.x >> 6, lane = threadIdx.x & 63;
  int r = blockIdx.x * 4 + wv;
  int b = r & 31;
  const double* hr = h1 + (size_t)(idx[r]*32 + b) * 128;
  double v0 = hr[lane*2], v1 = hr[lane*2 + 1];
  double s0 = fma(v0, h2lw[lane*2],       v1 * h2lw[lane*2 + 1]);
  double s1 = fma(v0, h2lw[128 + lane*2], v1 * h2lw[128 + lane*2 + 1]);
  double s2 = fma(v0, h2lw[256 + lane*2], v1 * h2lw[256 + lane*2 + 1]);
  for (int d = 32; d; d >>= 1) {
    s0 += __shfl_xor(s0, d, 64);
    s1 += __shfl_xor(s1, d, 64);
    s2 += __shfl_xor(s2, d, 64);
  }
  if (lane == 0) {
    float* o = pfout + r * 3;
    o[0] = (float)(1.0 / (1.0 + exp(-(s0 + h2lb[0]))));
    o[1] = (float)(1.0 / (1.0 + exp(-(s1 + h2lb[1]))));
    o[2] = (float)(1.0 / (1.0 + exp(-(s2 + h2lb[2]))));
  }
}

// ===================== host launch =====================
extern "C" void kernel_launch(void* const* d_in, const int* in_sizes, int n_in,
                              void* d_out, int out_size, void* d_ws, size_t ws_size,
                              hipStream_t stream)
{
  (void)in_sizes; (void)n_in; (void)out_size; (void)ws_size;
  const float* map_in = (const float*)d_in[0];
  const float* obs_in = (const float*)d_in[1];
  const float* act_in = (const float*)d_in[2];
  const float* c1_w = (const float*)d_in[3];
  const float* c1_g = (const float*)d_in[4];
  const float* c1_b = (const float*)d_in[5];
  const float* c2_w = (const float*)d_in[6];
  const float* c2_g = (const float*)d_in[7];
  const float* c2_b = (const float*)d_in[8];
  const float* c3_w = (const float*)d_in[9];
  const float* c3_g = (const float*)d_in[10];
  const float* c3_b = (const float*)d_in[11];
  const float* map_w = (const float*)d_in[12];
  const float* map_b = (const float*)d_in[13];
  const float* m2o_w = (const float*)d_in[14];
  const float* m2o_b = (const float*)d_in[15];
  const float* m2a_w = (const float*)d_in[16];
  const float* m2a_b = (const float*)d_in[17];
  const float* obs_w = (const float*)d_in[18];
  const float* obs_b = (const float*)d_in[19];
  const float* act_w = (const float*)d_in[20];
  const float* act_b = (const float*)d_in[21];
  const float* fcz_w = (const float*)d_in[22];
  const float* fcz_b = (const float*)d_in[23];
  const float* fcr_w = (const float*)d_in[24];
  const float* fcr_b = (const float*)d_in[25];
  const float* fcn_w = (const float*)d_in[26];
  const float* fcn_b = (const float*)d_in[27];
  const float* fco_w = (const float*)d_in[28];
  const float* fco_b = (const float*)d_in[29];
  const float* h2l_w = (const float*)d_in[30];
  const float* h2l_b = (const float*)d_in[31];

  float* yout  = (float*)d_out;
  float* pfout = (float*)d_out + 9600;

  char* ws = (char*)d_ws;
  double*   H0     = (double*)(ws + 0);           // 4096*128
  double*   H1A    = (double*)(ws + 4194304);
  double*   H1B    = (double*)(ws + 8388608);
  double*   XS     = (double*)(ws + 12582912);    // 100*32*128
  double*   C1O    = (double*)(ws + 15859712);    // 32*16*1024
  double*   C2O    = (double*)(ws + 20054016);    // 32*32*1024
  double*   C3O    = (double*)(ws + 28442624);    // 32*32*1024
  double*   XZR    = (double*)(ws + 15859712);    // 100*32*256 (overlay)
  double*   XN     = (double*)(ws + 22413312);    // 100*32*256 (overlay)
  double*   XO     = (double*)(ws + 28966912);    // 100*32     (overlay)
  double*   WZRT   = (double*)(ws + 36831232);    // 256*256
  double*   WNT    = (double*)(ws + 37355520);
  double*   WO     = (double*)(ws + 37879808);
  double*   BZ     = (double*)(ws + 37881856);
  double*   BR     = (double*)(ws + 37882880);
  double*   BNN    = (double*)(ws + 37883904);
  double*   BO     = (double*)(ws + 37885952);
  double*   H2LW   = (double*)(ws + 37886208);
  double*   H2LB   = (double*)(ws + 37889280);
  double*   EMB    = (double*)(ws + 37889536);    // 32*128
  double*   OMAP   = (double*)(ws + 37922304);    // 32*64
  double*   AMAP   = (double*)(ws + 37938688);
  double*   P      = (double*)(ws + 37955072);    // 4096  [b][p]
  double*   LP     = (double*)(ws + 37987840);    // 4096  [b][p]
  int*      IDX    = (int*)   (ws + 38020608);    // 4096  [p*32+b]
  unsigned* KEYS   = (unsigned*)(ws + 38036992);  // 402
  double*   SCSH   = (double*)(ws + 38039040);    // 32*2
  double*   PARTS  = (double*)(ws + 38039552);    // 256
  double*   PARTS2 = (double*)(ws + 38041600);    // 256
  double*   PNPRE  = (double*)(ws + 38043648);    // 4096  [b][p]

  // ---- setup ----
  k_keys<<<1, 64, 0, stream>>>(KEYS);
  k_prep<<<517, 256, 0, stream>>>(fcz_w, fcz_b, fcr_w, fcr_b, fcn_w, fcn_b,
                                  fco_w, fco_b, h2l_w, h2l_b,
                                  WZRT, WNT, WO, BZ, BR, BNN, BO, H2LW, H2LB);
  k_h0<<<2048, 256, 0, stream>>>(KEYS, H0, P);

  // ---- frontend ----
  k_conv1<<<512, 256, 0, stream>>>(map_in, c1_w, C1O);
  k_bnstats1<<<128, 256, 0, stream>>>(C1O, PARTS, PARTS2, 16);
  k_bnstats2<<<1, 32, 0, stream>>>(PARTS, PARTS2, c1_g, c1_b, SCSH, 16);
  k_bnapply<<<2048, 256, 0, stream>>>(C1O, SCSH, 16);
  k_conv3x3<<<512, 256, 0, stream>>>(C1O, c2_w, C2O, 16, 32);
  k_bnstats1<<<256, 256, 0, stream>>>(C2O, PARTS, PARTS2, 32);
  k_bnstats2<<<1, 32, 0, stream>>>(PARTS, PARTS2, c2_g, c2_b, SCSH, 32);
  k_bnapply<<<4096, 256, 0, stream>>>(C2O, SCSH, 32);
  k_conv3x3<<<512, 256, 0, stream>>>(C2O, c3_w, C3O, 32, 32);
  k_bnstats1<<<256, 256, 0, stream>>>(C3O, PARTS, PARTS2, 32);
  k_bnstats2<<<1, 32, 0, stream>>>(PARTS, PARTS2, c3_g, c3_b, SCSH, 32);
  k_bnapply<<<4096, 256, 0, stream>>>(C3O, SCSH, 32);
  k_mapfc<<<512, 256, 0, stream>>>(C3O, map_w, map_b, EMB);
  k_maps<<<32, 64, 0, stream>>>(EMB, m2o_w, m2o_b, m2a_w, m2a_b, OMAP, AMAP);
  {
    dim3 g(100, 32);
    k_xs<<<g, 128, 0, stream>>>(obs_in, act_in, obs_w, obs_b, act_w, act_b,
                                OMAP, AMAP, WO, XS, XO);
  }
  k_xpre2<<<400, 256, 0, stream>>>(XS, WZRT, WNT, XZR, XN);

  // ---- scan over 100 timesteps (2 kernels/step) ----
  double* hb[2] = { H1A, H1B };
  for (int s = 0; s < 100; ++s) {
    const double* hsrc = (s == 0) ? H0 : hb[(s - 1) & 1];
    const int* idxp = (s == 0) ? nullptr : IDX;
    float* pfprev = (s == 0) ? nullptr : (pfout + (size_t)(s - 1) * 12288);
    k_step1<<<256, 512, 0, stream>>>(hsrc, idxp,
        XZR + (size_t)s*32*256, XN + (size_t)s*32*256, XO + (size_t)s*32,
        WZRT, WNT, BZ, BR, BNN, WO, BO, P, H2LW, H2LB,
        hb[s & 1], LP, PNPRE, pfprev, yout, KEYS, s);
    k_sr<<<512, 512, 0, stream>>>(LP, P, KEYS, s, IDX, PNPRE);
  }
  k_yfinal<<<32, 512, 0, stream>>>(hb[1], IDX, PNPRE, P, H2LW, H2LB, yout);
  k_pfend<<<1024, 256, 0, stream>>>(hb[1], IDX, H2LW, H2LB,
                                    pfout + (size_t)99 * 12288);
}

// Round 11
// 5156.696 us; speedup vs baseline: 1.9592x; 1.2292x over previous
//
#include <hip/hip_runtime.h>
#include <math.h>

typedef double double2v __attribute__((ext_vector_type(2)));
typedef double double4v __attribute__((ext_vector_type(4)));

#if defined(__has_builtin)
#if __has_builtin(__builtin_amdgcn_mfma_f64_16x16x4f64)
#define HAVE_MFMA_F64 1
#endif
#endif

// ===================== JAX Threefry-2x32 (bit-exact) =====================
__device__ __forceinline__ void threefry2x32(unsigned k0, unsigned k1,
                                             unsigned x0, unsigned x1,
                                             unsigned& o0, unsigned& o1)
{
  unsigned ks2 = k0 ^ k1 ^ 0x1BD11BDAu;
  x0 += k0; x1 += k1;
#define TFR(r) { x0 += x1; x1 = (x1 << r) | (x1 >> (32 - r)); x1 ^= x0; }
  TFR(13) TFR(15) TFR(26) TFR(6)
  x0 += k1;  x1 += ks2 + 1u;
  TFR(17) TFR(29) TFR(16) TFR(24)
  x0 += ks2; x1 += k0 + 2u;
  TFR(13) TFR(15) TFR(26) TFR(6)
  x0 += k0;  x1 += k1 + 3u;
  TFR(17) TFR(29) TFR(16) TFR(24)
  x0 += k1;  x1 += ks2 + 4u;
  TFR(13) TFR(15) TFR(26) TFR(6)
  x0 += ks2; x1 += k0 + 5u;
#undef TFR
  o0 = x0; o1 = x1;
}

// jax_threefry_partitionable=True: word e = o0 ^ o1 of block (0, e)
__device__ __forceinline__ unsigned rand_word(unsigned kA, unsigned kB, unsigned e)
{
  unsigned o0, o1;
  threefry2x32(kA, kB, 0u, e, o0, o1);
  return o0 ^ o1;
}

__device__ __forceinline__ float bits_to_unit(unsigned bits)
{
  unsigned u = (bits >> 9) | 0x3f800000u;
  return __uint_as_float(u) - 1.0f;   // exact, in [0,1)
}

// erfinv in double: Giles poly init + 1 Halley iteration on erf()
__device__ __forceinline__ double erfinv_d(double x)
{
  double w = -log((1.0 - x) * (1.0 + x));
  double p;
  if (w < 5.0) {
    w -= 2.5;
    p = 2.81022636e-08;
    p = fma(p, w, 3.43273939e-07);
    p = fma(p, w, -3.5233877e-06);
    p = fma(p, w, -4.39150654e-06);
    p = fma(p, w, 0.00021858087);
    p = fma(p, w, -0.00125372503);
    p = fma(p, w, -0.00417768164);
    p = fma(p, w, 0.246640727);
    p = fma(p, w, 1.50140941);
  } else {
    w = sqrt(w) - 3.0;
    p = -0.000200214257;
    p = fma(p, w, 0.000100950558);
    p = fma(p, w, 0.00134934322);
    p = fma(p, w, -0.00367342844);
    p = fma(p, w, 0.00573950773);
    p = fma(p, w, -0.0076224613);
    p = fma(p, w, 0.00943887047);
    p = fma(p, w, 1.00167406);
    p = fma(p, w, 2.83297682);
  }
  double r = p * x;
  double f  = erf(r) - x;
  double fp = 1.1283791670955126 * exp(-r * r);   // 2/sqrt(pi) e^{-r^2}
  double q  = f / fp;
  return r - q / (1.0 + r * q);
}

// N(0,1) sample e of a jax.random.normal(f32) draw
__device__ __forceinline__ double eps_normal(unsigned kA, unsigned kB, unsigned e)
{
  float f = bits_to_unit(rand_word(kA, kB, e));
  double u = (double)f * (2.0 - 5.9604644775390625e-8)
           - (1.0 - 5.9604644775390625e-8);
  return 1.4142135623730951 * erfinv_d(u);
}

__device__ __forceinline__ double sigd(double x) { return 1.0 / (1.0 + exp(-x)); }

__device__ __forceinline__ double gumbel_d(unsigned kA, unsigned kB, unsigned e)
{
  float f = bits_to_unit(rand_word(kA, kB, e));
  double u = (f == 0.0f) ? 1.1754943508222875e-38 : (double)f;
  return -log(-log(u));
}

// ===================== MFMA layout probe =====================
// Two chained f64 MFMAs on asymmetric integer matrices; exact-check against
// 4 candidate D layouts.  flag: 0..3 = candidate id, 4 = none/absent.
__global__ void k_probe(int* flag)
{
#ifdef HAVE_MFMA_F64
  int l = threadIdx.x;
  int mr = l & 15, kg = l >> 4;
  double a = (double)(1 + 5*mr + 7*kg);       // A[mr][kg]
  double b = (double)(2 + 11*kg + 13*mr);     // B[kg][mr]
  double4v d = {0.0, 0.0, 0.0, 0.0};
  d = __builtin_amdgcn_mfma_f64_16x16x4f64(a, b, d, 0, 0, 0);
  d = __builtin_amdgcn_mfma_f64_16x16x4f64(a, b, d, 0, 0, 0);   // chain test
  bool ok0 = true, ok1 = true, ok2 = true, ok3 = true;
  for (int q = 0; q < 4; ++q) {
    int rows[4] = { kg*4 + q, kg + 4*q, mr,         mr };
    int cols[4] = { mr,       mr,       kg*4 + q,   kg + 4*q };
    double t[4];
    for (int c = 0; c < 4; ++c) {
      double acc = 0.0;
      for (int k = 0; k < 4; ++k)
        acc += (double)((1 + 5*rows[c] + 7*k) * (2 + 11*k + 13*cols[c]));
      t[c] = 2.0 * acc;
    }
    if (d[q] != t[0]) ok0 = false;
    if (d[q] != t[1]) ok1 = false;
    if (d[q] != t[2]) ok2 = false;
    if (d[q] != t[3]) ok3 = false;
  }
  unsigned long long m0 = __ballot(ok0), m1 = __ballot(ok1);
  unsigned long long m2 = __ballot(ok2), m3 = __ballot(ok3);
  if (l == 0) {
    const unsigned long long ALL = 0xFFFFFFFFFFFFFFFFULL;
    int fl = 4;
    if (m0 == ALL) fl = 0;
    else if (m1 == ALL) fl = 1;
    else if (m2 == ALL) fl = 2;
    else if (m3 == ALL) fl = 3;
    flag[0] = fl;
  }
#else
  if (threadIdx.x == 0) flag[0] = 4;
#endif
}

// flag reporters: exactly one spins ~130us; its NAME in the profile = flag.
#define REP_KERNEL(NAME, VAL)                                               \
__global__ void NAME(const int* flag, double* sink) {                      \
  if (*flag != VAL) return;                                                 \
  double x = 1.0;                                                           \
  for (int i = 0; i < 80000; ++i) x = fma(x, 1.0000000000001, 1e-300);      \
  if (threadIdx.x == 0) sink[0] = x;                                        \
}
REP_KERNEL(k_rep0, 0)
REP_KERNEL(k_rep1, 1)
REP_KERNEL(k_rep2, 2)
REP_KERNEL(k_rep3, 3)
REP_KERNEL(k_rep4, 4)

// ===================== setup kernels =====================
__global__ void k_keys(unsigned* keys)
{
  if (threadIdx.x != 0 || blockIdx.x != 0) return;
  unsigned a0,a1,b0,b1,c0,c1,d0,d1;
  unsigned kx = 0u, ky = 42u;                 // jax.random.key(42)
  threefry2x32(kx, ky, 0u, 0u, a0, a1);       // carried key
  threefry2x32(kx, ky, 0u, 1u, b0, b1);       // k0 (h0 uniform)
  keys[0] = b0; keys[1] = b1;
  kx = a0; ky = a1;
  for (int s = 0; s < 100; ++s) {
    threefry2x32(kx, ky, 0u, 0u, a0, a1);     // k
    threefry2x32(kx, ky, 0u, 1u, c0, c1);     // ke
    threefry2x32(kx, ky, 0u, 2u, d0, d1);     // kr
    keys[2 + 4*s + 0] = c0; keys[2 + 4*s + 1] = c1;
    keys[2 + 4*s + 2] = d0; keys[2 + 4*s + 3] = d1;
    kx = a0; ky = a1;
  }
}

__global__ __launch_bounds__(256) void k_prep(
    const float* fcz_w, const float* fcz_b, const float* fcr_w, const float* fcr_b,
    const float* fcn_w, const float* fcn_b, const float* fco_w, const float* fco_b,
    const float* h2l_w, const float* h2l_b,
    double* wzrT, double* wnT, double* wo, double* bz, double* br,
    double* bnn, double* bo, double* h2lw, double* h2lb)
{
  int id = blockIdx.x * 256 + threadIdx.x;
  if (id < 65536) {
    int k = id >> 8, j = id & 255;
    wzrT[id] = (double)((j < 128) ? fcz_w[j*256 + k] : fcr_w[(j-128)*256 + k]);
    return;
  }
  id -= 65536;
  if (id < 65536) { int k = id >> 8, j = id & 255; wnT[id] = (double)fcn_w[j*256 + k]; return; }
  id -= 65536;
  if (id < 256) { wo[id] = (double)fco_w[id]; return; }
  id -= 256;
  if (id < 128) { bz[id] = (double)fcz_b[id]; return; }
  id -= 128;
  if (id < 128) { br[id] = (double)fcr_b[id]; return; }
  id -= 128;
  if (id < 256) { bnn[id] = (double)fcn_b[id]; return; }
  id -= 256;
  if (id < 1) { bo[0] = (double)fco_b[0]; return; }
  id -= 1;
  if (id < 384) { h2lw[id] = (double)h2l_w[id]; return; }
  id -= 384;
  if (id < 3) { h2lb[id] = (double)h2l_b[id]; return; }
}

__global__ __launch_bounds__(256) void k_h0(const unsigned* keys, double* h, double* p)
{
  unsigned e = blockIdx.x * 256 + threadIdx.x;    // < 524288
  h[e] = (double)bits_to_unit(rand_word(keys[0], keys[1], e));
  if (e < 4096) p[e] = (double)(float)log(1.0 / 128.0);
}

// ===================== frontend (map CNN encoder) =====================
__global__ __launch_bounds__(256) void k_conv1(const float* in, const float* w, double* out)
{
  int bc = blockIdx.x; int b = bc >> 4, co = bc & 15;
  __shared__ double wl[25];
  __shared__ float plf[4096];
  if (threadIdx.x < 25) wl[threadIdx.x] = (double)w[co*25 + threadIdx.x];
  const float* ib = in + (size_t)b * 4096;
  for (int j = 0; j < 16; ++j) plf[threadIdx.x + j*256] = ib[threadIdx.x + j*256];
  __syncthreads();
  for (int q = 0; q < 4; ++q) {
    int px = q*256 + threadIdx.x;
    int oh = px >> 5, ow = px & 31;
    double acc = 0.0;
    for (int kh = 0; kh < 5; ++kh) {
      int ih = oh*2 - 2 + kh; if (ih < 0 || ih >= 64) continue;
      for (int kw = 0; kw < 5; ++kw) {
        int iw = ow*2 - 2 + kw; if (iw < 0 || iw >= 64) continue;
        acc = fma((double)plf[ih*64 + iw], wl[kh*5 + kw], acc);
      }
    }
    out[((size_t)b*16 + co)*1024 + px] = fmax(acc, 0.0);
  }
}

// 2 output channels per block: input planes read once per pair
__global__ __launch_bounds__(256) void k_conv3x3(const double* in, const float* w,
                                                 double* out, int Ci, int Co)
{
  int bc = blockIdx.x; int b = bc / (Co >> 1), cop = bc % (Co >> 1);
  int co0 = cop * 2;
  __shared__ double wl0[288], wl1[288];
  __shared__ double pl[2][1024];
  for (int e = threadIdx.x; e < Ci*9; e += 256) {
    wl0[e] = (double)w[(size_t)co0*Ci*9 + e];
    wl1[e] = (double)w[(size_t)(co0 + 1)*Ci*9 + e];
  }
  double acc0[4] = {0.0, 0.0, 0.0, 0.0};
  double acc1[4] = {0.0, 0.0, 0.0, 0.0};
  const double* ib = in + (size_t)b * Ci * 1024;
  for (int q = 0; q < 4; ++q)
    pl[0][threadIdx.x + q*256] = ib[threadIdx.x + q*256];
  __syncthreads();
  for (int ci = 0; ci < Ci; ++ci) {
    int cur = ci & 1;
    if (ci + 1 < Ci) {
      for (int q = 0; q < 4; ++q)
        pl[cur ^ 1][threadIdx.x + q*256] = ib[(ci + 1)*1024 + threadIdx.x + q*256];
    }
    const double* wp0 = wl0 + ci*9;
    const double* wp1 = wl1 + ci*9;
    for (int q = 0; q < 4; ++q) {
      int px = q*256 + threadIdx.x;
      int oh = px >> 5, ow = px & 31;
      double a0 = acc0[q], a1 = acc1[q];
      for (int kh = 0; kh < 3; ++kh) {
        int ih = oh - 1 + kh; if (ih < 0 || ih >= 32) continue;
        for (int kw = 0; kw < 3; ++kw) {
          int iw = ow - 1 + kw; if (iw < 0 || iw >= 32) continue;
          double pv = pl[cur][ih*32 + iw];
          a0 = fma(pv, wp0[kh*3 + kw], a0);
          a1 = fma(pv, wp1[kh*3 + kw], a1);
        }
      }
      acc0[q] = a0; acc1[q] = a1;
    }
    __syncthreads();
  }
  for (int q = 0; q < 4; ++q) {
    int px = q*256 + threadIdx.x;
    out[((size_t)b*Co + co0)*1024 + px]     = fmax(acc0[q], 0.0);
    out[((size_t)b*Co + co0 + 1)*1024 + px] = fmax(acc1[q], 0.0);
  }
}

__global__ __launch_bounds__(256) void k_bnstats1(const double* __restrict__ x,
    double* __restrict__ partS, double* __restrict__ partS2, int C)
{
  int c = blockIdx.x >> 3, chunk = blockIdx.x & 7;
  double s = 0.0, s2 = 0.0;
  for (int e = threadIdx.x; e < 4096; e += 256) {
    int b = chunk*4 + (e >> 10), px = e & 1023;
    double v = x[((size_t)b*C + c)*1024 + px];
    s += v; s2 = fma(v, v, s2);
  }
  __shared__ double rs[256], rs2[256];
  rs[threadIdx.x] = s; rs2[threadIdx.x] = s2;
  __syncthreads();
  for (int d = 128; d; d >>= 1) {
    if (threadIdx.x < d) { rs[threadIdx.x] += rs[threadIdx.x + d]; rs2[threadIdx.x] += rs2[threadIdx.x + d]; }
    __syncthreads();
  }
  if (threadIdx.x == 0) { partS[blockIdx.x] = rs[0]; partS2[blockIdx.x] = rs2[0]; }
}

__global__ void k_bnstats2(const double* __restrict__ partS,
                           const double* __restrict__ partS2,
                           const float* g, const float* bta, double* scsh, int C)
{
  int c = threadIdx.x;
  if (c >= C) return;
  double s = 0.0, s2 = 0.0;
  for (int j = 0; j < 8; ++j) { s += partS[c*8 + j]; s2 += partS2[c*8 + j]; }
  double n = 32768.0;
  double mean = s / n;
  double var = s2 / n - mean*mean;
  double sc = (double)g[c] / sqrt(var + 1e-5);
  scsh[c*2] = sc;
  scsh[c*2 + 1] = (double)bta[c] - mean * sc;
}

__global__ __launch_bounds__(256) void k_bnapply(double* x, const double* scsh, int C)
{
  size_t e = (size_t)blockIdx.x * 256 + threadIdx.x;
  int c = (int)((e >> 10) % (size_t)C);
  x[e] = fma(x[e], scsh[c*2], scsh[c*2 + 1]);
}

__global__ __launch_bounds__(256) void k_mapfc(const double* x, const float* w,
                                               const float* bias, double* emb)
{
  int blk = blockIdx.x; int b = blk >> 4, jg = blk & 15;
  double acc[8];
  #pragma unroll
  for (int jj = 0; jj < 8; ++jj) acc[jj] = 0.0;
  const double* xb = x + (size_t)b * 32768;
  for (int e = threadIdx.x; e < 32768; e += 256) {
    double xv = xb[e];
    #pragma unroll
    for (int jj = 0; jj < 8; ++jj)
      acc[jj] = fma(xv, (double)w[(size_t)(jg*8 + jj)*32768 + e], acc[jj]);
  }
  __shared__ double red[8][256];
  #pragma unroll
  for (int jj = 0; jj < 8; ++jj) red[jj][threadIdx.x] = acc[jj];
  __syncthreads();
  for (int d = 128; d; d >>= 1) {
    if (threadIdx.x < d)
      #pragma unroll
      for (int jj = 0; jj < 8; ++jj) red[jj][threadIdx.x] += red[jj][threadIdx.x + d];
    __syncthreads();
  }
  if (threadIdx.x < 8) {
    int j = jg*8 + threadIdx.x;
    emb[b*128 + j] = fmax(red[threadIdx.x][0] + (double)bias[j], 0.0);
  }
}

__global__ void k_maps(const double* emb, const float* m2o_w, const float* m2o_b,
                       const float* m2a_w, const float* m2a_b,
                       double* omap, double* amap)
{
  int b = blockIdx.x, j = threadIdx.x;   // 64 threads
  double a1 = (double)m2o_b[j], a2 = (double)m2a_b[j];
  for (int k = 0; k < 128; ++k) {
    double ev = emb[b*128 + k];
    a1 = fma(ev, (double)m2o_w[j*128 + k], a1);
    a2 = fma(ev, (double)m2a_w[j*128 + k], a2);
  }
  omap[b*64 + j] = fmax(a1, 0.0);
  amap[b*64 + j] = fmax(a2, 0.0);
}

__global__ __launch_bounds__(128) void k_xs(const float* obs_in, const float* act_in,
                                            const float* obs_w, const float* obs_b,
                                            const float* act_w, const float* act_b,
                                            const double* omap, const double* amap,
                                            const double* wo,
                                            double* xs, double* xo)
{
  int s = blockIdx.x, b = blockIdx.y, j = threadIdx.x;
  double v;
  if (j < 64) {
    double a = (double)obs_b[j];
    const float* o = obs_in + ((size_t)b*100 + s)*16;
    for (int k = 0; k < 16; ++k) a = fma((double)o[k], (double)obs_w[j*16 + k], a);
    v = fmax(a, 0.0) * omap[b*64 + j];
  } else {
    int j2 = j - 64;
    double a = (double)act_b[j2];
    const float* o = act_in + ((size_t)b*100 + s)*3;
    for (int k = 0; k < 3; ++k) a = fma((double)o[k], (double)act_w[j2*3 + k], a);
    v = fmax(a, 0.0) * amap[b*64 + j2];
  }
  xs[((size_t)s*32 + b)*128 + j] = v;
  __shared__ double red[128];
  red[j] = v * wo[128 + j];
  __syncthreads();
  for (int d = 64; d; d >>= 1) {
    if (j < d) red[j] += red[j + d];
    __syncthreads();
  }
  if (j == 0) xo[s*32 + b] = red[0];
}

__global__ __launch_bounds__(256, 2) void k_xpre2(const double* __restrict__ xs,
    const double* __restrict__ wzrT, const double* __restrict__ wnT,
    double* __restrict__ xzr, double* __restrict__ xn)
{
  int s = blockIdx.x >> 2, bg = blockIdx.x & 3;
  __shared__ double xl[8][128];
  int t = threadIdx.x;
  #pragma unroll
  for (int j = 0; j < 4; ++j) {
    int e = t + j*256;
    int i = e >> 7, cc = e & 127;
    xl[i][cc] = xs[((size_t)s*32 + bg*8 + i)*128 + cc];
  }
  __syncthreads();
  double az[8], an[8];
  #pragma unroll
  for (int i = 0; i < 8; ++i) { az[i] = 0.0; an[i] = 0.0; }
  for (int k = 0; k < 128; ++k) {
    double wz = wzrT[k*256 + t];
    double wn = wnT[(128 + k)*256 + t];
    #pragma unroll
    for (int i = 0; i < 8; ++i) {
      double xv = xl[i][k];
      az[i] = fma(xv, wz, az[i]);
      an[i] = fma(xv, wn, an[i]);
    }
  }
  #pragma unroll
  for (int i = 0; i < 8; ++i) {
    size_t sb = (size_t)s*32 + bg*8 + i;
    xzr[sb*256 + t] = az[i];
    xn [sb*256 + t] = an[i];
  }
}

// ===================== scan kernels =====================
// k_stepV: R9's verified vector kernel (bit-exact).  Runs when flag NOT in 1..3.
__global__ __launch_bounds__(512, 2) void k_stepV(
    const double* __restrict__ hsrc, const int* __restrict__ idxp,
    const double* __restrict__ xzr, const double* __restrict__ xn,
    const double* __restrict__ xo,
    const double* __restrict__ wzrT, const double* __restrict__ wnT,
    const double* __restrict__ bz, const double* __restrict__ br,
    const double* __restrict__ bnn, const double* __restrict__ wo,
    const double* __restrict__ bo, double* __restrict__ P,
    const double* __restrict__ h2lw, const double* __restrict__ h2lb,
    double* __restrict__ h1out, double* __restrict__ LP,
    const double* __restrict__ PNPRE,
    float* __restrict__ pfout, float* __restrict__ yout,
    const unsigned* __restrict__ keys, int s, const int* __restrict__ flagp)
{
  {
    int f = *flagp;
    if (f >= 1 && f <= 3) return;
  }
  __shared__ double ah[16][128];   // gathered h
  __shared__ double aw[16][128];   // rg*h, later h1
  __shared__ double wsh[128], ys[128], red8[8][128];
  __shared__ int    isx[128];
  __shared__ double smx[2], ssx[2];
  const int t  = threadIdx.x;
  const int rq = t >> 7;           // 0..3: rows rq*4 .. rq*4+3
  const int c2 = t & 127;          // cols c2, c2+128
  const int r0 = blockIdx.x * 16;
  const int wv = t >> 6, lane = t & 63;
  const bool first = (idxp == nullptr);

  // ---- phase C of step s-1 (blocks 0..31): pn normalize + y ----
  if (!first && blockIdx.x < 32) {
    int b = blockIdx.x;
    if (t < 128) {
      double q = PNPRE[b*128 + t];
      double m = q;
      for (int d = 32; d; d >>= 1) m = fmax(m, __shfl_xor(m, d, 64));
      if ((t & 63) == 0) smx[t >> 6] = m;
    }
    __syncthreads();
    if (t < 128) {
      double q = PNPRE[b*128 + t];
      double m = fmax(smx[0], smx[1]);
      double e = exp(q - m), su = e;
      for (int d = 32; d; d >>= 1) su += __shfl_xor(su, d, 64);
      if ((t & 63) == 0) ssx[t >> 6] = su;
    }
    __syncthreads();
    if (t < 128) {
      double q = PNPRE[b*128 + t];
      double m = fmax(smx[0], smx[1]);
      double pn = q - (m + log(ssx[0] + ssx[1]));
      P[b*128 + t] = pn;
      wsh[t] = exp(pn);
      isx[t] = idxp[t*32 + b];
    }
    __syncthreads();
    {
      #pragma unroll
      for (int colh = 0; colh < 2; ++colh) {
        int col = lane + colh*64;
        double acc = 0.0;
        for (int q = 0; q < 16; ++q) {
          int ii = wv*16 + q;
          acc = fma(wsh[ii], hsrc[(size_t)(isx[ii]*32 + b)*128 + col], acc);
        }
        red8[wv][col] = acc;
      }
    }
    __syncthreads();
    if (t < 128) {
      double a = red8[0][t];
      for (int gg = 1; gg < 8; ++gg) a += red8[gg][t];
      ys[t] = a;
    }
    __syncthreads();
    if (t < 3) {
      double dsum = h2lb[t];
      for (int cc = 0; cc < 128; ++cc)
        dsum = fma(h2lw[t*128 + cc], ys[cc], dsum);
      yout[(s - 1)*96 + b*3 + t] = (float)(1.0 / (1.0 + exp(-dsum)));
    }
    __syncthreads();
  }

  // ---- gather prev h (4 elements/thread, coalesced) ----
  #pragma unroll
  for (int j = 0; j < 4; ++j) {
    int e = t + j*512;
    int r = e >> 7, cc = e & 127;
    int R = r0 + r, b = R & 31;
    int src = first ? R : (idxp[R]*32 + b);
    ah[r][cc] = hsrc[(size_t)src*128 + cc];
  }
  __syncthreads();
  // ---- pf for previous step: 8 waves x 2 rows ----
  if (pfout != nullptr) {
    #pragma unroll
    for (int q = 0; q < 2; ++q) {
      int i = wv*2 + q;
      double v0 = ah[i][lane*2], v1 = ah[i][lane*2 + 1];
      double s0 = fma(v0, h2lw[lane*2],       v1 * h2lw[lane*2 + 1]);
      double s1 = fma(v0, h2lw[128 + lane*2], v1 * h2lw[128 + lane*2 + 1]);
      double s2 = fma(v0, h2lw[256 + lane*2], v1 * h2lw[256 + lane*2 + 1]);
      for (int d = 32; d; d >>= 1) {
        s0 += __shfl_xor(s0, d, 64);
        s1 += __shfl_xor(s1, d, 64);
        s2 += __shfl_xor(s2, d, 64);
      }
      if (lane == 0) {
        float* o = pfout + (r0 + i) * 3;
        o[0] = (float)(1.0 / (1.0 + exp(-(s0 + h2lb[0]))));
        o[1] = (float)(1.0 / (1.0 + exp(-(s1 + h2lb[1]))));
        o[2] = (float)(1.0 / (1.0 + exp(-(s2 + h2lb[2]))));
      }
    }
  }
  // ---- GEMM1: h-part of [x|h] @ Wzr^T; 4 rows x 2 cols/thread ----
  double ac0[4], ac1[4];
  #pragma unroll
  for (int i = 0; i < 4; ++i) { ac0[i] = 0.0; ac1[i] = 0.0; }
  {
    const double2v* ap0 = (const double2v*)&ah[rq*4 + 0][0];
    const double2v* ap1 = (const double2v*)&ah[rq*4 + 1][0];
    const double2v* ap2 = (const double2v*)&ah[rq*4 + 2][0];
    const double2v* ap3 = (const double2v*)&ah[rq*4 + 3][0];
    for (int k2 = 0; k2 < 64; ++k2) {
      const double* wr0 = &wzrT[(128 + 2*k2)*256];
      const double* wr1 = &wzrT[(128 + 2*k2 + 1)*256];
      double w00 = wr0[c2],       w01 = wr1[c2];
      double w10 = wr0[c2 + 128], w11 = wr1[c2 + 128];
      double2v A0 = ap0[k2], A1 = ap1[k2], A2 = ap2[k2], A3 = ap3[k2];
      ac0[0] = fma(A0.y, w01, fma(A0.x, w00, ac0[0]));
      ac1[0] = fma(A0.y, w11, fma(A0.x, w10, ac1[0]));
      ac0[1] = fma(A1.y, w01, fma(A1.x, w00, ac0[1]));
      ac1[1] = fma(A1.y, w11, fma(A1.x, w10, ac1[1]));
      ac0[2] = fma(A2.y, w01, fma(A2.x, w00, ac0[2]));
      ac1[2] = fma(A2.y, w11, fma(A2.x, w10, ac1[2]));
      ac0[3] = fma(A3.y, w01, fma(A3.x, w00, ac0[3]));
      ac1[3] = fma(A3.y, w11, fma(A3.x, w10, ac1[3]));
    }
  }
  double zrv[4];
  {
    double bzv = bz[c2], brv = br[c2];
    #pragma unroll
    for (int i = 0; i < 4; ++i) {
      int row = rq*4 + i;
      int b = (r0 + row) & 31;
      zrv[i] = sigd(ac0[i] + xzr[b*256 + c2] + bzv);
      double rgv = sigd(ac1[i] + xzr[b*256 + c2 + 128] + brv);
      aw[row][c2] = rgv * ah[row][c2];
    }
  }
  __syncthreads();
  // ---- GEMM2: (rg*h)-part of [rg*h|x] @ Wn^T ----
  #pragma unroll
  for (int i = 0; i < 4; ++i) { ac0[i] = 0.0; ac1[i] = 0.0; }
  {
    const double2v* ap0 = (const double2v*)&aw[rq*4 + 0][0];
    const double2v* ap1 = (const double2v*)&aw[rq*4 + 1][0];
    const double2v* ap2 = (const double2v*)&aw[rq*4 + 2][0];
    const double2v* ap3 = (const double2v*)&aw[rq*4 + 3][0];
    for (int k2 = 0; k2 < 64; ++k2) {
      const double* wr0 = &wnT[(2*k2)*256];
      const double* wr1 = &wnT[(2*k2 + 1)*256];
      double w00 = wr0[c2],       w01 = wr1[c2];
      double w10 = wr0[c2 + 128], w11 = wr1[c2 + 128];
      double2v A0 = ap0[k2], A1 = ap1[k2], A2 = ap2[k2], A3 = ap3[k2];
      ac0[0] = fma(A0.y, w01, fma(A0.x, w00, ac0[0]));
      ac1[0] = fma(A0.y, w11, fma(A0.x, w10, ac1[0]));
      ac0[1] = fma(A1.y, w01, fma(A1.x, w00, ac0[1]));
      ac1[1] = fma(A1.y, w11, fma(A1.x, w10, ac1[1]));
      ac0[2] = fma(A2.y, w01, fma(A2.x, w00, ac0[2]));
      ac1[2] = fma(A2.y, w11, fma(A2.x, w10, ac1[2]));
      ac0[3] = fma(A3.y, w01, fma(A3.x, w00, ac0[3]));
      ac1[3] = fma(A3.y, w11, fma(A3.x, w10, ac1[3]));
    }
  }
  double hv[4];
  {
    unsigned keA = keys[2 + 4*s], keB = keys[2 + 4*s + 1];
    double bn0 = bnn[c2], bn1 = bnn[c2 + 128];
    #pragma unroll
    for (int i = 0; i < 4; ++i) {
      int row = rq*4 + i, R = r0 + row;
      int b = R & 31;
      double mu  = ac0[i] + xn[b*256 + c2] + bn0;
      double var = ac1[i] + xn[b*256 + c2 + 128] + bn1;
      double sp = fmax(var, 0.0) + log1p(exp(-fabs(var)));
      double ep = eps_normal(keA, keB, (unsigned)(R*128 + c2));
      double n  = fma(ep, sp, mu);
      hv[i] = (1.0 - zrv[i])*n + zrv[i]*ah[row][c2];
      h1out[(size_t)R*128 + c2] = hv[i];
    }
  }
  __syncthreads();
  #pragma unroll
  for (int i = 0; i < 4; ++i) aw[rq*4 + i][c2] = hv[i];
  __syncthreads();
  // ---- logpdf partial (without +p): 8 waves x 2 rows ----
  {
    #pragma unroll
    for (int q = 0; q < 2; ++q) {
      int row = wv*2 + q, R = r0 + row, b = R & 31;
      double part = fma(aw[row][lane], wo[lane], aw[row][lane + 64] * wo[lane + 64]);
      for (int d = 32; d; d >>= 1) part += __shfl_xor(part, d, 64);
      if (lane == 0) LP[b*128 + (R >> 5)] = part + xo[b] + bo[0];
    }
  }
}

// k_stepM: MFMA kernel with probe-selected D mapping.  Runs when flag in 1..3.
__global__ __launch_bounds__(512, 1) void k_stepM(
    const double* __restrict__ hsrc, const int* __restrict__ idxp,
    const double* __restrict__ xzr, const double* __restrict__ xn,
    const double* __restrict__ xo,
    const double* __restrict__ wzrT, const double* __restrict__ wnT,
    const double* __restrict__ bz, const double* __restrict__ br,
    const double* __restrict__ bnn, const double* __restrict__ wo,
    const double* __restrict__ bo, double* __restrict__ P,
    const double* __restrict__ h2lw, const double* __restrict__ h2lb,
    double* __restrict__ h1out, double* __restrict__ LP,
    const double* __restrict__ PNPRE,
    float* __restrict__ pfout, float* __restrict__ yout,
    const unsigned* __restrict__ keys, int s, const int* __restrict__ flagp)
{
  const int f = *flagp;
  if (f < 1 || f > 3) return;
#ifdef HAVE_MFMA_F64
  __shared__ double ah [16][129];
  __shared__ double aw [16][129];
  __shared__ double zsh[16][129];
  __shared__ double sps[16][129];
  __shared__ double mus[16][129];
  __shared__ double wsh[128], ys[128], red8[8][128];
  __shared__ int    isx[128];
  __shared__ double smx[2], ssx[2];
  const int t  = threadIdx.x;
  const int r0 = blockIdx.x * 16;
  const int wv = t >> 6, lane = t & 63;
  const int mrow = lane & 15;
  const int kgrp = lane >> 4;
  const bool first = (idxp == nullptr);

  if (!first && blockIdx.x < 32) {
    int b = blockIdx.x;
    if (t < 128) {
      double q = PNPRE[b*128 + t];
      double m = q;
      for (int d = 32; d; d >>= 1) m = fmax(m, __shfl_xor(m, d, 64));
      if ((t & 63) == 0) smx[t >> 6] = m;
    }
    __syncthreads();
    if (t < 128) {
      double q = PNPRE[b*128 + t];
      double m = fmax(smx[0], smx[1]);
      double e = exp(q - m), su = e;
      for (int d = 32; d; d >>= 1) su += __shfl_xor(su, d, 64);
      if ((t & 63) == 0) ssx[t >> 6] = su;
    }
    __syncthreads();
    if (t < 128) {
      double q = PNPRE[b*128 + t];
      double m = fmax(smx[0], smx[1]);
      double pn = q - (m + log(ssx[0] + ssx[1]));
      P[b*128 + t] = pn;
      wsh[t] = exp(pn);
      isx[t] = idxp[t*32 + b];
    }
    __syncthreads();
    {
      #pragma unroll
      for (int colh = 0; colh < 2; ++colh) {
        int col = lane + colh*64;
        double acc = 0.0;
        for (int q = 0; q < 16; ++q) {
          int ii = wv*16 + q;
          acc = fma(wsh[ii], hsrc[(size_t)(isx[ii]*32 + b)*128 + col], acc);
        }
        red8[wv][col] = acc;
      }
    }
    __syncthreads();
    if (t < 128) {
      double a = red8[0][t];
      for (int gg = 1; gg < 8; ++gg) a += red8[gg][t];
      ys[t] = a;
    }
    __syncthreads();
    if (t < 3) {
      double dsum = h2lb[t];
      for (int cc = 0; cc < 128; ++cc)
        dsum = fma(h2lw[t*128 + cc], ys[cc], dsum);
      yout[(s - 1)*96 + b*3 + t] = (float)(1.0 / (1.0 + exp(-dsum)));
    }
    __syncthreads();
  }

  #pragma unroll
  for (int j = 0; j < 4; ++j) {
    int e = t + j*512;
    int r = e >> 7, cc = e & 127;
    int R = r0 + r, b = R & 31;
    int src = first ? R : (idxp[R]*32 + b);
    ah[r][cc] = hsrc[(size_t)src*128 + cc];
  }
  __syncthreads();
  if (pfout != nullptr) {
    #pragma unroll
    for (int q = 0; q < 2; ++q) {
      int i = wv*2 + q;
      double v0 = ah[i][lane*2], v1 = ah[i][lane*2 + 1];
      double s0 = fma(v0, h2lw[lane*2],       v1 * h2lw[lane*2 + 1]);
      double s1 = fma(v0, h2lw[128 + lane*2], v1 * h2lw[128 + lane*2 + 1]);
      double s2 = fma(v0, h2lw[256 + lane*2], v1 * h2lw[256 + lane*2 + 1]);
      for (int d = 32; d; d >>= 1) {
        s0 += __shfl_xor(s0, d, 64);
        s1 += __shfl_xor(s1, d, 64);
        s2 += __shfl_xor(s2, d, 64);
      }
      if (lane == 0) {
        float* o = pfout + (r0 + i) * 3;
        o[0] = (float)(1.0 / (1.0 + exp(-(s0 + h2lb[0]))));
        o[1] = (float)(1.0 / (1.0 + exp(-(s1 + h2lb[1]))));
        o[2] = (float)(1.0 / (1.0 + exp(-(s2 + h2lb[2]))));
      }
    }
  }
  // ---- GEMM1 (MFMA) ----
  double4v acc0 = {0.0, 0.0, 0.0, 0.0};
  double4v acc1 = {0.0, 0.0, 0.0, 0.0};
  for (int k4 = 0; k4 < 32; ++k4) {
    int k = k4*4 + kgrp;
    double a  = ah[mrow][k];
    double b0 = wzrT[(size_t)(128 + k)*256 + wv*16 + mrow];
    double b1 = wzrT[(size_t)(128 + k)*256 + 128 + wv*16 + mrow];
    acc0 = __builtin_amdgcn_mfma_f64_16x16x4f64(a, b0, acc0, 0, 0, 0);
    acc1 = __builtin_amdgcn_mfma_f64_16x16x4f64(a, b1, acc1, 0, 0, 0);
  }
  #pragma unroll
  for (int q = 0; q < 4; ++q) {
    int row, col;
    if (f == 1)      { row = kgrp + 4*q; col = wv*16 + mrow; }
    else if (f == 2) { row = mrow;       col = wv*16 + kgrp*4 + q; }
    else             { row = mrow;       col = wv*16 + kgrp + 4*q; }
    int b = (r0 + row) & 31;
    zsh[row][col] = sigd(acc0[q] + xzr[b*256 + col] + bz[col]);
    double rgv = sigd(acc1[q] + xzr[b*256 + 128 + col] + br[col]);
    aw[row][col] = rgv * ah[row][col];
  }
  __syncthreads();
  // ---- GEMM2 (MFMA) ----
  acc0 = double4v{0.0, 0.0, 0.0, 0.0};
  acc1 = double4v{0.0, 0.0, 0.0, 0.0};
  for (int k4 = 0; k4 < 32; ++k4) {
    int k = k4*4 + kgrp;
    double a  = aw[mrow][k];
    double b0 = wnT[(size_t)k*256 + wv*16 + mrow];
    double b1 = wnT[(size_t)k*256 + 128 + wv*16 + mrow];
    acc0 = __builtin_amdgcn_mfma_f64_16x16x4f64(a, b0, acc0, 0, 0, 0);
    acc1 = __builtin_amdgcn_mfma_f64_16x16x4f64(a, b1, acc1, 0, 0, 0);
  }
  #pragma unroll
  for (int q = 0; q < 4; ++q) {
    int row, col;
    if (f == 1)      { row = kgrp + 4*q; col = wv*16 + mrow; }
    else if (f == 2) { row = mrow;       col = wv*16 + kgrp*4 + q; }
    else             { row = mrow;       col = wv*16 + kgrp + 4*q; }
    int b = (r0 + row) & 31;
    mus[row][col] = acc0[q] + xn[b*256 + col] + bnn[col];
    double var = acc1[q] + xn[b*256 + 128 + col] + bnn[128 + col];
    sps[row][col] = fmax(var, 0.0) + log1p(exp(-fabs(var)));
  }
  __syncthreads();
  {
    unsigned keA = keys[2 + 4*s], keB = keys[2 + 4*s + 1];
    #pragma unroll
    for (int j = 0; j < 4; ++j) {
      int e = t + j*512;
      int r = e >> 7, cc = e & 127;
      int R = r0 + r;
      double ep = eps_normal(keA, keB, (unsigned)(R*128 + cc));
      double n  = fma(ep, sps[r][cc], mus[r][cc]);
      double z  = zsh[r][cc];
      double hv = (1.0 - z)*n + z*ah[r][cc];
      h1out[(size_t)R*128 + cc] = hv;
      mus[r][cc] = hv;
    }
  }
  __syncthreads();
  {
    #pragma unroll
    for (int q = 0; q < 2; ++q) {
      int row = wv*2 + q, R = r0 + row, b = R & 31;
      double part = fma(mus[row][lane], wo[lane], mus[row][lane + 64] * wo[lane + 64]);
      for (int d = 32; d; d >>= 1) part += __shfl_xor(part, d, 64);
      if (lane == 0) LP[b*128 + (R >> 5)] = part + xo[b] + bo[0];
    }
  }
#endif
}

// k_sr: barrier-free per-wave softmax + Gumbel-argmax.
__global__ __launch_bounds__(512, 4) void k_sr(
    const double* __restrict__ LP, const double* __restrict__ P,
    const unsigned* __restrict__ keys, int s,
    int* __restrict__ idx, double* __restrict__ PNPRE)
{
  int t = threadIdx.x;
  int wv = t >> 6, lane = t & 63;
  int rw = blockIdx.x * 8 + wv;
  int bw = rw & 31;
  unsigned kA = keys[2 + 4*s + 2], kB = keys[2 + 4*s + 3];
  double v0 = LP[bw*128 + lane]      + P[bw*128 + lane];
  double v1 = LP[bw*128 + lane + 64] + P[bw*128 + lane + 64];
  double m0 = v0, m1 = v1;
  for (int d = 32; d; d >>= 1) {
    m0 = fmax(m0, __shfl_xor(m0, d, 64));
    m1 = fmax(m1, __shfl_xor(m1, d, 64));
  }
  double m = fmax(m0, m1);
  double e0 = exp(v0 - m), e1 = exp(v1 - m);
  double s0 = e0, s1 = e1;
  for (int d = 32; d; d >>= 1) {
    s0 += __shfl_xor(s0, d, 64);
    s1 += __shfl_xor(s1, d, 64);
  }
  double lse = log(s0 + s1);
  double p1_0 = v0 - m - lse;
  double p1_1 = v1 - m - lse;
  double lg0 = log(0.5*exp(p1_0) + 0.00390625);
  double lg1 = log(0.5*exp(p1_1) + 0.00390625);
  double g0 = gumbel_d(kA, kB, (unsigned)(rw*128 + lane)) + lg0;
  double g1 = gumbel_d(kA, kB, (unsigned)(rw*128 + lane + 64)) + lg1;
  double val; int bj;
  if (g0 >= g1) { val = g0; bj = lane; } else { val = g1; bj = lane + 64; }
  for (int d = 32; d; d >>= 1) {
    double ov = __shfl_xor(val, d, 64);
    int    oj = __shfl_xor(bj, d, 64);
    if (ov > val || (ov == val && oj < bj)) { val = ov; bj = oj; }
  }
  double pl = __shfl(p1_0, bj & 63, 64);
  double ph = __shfl(p1_1, bj & 63, 64);
  if (lane == 0) {
    idx[rw] = bj;
    double p1b = (bj < 64) ? pl : ph;
    double pe = exp(p1b);
    PNPRE[bw*128 + (rw >> 5)] = log(pe / (0.5*pe + 0.00390625));
  }
}

// k_yfinal: phase C for step 99 (32 blocks x 512)
__global__ __launch_bounds__(512) void k_yfinal(
    const double* __restrict__ hlast, const int* __restrict__ idxp,
    const double* __restrict__ PNPRE, double* __restrict__ P,
    const double* __restrict__ h2lw, const double* __restrict__ h2lb,
    float* __restrict__ yout)
{
  __shared__ double wsh[128], ys[128], red8[8][128];
  __shared__ int    isx[128];
  __shared__ double smx[2], ssx[2];
  int t = threadIdx.x, b = blockIdx.x;
  int wv = t >> 6, lane = t & 63;
  if (t < 128) {
    double q = PNPRE[b*128 + t];
    double m = q;
    for (int d = 32; d; d >>= 1) m = fmax(m, __shfl_xor(m, d, 64));
    if ((t & 63) == 0) smx[t >> 6] = m;
  }
  __syncthreads();
  if (t < 128) {
    double q = PNPRE[b*128 + t];
    double m = fmax(smx[0], smx[1]);
    double e = exp(q - m), su = e;
    for (int d = 32; d; d >>= 1) su += __shfl_xor(su, d, 64);
    if ((t & 63) == 0) ssx[t >> 6] = su;
  }
  __syncthreads();
  if (t < 128) {
    double q = PNPRE[b*128 + t];
    double m = fmax(smx[0], smx[1]);
    double pn = q - (m + log(ssx[0] + ssx[1]));
    P[b*128 + t] = pn;
    wsh[t] = exp(pn);
    isx[t] = idxp[t*32 + b];
  }
  __syncthreads();
  #pragma unroll
  for (int colh = 0; colh < 2; ++colh) {
    int col = lane + colh*64;
    double acc = 0.0;
    for (int q = 0; q < 16; ++q) {
      int ii = wv*16 + q;
      acc = fma(wsh[ii], hlast[(size_t)(isx[ii]*32 + b)*128 + col], acc);
    }
    red8[wv][col] = acc;
  }
  __syncthreads();
  if (t < 128) {
    double a = red8[0][t];
    for (int gg = 1; gg < 8; ++gg) a += red8[gg][t];
    ys[t] = a;
  }
  __syncthreads();
  if (t < 3) {
    double dsum = h2lb[t];
    for (int cc = 0; cc < 128; ++cc)
      dsum = fma(h2lw[t*128 + cc], ys[cc], dsum);
    yout[99*96 + b*3 + t] = (float)(1.0 / (1.0 + exp(-dsum)));
  }
}

// epilogue: pf for the last step (gather via idx)
__global__ __launch_bounds__(256) void k_pfend(const double* __restrict__ h1,
    const int* __restrict__ idx, const double* __restrict__ h2lw,
    const double* __restrict__ h2lb, float* __restrict__ pfout)
{
  int wv = threadIdx.x >> 6, lane = threadIdx.x & 63;
  int r = blockIdx.x * 4 + wv;
  int b = r & 31;
  const double* hr = h1 + (size_t)(idx[r]*32 + b) * 128;
  double v0 = hr[lane*2], v1 = hr[lane*2 + 1];
  double s0 = fma(v0, h2lw[lane*2],       v1 * h2lw[lane*2 + 1]);
  double s1 = fma(v0, h2lw[128 + lane*2], v1 * h2lw[128 + lane*2 + 1]);
  double s2 = fma(v0, h2lw[256 + lane*2], v1 * h2lw[256 + lane*2 + 1]);
  for (int d = 32; d; d >>= 1) {
    s0 += __shfl_xor(s0, d, 64);
    s1 += __shfl_xor(s1, d, 64);
    s2 += __shfl_xor(s2, d, 64);
  }
  if (lane == 0) {
    float* o = pfout + r * 3;
    o[0] = (float)(1.0 / (1.0 + exp(-(s0 + h2lb[0]))));
    o[1] = (float)(1.0 / (1.0 + exp(-(s1 + h2lb[1]))));
    o[2] = (float)(1.0 / (1.0 + exp(-(s2 + h2lb[2]))));
  }
}

// ===================== host launch =====================
extern "C" void kernel_launch(void* const* d_in, const int* in_sizes, int n_in,
                              void* d_out, int out_size, void* d_ws, size_t ws_size,
                              hipStream_t stream)
{
  (void)in_sizes; (void)n_in; (void)out_size; (void)ws_size;
  const float* map_in = (const float*)d_in[0];
  const float* obs_in = (const float*)d_in[1];
  const float* act_in = (const float*)d_in[2];
  const float* c1_w = (const float*)d_in[3];
  const float* c1_g = (const float*)d_in[4];
  const float* c1_b = (const float*)d_in[5];
  const float* c2_w = (const float*)d_in[6];
  const float* c2_g = (const float*)d_in[7];
  const float* c2_b = (const float*)d_in[8];
  const float* c3_w = (const float*)d_in[9];
  const float* c3_g = (const float*)d_in[10];
  const float* c3_b = (const float*)d_in[11];
  const float* map_w = (const float*)d_in[12];
  const float* map_b = (const float*)d_in[13];
  const float* m2o_w = (const float*)d_in[14];
  const float* m2o_b = (const float*)d_in[15];
  const float* m2a_w = (const float*)d_in[16];
  const float* m2a_b = (const float*)d_in[17];
  const float* obs_w = (const float*)d_in[18];
  const float* obs_b = (const float*)d_in[19];
  const float* act_w = (const float*)d_in[20];
  const float* act_b = (const float*)d_in[21];
  const float* fcz_w = (const float*)d_in[22];
  const float* fcz_b = (const float*)d_in[23];
  const float* fcr_w = (const float*)d_in[24];
  const float* fcr_b = (const float*)d_in[25];
  const float* fcn_w = (const float*)d_in[26];
  const float* fcn_b = (const float*)d_in[27];
  const float* fco_w = (const float*)d_in[28];
  const float* fco_b = (const float*)d_in[29];
  const float* h2l_w = (const float*)d_in[30];
  const float* h2l_b = (const float*)d_in[31];

  float* yout  = (float*)d_out;
  float* pfout = (float*)d_out + 9600;

  char* ws = (char*)d_ws;
  double*   H0     = (double*)(ws + 0);           // 4096*128
  double*   H1A    = (double*)(ws + 4194304);
  double*   H1B    = (double*)(ws + 8388608);
  double*   XS     = (double*)(ws + 12582912);    // 100*32*128
  double*   C1O    = (double*)(ws + 15859712);    // 32*16*1024
  double*   C2O    = (double*)(ws + 20054016);    // 32*32*1024
  double*   C3O    = (double*)(ws + 28442624);    // 32*32*1024
  double*   XZR    = (double*)(ws + 15859712);    // 100*32*256 (overlay)
  double*   XN     = (double*)(ws + 22413312);    // 100*32*256 (overlay)
  double*   XO     = (double*)(ws + 28966912);    // 100*32     (overlay)
  double*   WZRT   = (double*)(ws + 36831232);    // 256*256
  double*   WNT    = (double*)(ws + 37355520);
  double*   WO     = (double*)(ws + 37879808);
  double*   BZ     = (double*)(ws + 37881856);
  double*   BR     = (double*)(ws + 37882880);
  double*   BNN    = (double*)(ws + 37883904);
  double*   BO     = (double*)(ws + 37885952);
  double*   H2LW   = (double*)(ws + 37886208);
  double*   H2LB   = (double*)(ws + 37889280);
  double*   EMB    = (double*)(ws + 37889536);    // 32*128
  double*   OMAP   = (double*)(ws + 37922304);    // 32*64
  double*   AMAP   = (double*)(ws + 37938688);
  double*   P      = (double*)(ws + 37955072);    // 4096  [b][p]
  double*   LP     = (double*)(ws + 37987840);    // 4096  [b][p]
  int*      IDX    = (int*)   (ws + 38020608);    // 4096  [p*32+b]
  unsigned* KEYS   = (unsigned*)(ws + 38036992);  // 402
  double*   SCSH   = (double*)(ws + 38039040);    // 32*2
  double*   PARTS  = (double*)(ws + 38039552);    // 256
  double*   PARTS2 = (double*)(ws + 38041600);    // 256
  double*   PNPRE  = (double*)(ws + 38043648);    // 4096  [b][p]
  int*      FLAG   = (int*)   (ws + 38076416);
  double*   SINK   = (double*)(ws + 38076480);

  // ---- setup + layout probe ----
  k_keys<<<1, 64, 0, stream>>>(KEYS);
  k_probe<<<1, 64, 0, stream>>>(FLAG);
  k_rep0<<<1, 64, 0, stream>>>(FLAG, SINK);
  k_rep1<<<1, 64, 0, stream>>>(FLAG, SINK);
  k_rep2<<<1, 64, 0, stream>>>(FLAG, SINK);
  k_rep3<<<1, 64, 0, stream>>>(FLAG, SINK);
  k_rep4<<<1, 64, 0, stream>>>(FLAG, SINK);
  k_prep<<<517, 256, 0, stream>>>(fcz_w, fcz_b, fcr_w, fcr_b, fcn_w, fcn_b,
                                  fco_w, fco_b, h2l_w, h2l_b,
                                  WZRT, WNT, WO, BZ, BR, BNN, BO, H2LW, H2LB);
  k_h0<<<2048, 256, 0, stream>>>(KEYS, H0, P);

  // ---- frontend ----
  k_conv1<<<512, 256, 0, stream>>>(map_in, c1_w, C1O);
  k_bnstats1<<<128, 256, 0, stream>>>(C1O, PARTS, PARTS2, 16);
  k_bnstats2<<<1, 32, 0, stream>>>(PARTS, PARTS2, c1_g, c1_b, SCSH, 16);
  k_bnapply<<<2048, 256, 0, stream>>>(C1O, SCSH, 16);
  k_conv3x3<<<512, 256, 0, stream>>>(C1O, c2_w, C2O, 16, 32);
  k_bnstats1<<<256, 256, 0, stream>>>(C2O, PARTS, PARTS2, 32);
  k_bnstats2<<<1, 32, 0, stream>>>(PARTS, PARTS2, c2_g, c2_b, SCSH, 32);
  k_bnapply<<<4096, 256, 0, stream>>>(C2O, SCSH, 32);
  k_conv3x3<<<512, 256, 0, stream>>>(C2O, c3_w, C3O, 32, 32);
  k_bnstats1<<<256, 256, 0, stream>>>(C3O, PARTS, PARTS2, 32);
  k_bnstats2<<<1, 32, 0, stream>>>(PARTS, PARTS2, c3_g, c3_b, SCSH, 32);
  k_bnapply<<<4096, 256, 0, stream>>>(C3O, SCSH, 32);
  k_mapfc<<<512, 256, 0, stream>>>(C3O, map_w, map_b, EMB);
  k_maps<<<32, 64, 0, stream>>>(EMB, m2o_w, m2o_b, m2a_w, m2a_b, OMAP, AMAP);
  {
    dim3 g(100, 32);
    k_xs<<<g, 128, 0, stream>>>(obs_in, act_in, obs_w, obs_b, act_w, act_b,
                                OMAP, AMAP, WO, XS, XO);
  }
  k_xpre2<<<400, 256, 0, stream>>>(XS, WZRT, WNT, XZR, XN);

  // ---- scan over 100 timesteps ----
  double* hb[2] = { H1A, H1B };
  for (int s = 0; s < 100; ++s) {
    const double* hsrc = (s == 0) ? H0 : hb[(s - 1) & 1];
    const int* idxp = (s == 0) ? nullptr : IDX;
    float* pfprev = (s == 0) ? nullptr : (pfout + (size_t)(s - 1) * 12288);
    k_stepV<<<256, 512, 0, stream>>>(hsrc, idxp,
        XZR + (size_t)s*32*256, XN + (size_t)s*32*256, XO + (size_t)s*32,
        WZRT, WNT, BZ, BR, BNN, WO, BO, P, H2LW, H2LB,
        hb[s & 1], LP, PNPRE, pfprev, yout, KEYS, s, FLAG);
    k_stepM<<<256, 512, 0, stream>>>(hsrc, idxp,
        XZR + (size_t)s*32*256, XN + (size_t)s*32*256, XO + (size_t)s*32,
        WZRT, WNT, BZ, BR, BNN, WO, BO, P, H2LW, H2LB,
        hb[s & 1], LP, PNPRE, pfprev, yout, KEYS, s, FLAG);
    k_sr<<<512, 512, 0, stream>>>(LP, P, KEYS, s, IDX, PNPRE);
  }
  k_yfinal<<<32, 512, 0, stream>>>(hb[1], IDX, PNPRE, P, H2LW, H2LB, yout);
  k_pfend<<<1024, 256, 0, stream>>>(hb[1], IDX, H2LW, H2LB,
                                    pfout + (size_t)99 * 12288);
}

// Round 12
// 4860.316 us; speedup vs baseline: 2.0787x; 1.0610x over previous
//
#include <hip/hip_runtime.h>
#include <math.h>

typedef double double2v __attribute__((ext_vector_type(2)));
typedef double double4v __attribute__((ext_vector_type(4)));

#if defined(__has_builtin)
#if __has_builtin(__builtin_amdgcn_mfma_f64_16x16x4f64)
#define HAVE_MFMA_F64 1
#endif
#endif

// ===================== JAX Threefry-2x32 (bit-exact) =====================
__device__ __forceinline__ void threefry2x32(unsigned k0, unsigned k1,
                                             unsigned x0, unsigned x1,
                                             unsigned& o0, unsigned& o1)
{
  unsigned ks2 = k0 ^ k1 ^ 0x1BD11BDAu;
  x0 += k0; x1 += k1;
#define TFR(r) { x0 += x1; x1 = (x1 << r) | (x1 >> (32 - r)); x1 ^= x0; }
  TFR(13) TFR(15) TFR(26) TFR(6)
  x0 += k1;  x1 += ks2 + 1u;
  TFR(17) TFR(29) TFR(16) TFR(24)
  x0 += ks2; x1 += k0 + 2u;
  TFR(13) TFR(15) TFR(26) TFR(6)
  x0 += k0;  x1 += k1 + 3u;
  TFR(17) TFR(29) TFR(16) TFR(24)
  x0 += k1;  x1 += ks2 + 4u;
  TFR(13) TFR(15) TFR(26) TFR(6)
  x0 += ks2; x1 += k0 + 5u;
#undef TFR
  o0 = x0; o1 = x1;
}

// jax_threefry_partitionable=True: word e = o0 ^ o1 of block (0, e)
__device__ __forceinline__ unsigned rand_word(unsigned kA, unsigned kB, unsigned e)
{
  unsigned o0, o1;
  threefry2x32(kA, kB, 0u, e, o0, o1);
  return o0 ^ o1;
}

__device__ __forceinline__ float bits_to_unit(unsigned bits)
{
  unsigned u = (bits >> 9) | 0x3f800000u;
  return __uint_as_float(u) - 1.0f;   // exact, in [0,1)
}

// erfinv in double: Giles poly init + 1 Halley iteration on erf()
__device__ __forceinline__ double erfinv_d(double x)
{
  double w = -log((1.0 - x) * (1.0 + x));
  double p;
  if (w < 5.0) {
    w -= 2.5;
    p = 2.81022636e-08;
    p = fma(p, w, 3.43273939e-07);
    p = fma(p, w, -3.5233877e-06);
    p = fma(p, w, -4.39150654e-06);
    p = fma(p, w, 0.00021858087);
    p = fma(p, w, -0.00125372503);
    p = fma(p, w, -0.00417768164);
    p = fma(p, w, 0.246640727);
    p = fma(p, w, 1.50140941);
  } else {
    w = sqrt(w) - 3.0;
    p = -0.000200214257;
    p = fma(p, w, 0.000100950558);
    p = fma(p, w, 0.00134934322);
    p = fma(p, w, -0.00367342844);
    p = fma(p, w, 0.00573950773);
    p = fma(p, w, -0.0076224613);
    p = fma(p, w, 0.00943887047);
    p = fma(p, w, 1.00167406);
    p = fma(p, w, 2.83297682);
  }
  double r = p * x;
  double f  = erf(r) - x;
  double fp = 1.1283791670955126 * exp(-r * r);   // 2/sqrt(pi) e^{-r^2}
  double q  = f / fp;
  return r - q / (1.0 + r * q);
}

// N(0,1) sample e of a jax.random.normal(f32) draw
__device__ __forceinline__ double eps_normal(unsigned kA, unsigned kB, unsigned e)
{
  float f = bits_to_unit(rand_word(kA, kB, e));
  double u = (double)f * (2.0 - 5.9604644775390625e-8)
           - (1.0 - 5.9604644775390625e-8);
  return 1.4142135623730951 * erfinv_d(u);
}

__device__ __forceinline__ double sigd(double x) { return 1.0 / (1.0 + exp(-x)); }

__device__ __forceinline__ double gumbel_d(unsigned kA, unsigned kB, unsigned e)
{
  float f = bits_to_unit(rand_word(kA, kB, e));
  double u = (f == 0.0f) ? 1.1754943508222875e-38 : (double)f;
  return -log(-log(u));
}

// ===================== MFMA layout probe =====================
__global__ void k_probe(int* flag)
{
#ifdef HAVE_MFMA_F64
  int l = threadIdx.x;
  int mr = l & 15, kg = l >> 4;
  double a = (double)(1 + 5*mr + 7*kg);       // A[mr][kg]
  double b = (double)(2 + 11*kg + 13*mr);     // B[kg][mr]
  double4v d = {0.0, 0.0, 0.0, 0.0};
  d = __builtin_amdgcn_mfma_f64_16x16x4f64(a, b, d, 0, 0, 0);
  d = __builtin_amdgcn_mfma_f64_16x16x4f64(a, b, d, 0, 0, 0);   // chain test
  bool ok0 = true, ok1 = true, ok2 = true, ok3 = true;
  for (int q = 0; q < 4; ++q) {
    int rows[4] = { kg*4 + q, kg + 4*q, mr,         mr };
    int cols[4] = { mr,       mr,       kg*4 + q,   kg + 4*q };
    double t[4];
    for (int c = 0; c < 4; ++c) {
      double acc = 0.0;
      for (int k = 0; k < 4; ++k)
        acc += (double)((1 + 5*rows[c] + 7*k) * (2 + 11*k + 13*cols[c]));
      t[c] = 2.0 * acc;
    }
    if (d[q] != t[0]) ok0 = false;
    if (d[q] != t[1]) ok1 = false;
    if (d[q] != t[2]) ok2 = false;
    if (d[q] != t[3]) ok3 = false;
  }
  unsigned long long m0 = __ballot(ok0), m1 = __ballot(ok1);
  unsigned long long m2 = __ballot(ok2), m3 = __ballot(ok3);
  if (l == 0) {
    const unsigned long long ALL = 0xFFFFFFFFFFFFFFFFULL;
    int fl = 4;
    if (m0 == ALL) fl = 0;
    else if (m1 == ALL) fl = 1;
    else if (m2 == ALL) fl = 2;
    else if (m3 == ALL) fl = 3;
    flag[0] = fl;
  }
#else
  if (threadIdx.x == 0) flag[0] = 4;
#endif
}

// flag reporters: exactly one spins ~65us; its NAME in the profile = flag.
#define REP_KERNEL(NAME, VAL)                                               \
__global__ void NAME(const int* flag, double* sink) {                      \
  if (*flag != VAL) return;                                                 \
  double x = 1.0;                                                           \
  for (int i = 0; i < 40000; ++i) x = fma(x, 1.0000000000001, 1e-300);      \
  if (threadIdx.x == 0) sink[0] = x;                                        \
}
REP_KERNEL(k_rep0, 0)
REP_KERNEL(k_rep1, 1)
REP_KERNEL(k_rep2, 2)
REP_KERNEL(k_rep3, 3)
REP_KERNEL(k_rep4, 4)

// ===================== setup kernels =====================
__global__ void k_keys(unsigned* keys)
{
  if (threadIdx.x != 0 || blockIdx.x != 0) return;
  unsigned a0,a1,b0,b1,c0,c1,d0,d1;
  unsigned kx = 0u, ky = 42u;                 // jax.random.key(42)
  threefry2x32(kx, ky, 0u, 0u, a0, a1);       // carried key
  threefry2x32(kx, ky, 0u, 1u, b0, b1);       // k0 (h0 uniform)
  keys[0] = b0; keys[1] = b1;
  kx = a0; ky = a1;
  for (int s = 0; s < 100; ++s) {
    threefry2x32(kx, ky, 0u, 0u, a0, a1);     // k
    threefry2x32(kx, ky, 0u, 1u, c0, c1);     // ke
    threefry2x32(kx, ky, 0u, 2u, d0, d1);     // kr
    keys[2 + 4*s + 0] = c0; keys[2 + 4*s + 1] = c1;
    keys[2 + 4*s + 2] = d0; keys[2 + 4*s + 3] = d1;
    kx = a0; ky = a1;
  }
}

__global__ __launch_bounds__(256) void k_prep(
    const float* fcz_w, const float* fcz_b, const float* fcr_w, const float* fcr_b,
    const float* fcn_w, const float* fcn_b, const float* fco_w, const float* fco_b,
    const float* h2l_w, const float* h2l_b,
    double* wzrT, double* wnT, double* wo, double* bz, double* br,
    double* bnn, double* bo, double* h2lw, double* h2lb)
{
  int id = blockIdx.x * 256 + threadIdx.x;
  if (id < 65536) {
    int k = id >> 8, j = id & 255;
    wzrT[id] = (double)((j < 128) ? fcz_w[j*256 + k] : fcr_w[(j-128)*256 + k]);
    return;
  }
  id -= 65536;
  if (id < 65536) { int k = id >> 8, j = id & 255; wnT[id] = (double)fcn_w[j*256 + k]; return; }
  id -= 65536;
  if (id < 256) { wo[id] = (double)fco_w[id]; return; }
  id -= 256;
  if (id < 128) { bz[id] = (double)fcz_b[id]; return; }
  id -= 128;
  if (id < 128) { br[id] = (double)fcr_b[id]; return; }
  id -= 128;
  if (id < 256) { bnn[id] = (double)fcn_b[id]; return; }
  id -= 256;
  if (id < 1) { bo[0] = (double)fco_b[0]; return; }
  id -= 1;
  if (id < 384) { h2lw[id] = (double)h2l_w[id]; return; }
  id -= 384;
  if (id < 3) { h2lb[id] = (double)h2l_b[id]; return; }
}

__global__ __launch_bounds__(256) void k_h0(const unsigned* keys, double* h, double* p)
{
  unsigned e = blockIdx.x * 256 + threadIdx.x;    // < 524288
  h[e] = (double)bits_to_unit(rand_word(keys[0], keys[1], e));
  if (e < 4096) p[e] = (double)(float)log(1.0 / 128.0);
}

// ===================== frontend (map CNN encoder) =====================
__global__ __launch_bounds__(256) void k_conv1(const float* in, const float* w, double* out)
{
  int bc = blockIdx.x; int b = bc >> 4, co = bc & 15;
  __shared__ double wl[25];
  __shared__ float plf[4096];
  if (threadIdx.x < 25) wl[threadIdx.x] = (double)w[co*25 + threadIdx.x];
  const float* ib = in + (size_t)b * 4096;
  for (int j = 0; j < 16; ++j) plf[threadIdx.x + j*256] = ib[threadIdx.x + j*256];
  __syncthreads();
  for (int q = 0; q < 4; ++q) {
    int px = q*256 + threadIdx.x;
    int oh = px >> 5, ow = px & 31;
    double acc = 0.0;
    for (int kh = 0; kh < 5; ++kh) {
      int ih = oh*2 - 2 + kh; if (ih < 0 || ih >= 64) continue;
      for (int kw = 0; kw < 5; ++kw) {
        int iw = ow*2 - 2 + kw; if (iw < 0 || iw >= 64) continue;
        acc = fma((double)plf[ih*64 + iw], wl[kh*5 + kw], acc);
      }
    }
    out[((size_t)b*16 + co)*1024 + px] = fmax(acc, 0.0);
  }
}

// 2 output channels per block: input planes read once per pair
__global__ __launch_bounds__(256) void k_conv3x3(const double* in, const float* w,
                                                 double* out, int Ci, int Co)
{
  int bc = blockIdx.x; int b = bc / (Co >> 1), cop = bc % (Co >> 1);
  int co0 = cop * 2;
  __shared__ double wl0[288], wl1[288];
  __shared__ double pl[2][1024];
  for (int e = threadIdx.x; e < Ci*9; e += 256) {
    wl0[e] = (double)w[(size_t)co0*Ci*9 + e];
    wl1[e] = (double)w[(size_t)(co0 + 1)*Ci*9 + e];
  }
  double acc0[4] = {0.0, 0.0, 0.0, 0.0};
  double acc1[4] = {0.0, 0.0, 0.0, 0.0};
  const double* ib = in + (size_t)b * Ci * 1024;
  for (int q = 0; q < 4; ++q)
    pl[0][threadIdx.x + q*256] = ib[threadIdx.x + q*256];
  __syncthreads();
  for (int ci = 0; ci < Ci; ++ci) {
    int cur = ci & 1;
    if (ci + 1 < Ci) {
      for (int q = 0; q < 4; ++q)
        pl[cur ^ 1][threadIdx.x + q*256] = ib[(ci + 1)*1024 + threadIdx.x + q*256];
    }
    const double* wp0 = wl0 + ci*9;
    const double* wp1 = wl1 + ci*9;
    for (int q = 0; q < 4; ++q) {
      int px = q*256 + threadIdx.x;
      int oh = px >> 5, ow = px & 31;
      double a0 = acc0[q], a1 = acc1[q];
      for (int kh = 0; kh < 3; ++kh) {
        int ih = oh - 1 + kh; if (ih < 0 || ih >= 32) continue;
        for (int kw = 0; kw < 3; ++kw) {
          int iw = ow - 1 + kw; if (iw < 0 || iw >= 32) continue;
          double pv = pl[cur][ih*32 + iw];
          a0 = fma(pv, wp0[kh*3 + kw], a0);
          a1 = fma(pv, wp1[kh*3 + kw], a1);
        }
      }
      acc0[q] = a0; acc1[q] = a1;
    }
    __syncthreads();
  }
  for (int q = 0; q < 4; ++q) {
    int px = q*256 + threadIdx.x;
    out[((size_t)b*Co + co0)*1024 + px]     = fmax(acc0[q], 0.0);
    out[((size_t)b*Co + co0 + 1)*1024 + px] = fmax(acc1[q], 0.0);
  }
}

__global__ __launch_bounds__(256) void k_bnstats1(const double* __restrict__ x,
    double* __restrict__ partS, double* __restrict__ partS2, int C)
{
  int c = blockIdx.x >> 3, chunk = blockIdx.x & 7;
  double s = 0.0, s2 = 0.0;
  for (int e = threadIdx.x; e < 4096; e += 256) {
    int b = chunk*4 + (e >> 10), px = e & 1023;
    double v = x[((size_t)b*C + c)*1024 + px];
    s += v; s2 = fma(v, v, s2);
  }
  __shared__ double rs[256], rs2[256];
  rs[threadIdx.x] = s; rs2[threadIdx.x] = s2;
  __syncthreads();
  for (int d = 128; d; d >>= 1) {
    if (threadIdx.x < d) { rs[threadIdx.x] += rs[threadIdx.x + d]; rs2[threadIdx.x] += rs2[threadIdx.x + d]; }
    __syncthreads();
  }
  if (threadIdx.x == 0) { partS[blockIdx.x] = rs[0]; partS2[blockIdx.x] = rs2[0]; }
}

__global__ void k_bnstats2(const double* __restrict__ partS,
                           const double* __restrict__ partS2,
                           const float* g, const float* bta, double* scsh, int C)
{
  int c = threadIdx.x;
  if (c >= C) return;
  double s = 0.0, s2 = 0.0;
  for (int j = 0; j < 8; ++j) { s += partS[c*8 + j]; s2 += partS2[c*8 + j]; }
  double n = 32768.0;
  double mean = s / n;
  double var = s2 / n - mean*mean;
  double sc = (double)g[c] / sqrt(var + 1e-5);
  scsh[c*2] = sc;
  scsh[c*2 + 1] = (double)bta[c] - mean * sc;
}

__global__ __launch_bounds__(256) void k_bnapply(double* x, const double* scsh, int C)
{
  size_t e = (size_t)blockIdx.x * 256 + threadIdx.x;
  int c = (int)((e >> 10) % (size_t)C);
  x[e] = fma(x[e], scsh[c*2], scsh[c*2 + 1]);
}

__global__ __launch_bounds__(256) void k_mapfc(const double* x, const float* w,
                                               const float* bias, double* emb)
{
  int blk = blockIdx.x; int b = blk >> 4, jg = blk & 15;
  double acc[8];
  #pragma unroll
  for (int jj = 0; jj < 8; ++jj) acc[jj] = 0.0;
  const double* xb = x + (size_t)b * 32768;
  for (int e = threadIdx.x; e < 32768; e += 256) {
    double xv = xb[e];
    #pragma unroll
    for (int jj = 0; jj < 8; ++jj)
      acc[jj] = fma(xv, (double)w[(size_t)(jg*8 + jj)*32768 + e], acc[jj]);
  }
  __shared__ double red[8][256];
  #pragma unroll
  for (int jj = 0; jj < 8; ++jj) red[jj][threadIdx.x] = acc[jj];
  __syncthreads();
  for (int d = 128; d; d >>= 1) {
    if (threadIdx.x < d)
      #pragma unroll
      for (int jj = 0; jj < 8; ++jj) red[jj][threadIdx.x] += red[jj][threadIdx.x + d];
    __syncthreads();
  }
  if (threadIdx.x < 8) {
    int j = jg*8 + threadIdx.x;
    emb[b*128 + j] = fmax(red[threadIdx.x][0] + (double)bias[j], 0.0);
  }
}

__global__ void k_maps(const double* emb, const float* m2o_w, const float* m2o_b,
                       const float* m2a_w, const float* m2a_b,
                       double* omap, double* amap)
{
  int b = blockIdx.x, j = threadIdx.x;   // 64 threads
  double a1 = (double)m2o_b[j], a2 = (double)m2a_b[j];
  for (int k = 0; k < 128; ++k) {
    double ev = emb[b*128 + k];
    a1 = fma(ev, (double)m2o_w[j*128 + k], a1);
    a2 = fma(ev, (double)m2a_w[j*128 + k], a2);
  }
  omap[b*64 + j] = fmax(a1, 0.0);
  amap[b*64 + j] = fmax(a2, 0.0);
}

__global__ __launch_bounds__(128) void k_xs(const float* obs_in, const float* act_in,
                                            const float* obs_w, const float* obs_b,
                                            const float* act_w, const float* act_b,
                                            const double* omap, const double* amap,
                                            const double* wo,
                                            double* xs, double* xo)
{
  int s = blockIdx.x, b = blockIdx.y, j = threadIdx.x;
  double v;
  if (j < 64) {
    double a = (double)obs_b[j];
    const float* o = obs_in + ((size_t)b*100 + s)*16;
    for (int k = 0; k < 16; ++k) a = fma((double)o[k], (double)obs_w[j*16 + k], a);
    v = fmax(a, 0.0) * omap[b*64 + j];
  } else {
    int j2 = j - 64;
    double a = (double)act_b[j2];
    const float* o = act_in + ((size_t)b*100 + s)*3;
    for (int k = 0; k < 3; ++k) a = fma((double)o[k], (double)act_w[j2*3 + k], a);
    v = fmax(a, 0.0) * amap[b*64 + j2];
  }
  xs[((size_t)s*32 + b)*128 + j] = v;
  __shared__ double red[128];
  red[j] = v * wo[128 + j];
  __syncthreads();
  for (int d = 64; d; d >>= 1) {
    if (j < d) red[j] += red[j + d];
    __syncthreads();
  }
  if (j == 0) xo[s*32 + b] = red[0];
}

__global__ __launch_bounds__(256, 2) void k_xpre2(const double* __restrict__ xs,
    const double* __restrict__ wzrT, const double* __restrict__ wnT,
    double* __restrict__ xzr, double* __restrict__ xn)
{
  int s = blockIdx.x >> 2, bg = blockIdx.x & 3;
  __shared__ double xl[8][128];
  int t = threadIdx.x;
  #pragma unroll
  for (int j = 0; j < 4; ++j) {
    int e = t + j*256;
    int i = e >> 7, cc = e & 127;
    xl[i][cc] = xs[((size_t)s*32 + bg*8 + i)*128 + cc];
  }
  __syncthreads();
  double az[8], an[8];
  #pragma unroll
  for (int i = 0; i < 8; ++i) { az[i] = 0.0; an[i] = 0.0; }
  for (int k = 0; k < 128; ++k) {
    double wz = wzrT[k*256 + t];
    double wn = wnT[(128 + k)*256 + t];
    #pragma unroll
    for (int i = 0; i < 8; ++i) {
      double xv = xl[i][k];
      az[i] = fma(xv, wz, az[i]);
      an[i] = fma(xv, wn, an[i]);
    }
  }
  #pragma unroll
  for (int i = 0; i < 8; ++i) {
    size_t sb = (size_t)s*32 + bg*8 + i;
    xzr[sb*256 + t] = az[i];
    xn [sb*256 + t] = an[i];
  }
}

// ===================== fused scan step (MFMA or vector, runtime flag) =====
// 256 blocks x 512 threads; 16 rows/block.
// MFMA: wave wv owns z-cols wv*16..+15 and rg-cols +128; z/mu/var/eps/h1
// thread-local (GEMM1 and GEMM2 epilogue owners are the same thread).
__global__ __launch_bounds__(512, 2) void k_step(
    const double* __restrict__ hsrc, const int* __restrict__ idxp,
    const double* __restrict__ xzr, const double* __restrict__ xn,
    const double* __restrict__ xo,
    const double* __restrict__ wzrT, const double* __restrict__ wnT,
    const double* __restrict__ bz, const double* __restrict__ br,
    const double* __restrict__ bnn, const double* __restrict__ wo,
    const double* __restrict__ bo, double* __restrict__ P,
    const double* __restrict__ h2lw, const double* __restrict__ h2lb,
    double* __restrict__ h1out, double* __restrict__ LP,
    const double* __restrict__ PNPRE,
    float* __restrict__ pfout, float* __restrict__ yout,
    const unsigned* __restrict__ keys, int s, const int* __restrict__ flagp)
{
  __shared__ double ah[16][130];   // gathered h  (130: 16B align + low conflicts)
  __shared__ double aw[16][130];   // rg*h, later h1
  __shared__ double wsh[128], ys[128], red8[8][128];
  __shared__ int    isx[128];
  __shared__ double smx[2], ssx[2];
  const int f  = *flagp;
  const int t  = threadIdx.x;
  const int r0 = blockIdx.x * 16;
  const int wv = t >> 6, lane = t & 63;
  const bool first = (idxp == nullptr);

  // ---- phase C of step s-1 (blocks 0..31): pn normalize + y ----
  if (!first && blockIdx.x < 32) {
    int b = blockIdx.x;
    if (t < 128) {
      double q = PNPRE[b*128 + t];
      double m = q;
      for (int d = 32; d; d >>= 1) m = fmax(m, __shfl_xor(m, d, 64));
      if ((t & 63) == 0) smx[t >> 6] = m;
    }
    __syncthreads();
    if (t < 128) {
      double q = PNPRE[b*128 + t];
      double m = fmax(smx[0], smx[1]);
      double e = exp(q - m), su = e;
      for (int d = 32; d; d >>= 1) su += __shfl_xor(su, d, 64);
      if ((t & 63) == 0) ssx[t >> 6] = su;
    }
    __syncthreads();
    if (t < 128) {
      double q = PNPRE[b*128 + t];
      double m = fmax(smx[0], smx[1]);
      double pn = q - (m + log(ssx[0] + ssx[1]));
      P[b*128 + t] = pn;
      wsh[t] = exp(pn);
      isx[t] = idxp[t*32 + b];
    }
    __syncthreads();
    {
      #pragma unroll
      for (int colh = 0; colh < 2; ++colh) {
        int col = lane + colh*64;
        double acc = 0.0;
        for (int q = 0; q < 16; ++q) {
          int ii = wv*16 + q;
          acc = fma(wsh[ii], hsrc[(size_t)(isx[ii]*32 + b)*128 + col], acc);
        }
        red8[wv][col] = acc;
      }
    }
    __syncthreads();
    if (t < 128) {
      double a = red8[0][t];
      for (int gg = 1; gg < 8; ++gg) a += red8[gg][t];
      ys[t] = a;
    }
    __syncthreads();
    if (t < 3) {
      double dsum = h2lb[t];
      for (int cc = 0; cc < 128; ++cc)
        dsum = fma(h2lw[t*128 + cc], ys[cc], dsum);
      yout[(s - 1)*96 + b*3 + t] = (float)(1.0 / (1.0 + exp(-dsum)));
    }
    __syncthreads();
  }

  // ---- gather prev h (4 elements/thread, coalesced) ----
  #pragma unroll
  for (int j = 0; j < 4; ++j) {
    int e = t + j*512;
    int r = e >> 7, cc = e & 127;
    int R = r0 + r, b = R & 31;
    int src = first ? R : (idxp[R]*32 + b);
    ah[r][cc] = hsrc[(size_t)src*128 + cc];
  }
  __syncthreads();
  // ---- pf for previous step: 8 waves x 2 rows ----
  if (pfout != nullptr) {
    #pragma unroll
    for (int q = 0; q < 2; ++q) {
      int i = wv*2 + q;
      double v0 = ah[i][lane*2], v1 = ah[i][lane*2 + 1];
      double s0 = fma(v0, h2lw[lane*2],       v1 * h2lw[lane*2 + 1]);
      double s1 = fma(v0, h2lw[128 + lane*2], v1 * h2lw[128 + lane*2 + 1]);
      double s2 = fma(v0, h2lw[256 + lane*2], v1 * h2lw[256 + lane*2 + 1]);
      for (int d = 32; d; d >>= 1) {
        s0 += __shfl_xor(s0, d, 64);
        s1 += __shfl_xor(s1, d, 64);
        s2 += __shfl_xor(s2, d, 64);
      }
      if (lane == 0) {
        float* o = pfout + (r0 + i) * 3;
        o[0] = (float)(1.0 / (1.0 + exp(-(s0 + h2lb[0]))));
        o[1] = (float)(1.0 / (1.0 + exp(-(s1 + h2lb[1]))));
        o[2] = (float)(1.0 / (1.0 + exp(-(s2 + h2lb[2]))));
      }
    }
  }

  if (f >= 1 && f <= 3) {
#ifdef HAVE_MFMA_F64
    // ================== MFMA path (probe-verified D layout) ==================
    const int mrow = lane & 15;
    const int kgrp = lane >> 4;
    // GEMM1: h-part of [x|h] @ Wzr^T
    double4v acc0 = {0.0, 0.0, 0.0, 0.0};
    double4v acc1 = {0.0, 0.0, 0.0, 0.0};
    for (int k4 = 0; k4 < 32; ++k4) {
      int k = k4*4 + kgrp;
      double a  = ah[mrow][k];
      double b0 = wzrT[(size_t)(128 + k)*256 + wv*16 + mrow];
      double b1 = wzrT[(size_t)(128 + k)*256 + 128 + wv*16 + mrow];
      acc0 = __builtin_amdgcn_mfma_f64_16x16x4f64(a, b0, acc0, 0, 0, 0);
      acc1 = __builtin_amdgcn_mfma_f64_16x16x4f64(a, b1, acc1, 0, 0, 0);
    }
    double zq[4];
    #pragma unroll
    for (int q = 0; q < 4; ++q) {
      int row, col;
      if (f == 1)      { row = kgrp + 4*q; col = wv*16 + mrow; }
      else if (f == 2) { row = mrow;       col = wv*16 + kgrp*4 + q; }
      else             { row = mrow;       col = wv*16 + kgrp + 4*q; }
      int b = (r0 + row) & 31;
      zq[q] = sigd(acc0[q] + xzr[b*256 + col] + bz[col]);
      double rgv = sigd(acc1[q] + xzr[b*256 + 128 + col] + br[col]);
      aw[row][col] = rgv * ah[row][col];
    }
    __syncthreads();
    // GEMM2: (rg*h)-part of [rg*h|x] @ Wn^T
    acc0 = double4v{0.0, 0.0, 0.0, 0.0};
    acc1 = double4v{0.0, 0.0, 0.0, 0.0};
    for (int k4 = 0; k4 < 32; ++k4) {
      int k = k4*4 + kgrp;
      double a  = aw[mrow][k];
      double b0 = wnT[(size_t)k*256 + wv*16 + mrow];
      double b1 = wnT[(size_t)k*256 + 128 + wv*16 + mrow];
      acc0 = __builtin_amdgcn_mfma_f64_16x16x4f64(a, b0, acc0, 0, 0, 0);
      acc1 = __builtin_amdgcn_mfma_f64_16x16x4f64(a, b1, acc1, 0, 0, 0);
    }
    // thread-local reparam + h1 (same owner as GEMM1 epilogue)
    double hq[4];
    {
      unsigned keA = keys[2 + 4*s], keB = keys[2 + 4*s + 1];
      #pragma unroll
      for (int q = 0; q < 4; ++q) {
        int row, col;
        if (f == 1)      { row = kgrp + 4*q; col = wv*16 + mrow; }
        else if (f == 2) { row = mrow;       col = wv*16 + kgrp*4 + q; }
        else             { row = mrow;       col = wv*16 + kgrp + 4*q; }
        int b = (r0 + row) & 31, R = r0 + row;
        double mu  = acc0[q] + xn[b*256 + col] + bnn[col];
        double var = acc1[q] + xn[b*256 + 128 + col] + bnn[128 + col];
        double sp = fmax(var, 0.0) + log1p(exp(-fabs(var)));
        double ep = eps_normal(keA, keB, (unsigned)(R*128 + col));
        double n  = fma(ep, sp, mu);
        double hv = (1.0 - zq[q])*n + zq[q]*ah[row][col];
        h1out[(size_t)R*128 + col] = hv;
        hq[q] = hv;
      }
    }
    __syncthreads();   // all GEMM2 aw reads complete
    #pragma unroll
    for (int q = 0; q < 4; ++q) {
      int row, col;
      if (f == 1)      { row = kgrp + 4*q; col = wv*16 + mrow; }
      else if (f == 2) { row = mrow;       col = wv*16 + kgrp*4 + q; }
      else             { row = mrow;       col = wv*16 + kgrp + 4*q; }
      aw[row][col] = hq[q];
    }
#endif
  } else {
    // ================== vector path (R9 bit-exact fallback) ==================
    const int rq = t >> 7;           // 0..3: rows rq*4 .. rq*4+3
    const int c2 = t & 127;          // cols c2, c2+128
    double ac0[4], ac1[4];
    #pragma unroll
    for (int i = 0; i < 4; ++i) { ac0[i] = 0.0; ac1[i] = 0.0; }
    {
      const double2v* ap0 = (const double2v*)&ah[rq*4 + 0][0];
      const double2v* ap1 = (const double2v*)&ah[rq*4 + 1][0];
      const double2v* ap2 = (const double2v*)&ah[rq*4 + 2][0];
      const double2v* ap3 = (const double2v*)&ah[rq*4 + 3][0];
      for (int k2 = 0; k2 < 64; ++k2) {
        const double* wr0 = &wzrT[(128 + 2*k2)*256];
        const double* wr1 = &wzrT[(128 + 2*k2 + 1)*256];
        double w00 = wr0[c2],       w01 = wr1[c2];
        double w10 = wr0[c2 + 128], w11 = wr1[c2 + 128];
        double2v A0 = ap0[k2], A1 = ap1[k2], A2 = ap2[k2], A3 = ap3[k2];
        ac0[0] = fma(A0.y, w01, fma(A0.x, w00, ac0[0]));
        ac1[0] = fma(A0.y, w11, fma(A0.x, w10, ac1[0]));
        ac0[1] = fma(A1.y, w01, fma(A1.x, w00, ac0[1]));
        ac1[1] = fma(A1.y, w11, fma(A1.x, w10, ac1[1]));
        ac0[2] = fma(A2.y, w01, fma(A2.x, w00, ac0[2]));
        ac1[2] = fma(A2.y, w11, fma(A2.x, w10, ac1[2]));
        ac0[3] = fma(A3.y, w01, fma(A3.x, w00, ac0[3]));
        ac1[3] = fma(A3.y, w11, fma(A3.x, w10, ac1[3]));
      }
    }
    double zrv[4];
    {
      double bzv = bz[c2], brv = br[c2];
      #pragma unroll
      for (int i = 0; i < 4; ++i) {
        int row = rq*4 + i;
        int b = (r0 + row) & 31;
        zrv[i] = sigd(ac0[i] + xzr[b*256 + c2] + bzv);
        double rgv = sigd(ac1[i] + xzr[b*256 + c2 + 128] + brv);
        aw[row][c2] = rgv * ah[row][c2];
      }
    }
    __syncthreads();
    #pragma unroll
    for (int i = 0; i < 4; ++i) { ac0[i] = 0.0; ac1[i] = 0.0; }
    {
      const double2v* ap0 = (const double2v*)&aw[rq*4 + 0][0];
      const double2v* ap1 = (const double2v*)&aw[rq*4 + 1][0];
      const double2v* ap2 = (const double2v*)&aw[rq*4 + 2][0];
      const double2v* ap3 = (const double2v*)&aw[rq*4 + 3][0];
      for (int k2 = 0; k2 < 64; ++k2) {
        const double* wr0 = &wnT[(2*k2)*256];
        const double* wr1 = &wnT[(2*k2 + 1)*256];
        double w00 = wr0[c2],       w01 = wr1[c2];
        double w10 = wr0[c2 + 128], w11 = wr1[c2 + 128];
        double2v A0 = ap0[k2], A1 = ap1[k2], A2 = ap2[k2], A3 = ap3[k2];
        ac0[0] = fma(A0.y, w01, fma(A0.x, w00, ac0[0]));
        ac1[0] = fma(A0.y, w11, fma(A0.x, w10, ac1[0]));
        ac0[1] = fma(A1.y, w01, fma(A1.x, w00, ac0[1]));
        ac1[1] = fma(A1.y, w11, fma(A1.x, w10, ac1[1]));
        ac0[2] = fma(A2.y, w01, fma(A2.x, w00, ac0[2]));
        ac1[2] = fma(A2.y, w11, fma(A2.x, w10, ac1[2]));
        ac0[3] = fma(A3.y, w01, fma(A3.x, w00, ac0[3]));
        ac1[3] = fma(A3.y, w11, fma(A3.x, w10, ac1[3]));
      }
    }
    double hv[4];
    {
      unsigned keA = keys[2 + 4*s], keB = keys[2 + 4*s + 1];
      double bn0 = bnn[c2], bn1 = bnn[c2 + 128];
      #pragma unroll
      for (int i = 0; i < 4; ++i) {
        int row = rq*4 + i, R = r0 + row;
        int b = R & 31;
        double mu  = ac0[i] + xn[b*256 + c2] + bn0;
        double var = ac1[i] + xn[b*256 + c2 + 128] + bn1;
        double sp = fmax(var, 0.0) + log1p(exp(-fabs(var)));
        double ep = eps_normal(keA, keB, (unsigned)(R*128 + c2));
        double n  = fma(ep, sp, mu);
        hv[i] = (1.0 - zrv[i])*n + zrv[i]*ah[row][c2];
        h1out[(size_t)R*128 + c2] = hv[i];
      }
    }
    __syncthreads();
    #pragma unroll
    for (int i = 0; i < 4; ++i) aw[rq*4 + i][c2] = hv[i];
  }
  __syncthreads();   // aw = h1 visible to all
  // ---- logpdf partial (without +p): 8 waves x 2 rows ----
  {
    #pragma unroll
    for (int q = 0; q < 2; ++q) {
      int row = wv*2 + q, R = r0 + row, b = R & 31;
      double part = fma(aw[row][lane], wo[lane], aw[row][lane + 64] * wo[lane + 64]);
      for (int d = 32; d; d >>= 1) part += __shfl_xor(part, d, 64);
      if (lane == 0) LP[b*128 + (R >> 5)] = part + xo[b] + bo[0];
    }
  }
}

// k_sr: barrier-free per-wave softmax + Gumbel-argmax.
__global__ __launch_bounds__(512, 4) void k_sr(
    const double* __restrict__ LP, const double* __restrict__ P,
    const unsigned* __restrict__ keys, int s,
    int* __restrict__ idx, double* __restrict__ PNPRE)
{
  int t = threadIdx.x;
  int wv = t >> 6, lane = t & 63;
  int rw = blockIdx.x * 8 + wv;
  int bw = rw & 31;
  unsigned kA = keys[2 + 4*s + 2], kB = keys[2 + 4*s + 3];
  double v0 = LP[bw*128 + lane]      + P[bw*128 + lane];
  double v1 = LP[bw*128 + lane + 64] + P[bw*128 + lane + 64];
  double m0 = v0, m1 = v1;
  for (int d = 32; d; d >>= 1) {
    m0 = fmax(m0, __shfl_xor(m0, d, 64));
    m1 = fmax(m1, __shfl_xor(m1, d, 64));
  }
  double m = fmax(m0, m1);
  double e0 = exp(v0 - m), e1 = exp(v1 - m);
  double s0 = e0, s1 = e1;
  for (int d = 32; d; d >>= 1) {
    s0 += __shfl_xor(s0, d, 64);
    s1 += __shfl_xor(s1, d, 64);
  }
  double lse = log(s0 + s1);
  double p1_0 = v0 - m - lse;
  double p1_1 = v1 - m - lse;
  double lg0 = log(0.5*exp(p1_0) + 0.00390625);
  double lg1 = log(0.5*exp(p1_1) + 0.00390625);
  double g0 = gumbel_d(kA, kB, (unsigned)(rw*128 + lane)) + lg0;
  double g1 = gumbel_d(kA, kB, (unsigned)(rw*128 + lane + 64)) + lg1;
  double val; int bj;
  if (g0 >= g1) { val = g0; bj = lane; } else { val = g1; bj = lane + 64; }
  for (int d = 32; d; d >>= 1) {
    double ov = __shfl_xor(val, d, 64);
    int    oj = __shfl_xor(bj, d, 64);
    if (ov > val || (ov == val && oj < bj)) { val = ov; bj = oj; }
  }
  double pl = __shfl(p1_0, bj & 63, 64);
  double ph = __shfl(p1_1, bj & 63, 64);
  if (lane == 0) {
    idx[rw] = bj;
    double p1b = (bj < 64) ? pl : ph;
    double pe = exp(p1b);
    PNPRE[bw*128 + (rw >> 5)] = log(pe / (0.5*pe + 0.00390625));
  }
}

// k_yfinal: phase C for step 99 (32 blocks x 512)
__global__ __launch_bounds__(512) void k_yfinal(
    const double* __restrict__ hlast, const int* __restrict__ idxp,
    const double* __restrict__ PNPRE, double* __restrict__ P,
    const double* __restrict__ h2lw, const double* __restrict__ h2lb,
    float* __restrict__ yout)
{
  __shared__ double wsh[128], ys[128], red8[8][128];
  __shared__ int    isx[128];
  __shared__ double smx[2], ssx[2];
  int t = threadIdx.x, b = blockIdx.x;
  int wv = t >> 6, lane = t & 63;
  if (t < 128) {
    double q = PNPRE[b*128 + t];
    double m = q;
    for (int d = 32; d; d >>= 1) m = fmax(m, __shfl_xor(m, d, 64));
    if ((t & 63) == 0) smx[t >> 6] = m;
  }
  __syncthreads();
  if (t < 128) {
    double q = PNPRE[b*128 + t];
    double m = fmax(smx[0], smx[1]);
    double e = exp(q - m), su = e;
    for (int d = 32; d; d >>= 1) su += __shfl_xor(su, d, 64);
    if ((t & 63) == 0) ssx[t >> 6] = su;
  }
  __syncthreads();
  if (t < 128) {
    double q = PNPRE[b*128 + t];
    double m = fmax(smx[0], smx[1]);
    double pn = q - (m + log(ssx[0] + ssx[1]));
    P[b*128 + t] = pn;
    wsh[t] = exp(pn);
    isx[t] = idxp[t*32 + b];
  }
  __syncthreads();
  #pragma unroll
  for (int colh = 0; colh < 2; ++colh) {
    int col = lane + colh*64;
    double acc = 0.0;
    for (int q = 0; q < 16; ++q) {
      int ii = wv*16 + q;
      acc = fma(wsh[ii], hlast[(size_t)(isx[ii]*32 + b)*128 + col], acc);
    }
    red8[wv][col] = acc;
  }
  __syncthreads();
  if (t < 128) {
    double a = red8[0][t];
    for (int gg = 1; gg < 8; ++gg) a += red8[gg][t];
    ys[t] = a;
  }
  __syncthreads();
  if (t < 3) {
    double dsum = h2lb[t];
    for (int cc = 0; cc < 128; ++cc)
      dsum = fma(h2lw[t*128 + cc], ys[cc], dsum);
    yout[99*96 + b*3 + t] = (float)(1.0 / (1.0 + exp(-dsum)));
  }
}

// epilogue: pf for the last step (gather via idx)
__global__ __launch_bounds__(256) void k_pfend(const double* __restrict__ h1,
    const int* __restrict__ idx, const double* __restrict__ h2lw,
    const double* __restrict__ h2lb, float* __restrict__ pfout)
{
  int wv = threadIdx.x >> 6, lane = threadIdx.x & 63;
  int r = blockIdx.x * 4 + wv;
  int b = r & 31;
  const double* hr = h1 + (size_t)(idx[r]*32 + b) * 128;
  double v0 = hr[lane*2], v1 = hr[lane*2 + 1];
  double s0 = fma(v0, h2lw[lane*2],       v1 * h2lw[lane*2 + 1]);
  double s1 = fma(v0, h2lw[128 + lane*2], v1 * h2lw[128 + lane*2 + 1]);
  double s2 = fma(v0, h2lw[256 + lane*2], v1 * h2lw[256 + lane*2 + 1]);
  for (int d = 32; d; d >>= 1) {
    s0 += __shfl_xor(s0, d, 64);
    s1 += __shfl_xor(s1, d, 64);
    s2 += __shfl_xor(s2, d, 64);
  }
  if (lane == 0) {
    float* o = pfout + r * 3;
    o[0] = (float)(1.0 / (1.0 + exp(-(s0 + h2lb[0]))));
    o[1] = (float)(1.0 / (1.0 + exp(-(s1 + h2lb[1]))));
    o[2] = (float)(1.0 / (1.0 + exp(-(s2 + h2lb[2]))));
  }
}

// ===================== host launch =====================
extern "C" void kernel_launch(void* const* d_in, const int* in_sizes, int n_in,
                              void* d_out, int out_size, void* d_ws, size_t ws_size,
                              hipStream_t stream)
{
  (void)in_sizes; (void)n_in; (void)out_size; (void)ws_size;
  const float* map_in = (const float*)d_in[0];
  const float* obs_in = (const float*)d_in[1];
  const float* act_in = (const float*)d_in[2];
  const float* c1_w = (const float*)d_in[3];
  const float* c1_g = (const float*)d_in[4];
  const float* c1_b = (const float*)d_in[5];
  const float* c2_w = (const float*)d_in[6];
  const float* c2_g = (const float*)d_in[7];
  const float* c2_b = (const float*)d_in[8];
  const float* c3_w = (const float*)d_in[9];
  const float* c3_g = (const float*)d_in[10];
  const float* c3_b = (const float*)d_in[11];
  const float* map_w = (const float*)d_in[12];
  const float* map_b = (const float*)d_in[13];
  const float* m2o_w = (const float*)d_in[14];
  const float* m2o_b = (const float*)d_in[15];
  const float* m2a_w = (const float*)d_in[16];
  const float* m2a_b = (const float*)d_in[17];
  const float* obs_w = (const float*)d_in[18];
  const float* obs_b = (const float*)d_in[19];
  const float* act_w = (const float*)d_in[20];
  const float* act_b = (const float*)d_in[21];
  const float* fcz_w = (const float*)d_in[22];
  const float* fcz_b = (const float*)d_in[23];
  const float* fcr_w = (const float*)d_in[24];
  const float* fcr_b = (const float*)d_in[25];
  const float* fcn_w = (const float*)d_in[26];
  const float* fcn_b = (const float*)d_in[27];
  const float* fco_w = (const float*)d_in[28];
  const float* fco_b = (const float*)d_in[29];
  const float* h2l_w = (const float*)d_in[30];
  const float* h2l_b = (const float*)d_in[31];

  float* yout  = (float*)d_out;
  float* pfout = (float*)d_out + 9600;

  char* ws = (char*)d_ws;
  double*   H0     = (double*)(ws + 0);           // 4096*128
  double*   H1A    = (double*)(ws + 4194304);
  double*   H1B    = (double*)(ws + 8388608);
  double*   XS     = (double*)(ws + 12582912);    // 100*32*128
  double*   C1O    = (double*)(ws + 15859712);    // 32*16*1024
  double*   C2O    = (double*)(ws + 20054016);    // 32*32*1024
  double*   C3O    = (double*)(ws + 28442624);    // 32*32*1024
  double*   XZR    = (double*)(ws + 15859712);    // 100*32*256 (overlay)
  double*   XN     = (double*)(ws + 22413312);    // 100*32*256 (overlay)
  double*   XO     = (double*)(ws + 28966912);    // 100*32     (overlay)
  double*   WZRT   = (double*)(ws + 36831232);    // 256*256
  double*   WNT    = (double*)(ws + 37355520);
  double*   WO     = (double*)(ws + 37879808);
  double*   BZ     = (double*)(ws + 37881856);
  double*   BR     = (double*)(ws + 37882880);
  double*   BNN    = (double*)(ws + 37883904);
  double*   BO     = (double*)(ws + 37885952);
  double*   H2LW   = (double*)(ws + 37886208);
  double*   H2LB   = (double*)(ws + 37889280);
  double*   EMB    = (double*)(ws + 37889536);    // 32*128
  double*   OMAP   = (double*)(ws + 37922304);    // 32*64
  double*   AMAP   = (double*)(ws + 37938688);
  double*   P      = (double*)(ws + 37955072);    // 4096  [b][p]
  double*   LP     = (double*)(ws + 37987840);    // 4096  [b][p]
  int*      IDX    = (int*)   (ws + 38020608);    // 4096  [p*32+b]
  unsigned* KEYS   = (unsigned*)(ws + 38036992);  // 402
  double*   SCSH   = (double*)(ws + 38039040);    // 32*2
  double*   PARTS  = (double*)(ws + 38039552);    // 256
  double*   PARTS2 = (double*)(ws + 38041600);    // 256
  double*   PNPRE  = (double*)(ws + 38043648);    // 4096  [b][p]
  int*      FLAG   = (int*)   (ws + 38076416);
  double*   SINK   = (double*)(ws + 38076480);

  // ---- setup + layout probe ----
  k_keys<<<1, 64, 0, stream>>>(KEYS);
  k_probe<<<1, 64, 0, stream>>>(FLAG);
  k_rep0<<<1, 64, 0, stream>>>(FLAG, SINK);
  k_rep1<<<1, 64, 0, stream>>>(FLAG, SINK);
  k_rep2<<<1, 64, 0, stream>>>(FLAG, SINK);
  k_rep3<<<1, 64, 0, stream>>>(FLAG, SINK);
  k_rep4<<<1, 64, 0, stream>>>(FLAG, SINK);
  k_prep<<<517, 256, 0, stream>>>(fcz_w, fcz_b, fcr_w, fcr_b, fcn_w, fcn_b,
                                  fco_w, fco_b, h2l_w, h2l_b,
                                  WZRT, WNT, WO, BZ, BR, BNN, BO, H2LW, H2LB);
  k_h0<<<2048, 256, 0, stream>>>(KEYS, H0, P);

  // ---- frontend ----
  k_conv1<<<512, 256, 0, stream>>>(map_in, c1_w, C1O);
  k_bnstats1<<<128, 256, 0, stream>>>(C1O, PARTS, PARTS2, 16);
  k_bnstats2<<<1, 32, 0, stream>>>(PARTS, PARTS2, c1_g, c1_b, SCSH, 16);
  k_bnapply<<<2048, 256, 0, stream>>>(C1O, SCSH, 16);
  k_conv3x3<<<512, 256, 0, stream>>>(C1O, c2_w, C2O, 16, 32);
  k_bnstats1<<<256, 256, 0, stream>>>(C2O, PARTS, PARTS2, 32);
  k_bnstats2<<<1, 32, 0, stream>>>(PARTS, PARTS2, c2_g, c2_b, SCSH, 32);
  k_bnapply<<<4096, 256, 0, stream>>>(C2O, SCSH, 32);
  k_conv3x3<<<512, 256, 0, stream>>>(C2O, c3_w, C3O, 32, 32);
  k_bnstats1<<<256, 256, 0, stream>>>(C3O, PARTS, PARTS2, 32);
  k_bnstats2<<<1, 32, 0, stream>>>(PARTS, PARTS2, c3_g, c3_b, SCSH, 32);
  k_bnapply<<<4096, 256, 0, stream>>>(C3O, SCSH, 32);
  k_mapfc<<<512, 256, 0, stream>>>(C3O, map_w, map_b, EMB);
  k_maps<<<32, 64, 0, stream>>>(EMB, m2o_w, m2o_b, m2a_w, m2a_b, OMAP, AMAP);
  {
    dim3 g(100, 32);
    k_xs<<<g, 128, 0, stream>>>(obs_in, act_in, obs_w, obs_b, act_w, act_b,
                                OMAP, AMAP, WO, XS, XO);
  }
  k_xpre2<<<400, 256, 0, stream>>>(XS, WZRT, WNT, XZR, XN);

  // ---- scan over 100 timesteps (2 kernels/step) ----
  double* hb[2] = { H1A, H1B };
  for (int s = 0; s < 100; ++s) {
    const double* hsrc = (s == 0) ? H0 : hb[(s - 1) & 1];
    const int* idxp = (s == 0) ? nullptr : IDX;
    float* pfprev = (s == 0) ? nullptr : (pfout + (size_t)(s - 1) * 12288);
    k_step<<<256, 512, 0, stream>>>(hsrc, idxp,
        XZR + (size_t)s*32*256, XN + (size_t)s*32*256, XO + (size_t)s*32,
        WZRT, WNT, BZ, BR, BNN, WO, BO, P, H2LW, H2LB,
        hb[s & 1], LP, PNPRE, pfprev, yout, KEYS, s, FLAG);
    k_sr<<<512, 512, 0, stream>>>(LP, P, KEYS, s, IDX, PNPRE);
  }
  k_yfinal<<<32, 512, 0, stream>>>(hb[1], IDX, PNPRE, P, H2LW, H2LB, yout);
  k_pfend<<<1024, 256, 0, stream>>>(hb[1], IDX, H2LW, H2LB,
                                    pfout + (size_t)99 * 12288);
}